// Round 3
// baseline (2099.492 us; speedup 1.0000x reference)
//
#include <hip/hip_runtime.h>
#include <hip/hip_bf16.h>

#define EPSV 1e-5f

// ---------------- workspace layout (float offsets) ----------------
static constexpr long O_WIT = 1024;                 // [768][1500] f32
static constexpr long O_WHT = O_WIT + 1152000;      // packed bf16 Wh: 225000 uints (5 groups)
static constexpr long O_WTT = O_WHT + 450000;       // packed bf16 Wt: 135000 uints (5 slices)
static constexpr long O_WNT = O_WTT + 270000;       // [600][300] f32
static constexpr long O_WRT = O_WNT + 180000;       // [600][300] f32
static constexpr long O_W1NT= O_WRT + 180000;       // [900][300] f32
static constexpr long O_W1RT= O_W1NT + 270000;      // [900][300] f32
static constexpr long O_XF  = O_W1RT + 270000;      // [800][768]
static constexpr long O_XG  = O_XF + 614400;        // [800][1500]
static constexpr long O_HPUB= O_XG + 1200000;       // cs_pub[1500][8]=12000, h_pub[300][8]=2400,
                                                    // c_pub[2][300][8]=4800, counters (ints)
static constexpr long O_HNER= O_HPUB + 19296;       // [800][300]
static constexpr long O_HRE = O_HNER + 240000;
static constexpr long O_HSH = O_HRE + 240000;
static constexpr long O_TG  = O_HSH + 240000;       // [2][800][300]
static constexpr long O_AU  = O_TG + 480000;        // [2][800][300]
static constexpr long O_BU  = O_AU + 480000;
static constexpr long O_CU  = O_BU + 480000;        // [2][8][300]
static constexpr long O_MASK= O_CU + 4800;          // [100][8]
static constexpr long O_BI  = O_MASK + 800;
static constexpr long O_BH  = O_BI + 1504;
static constexpr long O_BT  = O_BH + 1504;
static constexpr long O_BN  = O_BT + 304;
static constexpr long O_B1N = O_BN + 304;
static constexpr long O_GN  = O_B1N + 304;
static constexpr long O_BEN = O_GN + 304;
static constexpr long O_W2N = O_BEN + 304;          // [8][300]
static constexpr long O_B2N = O_W2N + 2400;
static constexpr long O_BR  = O_B2N + 16;
static constexpr long O_B1R = O_BR + 304;
static constexpr long O_GR  = O_B1R + 304;
static constexpr long O_BER = O_GR + 304;
static constexpr long O_W2R = O_BER + 304;          // [12][300]
static constexpr long O_B2R = O_W2R + 3600;

__device__ __forceinline__ float ldin(const void* p, long i, int f32) {
  if (f32) return ((const float*)p)[i];
  unsigned int w = ((unsigned int)(((const unsigned short*)p)[i])) << 16;
  return __uint_as_float(w);
}
__device__ __forceinline__ unsigned short inbits(const void* p, long i, int f32) {
  if (!f32) return ((const unsigned short*)p)[i];
  __hip_bfloat16 hb = __float2bfloat16(((const float*)p)[i]);
  return *reinterpret_cast<unsigned short*>(&hb);
}
__device__ __forceinline__ void stout(void* p, long i, float v, int f32) {
  if (f32) ((float*)p)[i] = v;
  else ((__hip_bfloat16*)p)[i] = __float2bfloat16(v);
}
__device__ __forceinline__ float blo(unsigned int u) { return __uint_as_float(u << 16); }
__device__ __forceinline__ float bhi(unsigned int u) { return __uint_as_float(u & 0xffff0000u); }

// MALL-coherent (cross-XCD) data transfer: relaxed agent atomics -> sc0/sc1, no L2 flush
__device__ __forceinline__ void pubst(float* p, float v) {
  __hip_atomic_store(p, v, __ATOMIC_RELAXED, __HIP_MEMORY_SCOPE_AGENT);
}
__device__ __forceinline__ float publd(const float* p) {
  return __hip_atomic_load(p, __ATOMIC_RELAXED, __HIP_MEMORY_SCOPE_AGENT);
}
// fence-free barrier: drain own stores (vmcnt), then relaxed flag add + spin
__device__ __forceinline__ void arrive_wait(int* cnt, int target) {
  asm volatile("s_waitcnt vmcnt(0)" ::: "memory");
  __syncthreads();
  if (threadIdx.x == 0) {
    __hip_atomic_fetch_add(cnt, 1, __ATOMIC_RELAXED, __HIP_MEMORY_SCOPE_AGENT);
    int it = 0;
    while (__hip_atomic_load(cnt, __ATOMIC_RELAXED, __HIP_MEMORY_SCOPE_AGENT) < target &&
           it < (1 << 20)) { ++it; __builtin_amdgcn_s_sleep(2); }
  }
  __syncthreads();
}

// ---------------- init: dtype flag + zero pub buffers/counters ----------------
__global__ void k_init(float* ws, const void* mask) {
  if (blockIdx.x == 0 && threadIdx.x == 0) {
    unsigned int u = *((const unsigned int*)mask);  // mask is all-ones
    ((int*)ws)[0] = (u == 0x3F800000u) ? 1 : 0;     // f32 1.0f vs bf16 {1,1}
  }
  for (long i = blockIdx.x * 1024 + threadIdx.x; i < 7232; i += (long)gridDim.x * 1024)
    ws[O_HPUB + 12000 + i] = 0.f;                   // h_pub, c_pub, counters
}

// ---------------- transpose f32 weights (non-scan) ----------------
__global__ __launch_bounds__(256) void k_transpose(float* ws,
    const void* w0, const void* w1, const void* w2, const void* w3, const void* w4) {
  __shared__ float ts[32][33];
  const int m = blockIdx.y;
  int R, C; long D; const void* src;
  switch (m) {
    case 0: src = w0; R = 1500; C = 768; D = O_WIT; break;
    case 1: src = w1; R = 300; C = 600; D = O_WNT; break;
    case 2: src = w2; R = 300; C = 600; D = O_WRT; break;
    case 3: src = w3; R = 300; C = 900; D = O_W1NT; break;
    default: src = w4; R = 300; C = 900; D = O_W1RT; break;
  }
  const int f32 = ((const int*)ws)[0];
  const int tC = (C + 31) >> 5, tR = (R + 31) >> 5;
  const int tx = threadIdx.x & 31, ty = threadIdx.x >> 5;
  for (int tile = blockIdx.x; tile < tC * tR; tile += gridDim.x) {
    int tr = tile / tC, tc = tile - tr * tC;
    int r0 = tr * 32, c0 = tc * 32;
    __syncthreads();
#pragma unroll
    for (int k = 0; k < 4; k++) {
      int r = r0 + ty + 8 * k, c = c0 + tx;
      ts[ty + 8 * k][tx] = (r < R && c < C) ? ldin(src, (long)r * C + c, f32) : 0.f;
    }
    __syncthreads();
#pragma unroll
    for (int k = 0; k < 4; k++) {
      int c = c0 + ty + 8 * k, r = r0 + tx;
      if (c < C && r < R) ws[D + (long)c * R + r] = ts[tx][ty + 8 * k];
    }
  }
}

// ---------------- pack scan weights: per-group / per-slice bf16 tiles ----------------
// WH: uint q = g*45000 + (k4*150+o2)*4+kk packs Wh[g*300+2o2][4k4+kk] | Wh[g*300+2o2+1][..]
// WT: uint q = s*27000 + (k4*30 +o2)*4+kk packs Wt[60s+2o2][4k4+kk]   | Wt[60s+2o2+1][..]
__global__ __launch_bounds__(256) void k_pack(float* ws, const void* wh, const void* wt) {
  const int f32 = ((const int*)ws)[0];
  int q = blockIdx.x * 256 + threadIdx.x;
  if (q < 225000) {
    int gq = q / 45000, q2 = q % 45000;
    int kk = q2 & 3, r = q2 >> 2;
    int o2 = r % 150, k4 = r / 150;
    int k = 4 * k4 + kk, row = gq * 300 + 2 * o2;
    unsigned int lo = inbits(wh, (long)row * 300 + k, f32);
    unsigned int hi = inbits(wh, (long)(row + 1) * 300 + k, f32);
    ((unsigned int*)(ws + O_WHT))[q] = (hi << 16) | lo;
  } else if (q < 360000) {
    int q2 = q - 225000;
    int s = q2 / 27000, q3 = q2 % 27000;
    int kk = q3 & 3, r = q3 >> 2;
    int o2 = r % 30, k4 = r / 30;
    int k = 4 * k4 + kk, row = s * 60 + 2 * o2;
    unsigned int lo = inbits(wt, (long)row * 900 + k, f32);
    unsigned int hi = inbits(wt, (long)(row + 1) * 900 + k, f32);
    ((unsigned int*)(ws + O_WTT))[q2] = (hi << 16) | lo;
  }
}

// ---------------- copy x / mask / biases to f32 ----------------
__global__ void k_misc(float* ws, const void* x, const void* mask,
    const void* bi, const void* bh, const void* bt,
    const void* bn, const void* b1n, const void* gn, const void* ben,
    const void* w2n, const void* b2n,
    const void* br, const void* b1r, const void* gr, const void* ber,
    const void* w2r, const void* b2r) {
  const int f32 = ((const int*)ws)[0];
  long i = (long)blockIdx.x * blockDim.x + threadIdx.x;
  long stride = (long)gridDim.x * blockDim.x;
  for (; i < 626920; i += stride) {
    long idx = i; const void* s; long d;
    if (idx < 614400)            { s = x;   d = O_XF; }
    else if ((idx -= 614400) < 800)  { s = mask; d = O_MASK; }
    else if ((idx -= 800) < 1500)    { s = bi;  d = O_BI; }
    else if ((idx -= 1500) < 1500)   { s = bh;  d = O_BH; }
    else if ((idx -= 1500) < 300)    { s = bt;  d = O_BT; }
    else if ((idx -= 300) < 300)     { s = bn;  d = O_BN; }
    else if ((idx -= 300) < 300)     { s = b1n; d = O_B1N; }
    else if ((idx -= 300) < 300)     { s = gn;  d = O_GN; }
    else if ((idx -= 300) < 300)     { s = ben; d = O_BEN; }
    else if ((idx -= 300) < 2400)    { s = w2n; d = O_W2N; }
    else if ((idx -= 2400) < 8)      { s = b2n; d = O_B2N; }
    else if ((idx -= 8) < 300)       { s = br;  d = O_BR; }
    else if ((idx -= 300) < 300)     { s = b1r; d = O_B1R; }
    else if ((idx -= 300) < 300)     { s = gr;  d = O_GR; }
    else if ((idx -= 300) < 300)     { s = ber; d = O_BER; }
    else if ((idx -= 300) < 3600)    { s = w2r; d = O_W2R; }
    else { idx -= 3600; s = b2r; d = O_B2R; }
    ws[d + idx] = ldin(s, idx, f32);
  }
}

// ---------------- xg = x @ WiT + bi : [800][1500] ----------------
__global__ __launch_bounds__(256) void k_xg(float* ws) {
  __shared__ float xs[768 * 16];             // [d][r]
  const int m0 = blockIdx.x * 16;
  const int col = blockIdx.y * 256 + threadIdx.x;
  for (int s = threadIdx.x; s < 768 * 16; s += 256) {
    int rr = s / 768, dd = s - rr * 768;
    xs[dd * 16 + rr] = ws[O_XF + (long)(m0 + rr) * 768 + dd];
  }
  __syncthreads();
  if (col < 1500) {
    float acc[16];
#pragma unroll
    for (int r = 0; r < 16; ++r) acc[r] = 0.f;
    const float* wp = ws + O_WIT + col;
    for (int d = 0; d < 768; ++d) {
      float w = wp[(long)d * 1500];
#pragma unroll
      for (int r = 0; r < 16; ++r) acc[r] += w * xs[d * 16 + r];
    }
    float bv = ws[O_BI + col];
#pragma unroll
    for (int r = 0; r < 16; ++r)
      ws[O_XG + (long)(m0 + r) * 1500 + col] = acc[r] + bv;
  }
}

// ---------------- the recurrent scan: 10 WGs = (group/slice, batch-half) ----------------
#define FMA8(u, vb, k) { float4 hv = (vb)[k]; float wl = blo(u), wh = bhi(u);       \
  a[0][0] = fmaf(wl, hv.x, a[0][0]); a[0][1] = fmaf(wl, hv.y, a[0][1]);             \
  a[0][2] = fmaf(wl, hv.z, a[0][2]); a[0][3] = fmaf(wl, hv.w, a[0][3]);             \
  a[1][0] = fmaf(wh, hv.x, a[1][0]); a[1][1] = fmaf(wh, hv.y, a[1][1]);             \
  a[1][2] = fmaf(wh, hv.z, a[1][2]); a[1][3] = fmaf(wh, hv.w, a[1][3]); }

__global__ __launch_bounds__(768, 1) void k_scan(float* ws) {
  const int w = blockIdx.x;            // 10
  const int g = w >> 1;                // gate group (phase A) / output slice (phase B)
  const int half = w & 1;
  const int b0 = 4 * half;
  const int t = threadIdx.x;
  const int lane = t & 63, wid = t >> 6;
  const uint4* WH4 = (const uint4*)(ws + O_WHT) + g * 11250;   // 180 KB slice, L2-resident
  const uint4* WT4 = (const uint4*)(ws + O_WTT) + g * 6750;    // 108 KB slice
  const float* xg = ws + O_XG;
  const float* bh = ws + O_BH;
  const float* bt = ws + O_BT;
  float* cs_pub = ws + O_HPUB;             // [1500][8]
  float* h_pub  = ws + O_HPUB + 12000;     // [300][8]
  float* c_pub  = ws + O_HPUB + 14400;     // [2][300][8]
  int* cnt = (int*)(ws + O_HPUB + 19200);  // [0]=A, [1]=B

  __shared__ __align__(16) float hL[1216];    // h[k][bb]
  __shared__ __align__(16) float gacc[6080];  // split-k partials (A) / (B, first 6000)
  __shared__ __align__(16) float gate[1216];  // [bb][304]
  __shared__ __align__(16) float catL[3616];  // cat[k][bb], k<900

  for (int l = 0; l < 100; ++l) {
    // ---- phase A: gather h (from MALL), GEMV1, cumsoftmax, publish cs ----
    for (int i = t; i < 1200; i += 768)
      hL[i] = publd(h_pub + (i >> 2) * 8 + b0 + (i & 3));
    __syncthreads();
    if (t < 750) {
      const int o2 = t % 150, kq = t / 150;
      float a[2][4] = {{0.f,0.f,0.f,0.f},{0.f,0.f,0.f,0.f}};
      const float4* h4 = (const float4*)hL;
#pragma unroll 3
      for (int k4 = kq * 15; k4 < kq * 15 + 15; ++k4) {
        uint4 wv = WH4[k4 * 150 + o2];
        FMA8(wv.x, h4, 4 * k4 + 0); FMA8(wv.y, h4, 4 * k4 + 1);
        FMA8(wv.z, h4, 4 * k4 + 2); FMA8(wv.w, h4, 4 * k4 + 3);
      }
#pragma unroll
      for (int oo = 0; oo < 2; ++oo)
#pragma unroll
        for (int bb = 0; bb < 4; ++bb)
          gacc[kq * 1216 + (2 * o2 + oo) * 4 + bb] = a[oo][bb];
    }
    __syncthreads();
    for (int i = t; i < 1200; i += 768) {
      int oidx = i >> 2, bb = i & 3;
      float v = gacc[oidx * 4 + bb] + gacc[1216 + oidx * 4 + bb] + gacc[2432 + oidx * 4 + bb]
              + gacc[3648 + oidx * 4 + bb] + gacc[4864 + oidx * 4 + bb];
      v += xg[((long)l * 8 + b0 + bb) * 1500 + g * 300 + oidx] + bh[g * 300 + oidx];
      gate[bb * 304 + oidx] = v;
    }
    __syncthreads();
    if (wid < 4) {                       // wave -> batch bb=wid
      const float* gr = gate + wid * 304;
      const int base = lane * 5;
      if (g == 0) {                      // cg: tanh
        if (lane < 60) {
#pragma unroll
          for (int i = 0; i < 5; ++i)
            pubst(cs_pub + (long)(base + i) * 8 + b0 + wid, tanhf(gr[base + i]));
        }
      } else {                           // cumsoftmax over 300
        float e0 = 0.f, e1 = 0.f, e2 = 0.f, e3 = 0.f, e4 = 0.f, m = -3.0e38f;
        if (lane < 60) {
          e0 = gr[base]; e1 = gr[base + 1]; e2 = gr[base + 2];
          e3 = gr[base + 3]; e4 = gr[base + 4];
          m = fmaxf(fmaxf(fmaxf(e0, e1), fmaxf(e2, e3)), e4);
        }
#pragma unroll
        for (int of = 32; of >= 1; of >>= 1) m = fmaxf(m, __shfl_xor(m, of, 64));
        float s0 = 0.f, s1 = 0.f, s2 = 0.f, s3 = 0.f, s4 = 0.f, tot = 0.f;
        if (lane < 60) {
          e0 = __expf(e0 - m); e1 = __expf(e1 - m); e2 = __expf(e2 - m);
          e3 = __expf(e3 - m); e4 = __expf(e4 - m);
          s0 = e0; s1 = s0 + e1; s2 = s1 + e2; s3 = s2 + e3; s4 = s3 + e4;
          tot = s4;
        }
        float sc = tot;
#pragma unroll
        for (int of = 1; of < 64; of <<= 1) {
          float u = __shfl_up(sc, of, 64);
          if (lane >= of) sc += u;
        }
        float total = __shfl(sc, 63);
        if (lane < 60) {
          float ex = sc - tot, inv = 1.f / total;
          pubst(cs_pub + (long)(g * 300 + base + 0) * 8 + b0 + wid, (ex + s0) * inv);
          pubst(cs_pub + (long)(g * 300 + base + 1) * 8 + b0 + wid, (ex + s1) * inv);
          pubst(cs_pub + (long)(g * 300 + base + 2) * 8 + b0 + wid, (ex + s2) * inv);
          pubst(cs_pub + (long)(g * 300 + base + 3) * 8 + b0 + wid, (ex + s3) * inv);
          pubst(cs_pub + (long)(g * 300 + base + 4) * 8 + b0 + wid, (ex + s4) * inv);
        }
      }
    }
    arrive_wait(cnt + 0, 10 * (l + 1));

    // ---- phase B: gather cs/c, combine -> cat, GEMV2 slice, publish h,c ----
    if (t < 600) {
      int tt = t % 300, pr = t / 300;
#pragma unroll
      for (int q = 0; q < 2; ++q) {
        int bb = pr * 2 + q, b = b0 + bb;
        float cgv = publd(cs_pub + (long)tt * 8 + b);
        float egi = 1.f - publd(cs_pub + (long)(300 + tt) * 8 + b);
        float rgi = publd(cs_pub + (long)(600 + tt) * 8 + b);
        float egc = 1.f - publd(cs_pub + (long)(900 + tt) * 8 + b);
        float rgc = publd(cs_pub + (long)(1200 + tt) * 8 + b);
        float cin = publd(c_pub + (l & 1) * 2400 + tt * 8 + b);
        float ovc = rgc * egc, upc = rgc - ovc, dnc = egc - ovc;
        float ovi = rgi * egi, upi = rgi - ovi, dni = egi - ovi;
        float sh = ovi * cin + ovc * cgv;
        float cre = upi * cin + upc * cgv + sh;
        float cner = dni * cin + dnc * cgv + sh;
        catL[tt * 4 + bb] = cre;
        catL[(300 + tt) * 4 + bb] = cner;
        catL[(600 + tt) * 4 + bb] = sh;
        if (g == 0) {
          long ob = ((long)l * 8 + b) * 300 + tt;
          ws[O_HNER + ob] = tanhf(cner);
          ws[O_HRE + ob] = tanhf(cre);
          ws[O_HSH + ob] = tanhf(sh);
        }
      }
    }
    __syncthreads();
    if (t < 750) {
      const int o2 = t % 30, kq = t / 30;
      float a[2][4] = {{0.f,0.f,0.f,0.f},{0.f,0.f,0.f,0.f}};
      const float4* c4 = (const float4*)catL;
#pragma unroll 3
      for (int k4 = kq * 9; k4 < kq * 9 + 9; ++k4) {
        uint4 wv = WT4[k4 * 30 + o2];
        FMA8(wv.x, c4, 4 * k4 + 0); FMA8(wv.y, c4, 4 * k4 + 1);
        FMA8(wv.z, c4, 4 * k4 + 2); FMA8(wv.w, c4, 4 * k4 + 3);
      }
#pragma unroll
      for (int oo = 0; oo < 2; ++oo)
#pragma unroll
        for (int bb = 0; bb < 4; ++bb)
          gacc[kq * 240 + (2 * o2 + oo) * 4 + bb] = a[oo][bb];
    }
    __syncthreads();
    if (t < 240) {
      int o = t >> 2, bb = t & 3;
      float s = bt[g * 60 + o];
#pragma unroll
      for (int kq = 0; kq < 25; ++kq) s += gacc[kq * 240 + o * 4 + bb];
      int go = g * 60 + o, b = b0 + bb;
      pubst(h_pub + (long)go * 8 + b, tanhf(s));
      pubst(c_pub + ((l + 1) & 1) * 2400 + go * 8 + b, s);
    }
    arrive_wait(cnt + 1, 10 * (l + 1));
  }
}

// ---------------- pooled units: tG = tanh(cat(h_share,h_x)@WT + b) ----------------
__global__ __launch_bounds__(320) void k_g3a(float* ws, void* dout) {
  const int u = blockIdx.y;
  const int lb0 = blockIdx.x * 16;
  const int f32 = ((const int*)ws)[0];
  __shared__ float csm[600 * 16];
  const float* h1 = ws + O_HSH;
  const float* h2 = ws + (u ? O_HRE : O_HNER);
  const float* WT = ws + (u ? O_WRT : O_WNT);
  const float* bias = ws + (u ? O_BR : O_BN);
  for (int s = threadIdx.x; s < 16 * 300; s += 320) {
    int r = s / 300, k = s - r * 300;
    csm[k * 16 + r] = h1[(long)(lb0 + r) * 300 + k];
    csm[(300 + k) * 16 + r] = h2[(long)(lb0 + r) * 300 + k];
  }
  __syncthreads();
  const int o = threadIdx.x;
  if (o < 300) {
    float acc[16];
#pragma unroll
    for (int r = 0; r < 16; ++r) acc[r] = 0.f;
    const float* wp = WT + o;
    for (int k = 0; k < 600; ++k) {
      float w = wp[(long)k * 300];
#pragma unroll
      for (int r = 0; r < 16; ++r) acc[r] += w * csm[k * 16 + r];
    }
    float bb = bias[o];
#pragma unroll
    for (int r = 0; r < 16; ++r) {
      float tv = tanhf(acc[r] + bb);
      ws[O_TG + (long)u * 240000 + (long)(lb0 + r) * 300 + o] = tv;
      if (u == 1) stout(dout, 1600000L + (long)(lb0 + r) * 300 + o, tv, f32);
    }
  }
}

// ---------------- max over L + global projection c ----------------
__global__ __launch_bounds__(320) void k_g3b(float* ws) {
  const int u = blockIdx.x >> 3, b = blockIdx.x & 7;
  __shared__ float hs[304];
  const int o = threadIdx.x;
  const float* tg = ws + O_TG + (long)u * 240000;
  if (o < 300) {
    float m = -3e38f;
    for (int l = 0; l < 100; ++l) m = fmaxf(m, tg[((long)l * 8 + b) * 300 + o]);
    hs[o] = m;
  }
  __syncthreads();
  if (o < 300) {
    const float* w1 = ws + (u ? O_W1RT : O_W1NT);
    float acc = ws[(u ? O_B1R : O_B1N) + o];
    for (int k = 0; k < 300; ++k) acc += hs[k] * w1[(long)(600 + k) * 300 + o];
    ws[O_CU + (long)u * 2400 + b * 300 + o] = acc;
  }
}

// ---------------- start/end token projections a,b ----------------
__global__ __launch_bounds__(320) void k_g3c(float* ws) {
  const int u = blockIdx.y;
  const int lb0 = blockIdx.x * 16;
  __shared__ float hx[300 * 16];
  const float* src = ws + (u ? O_HRE : O_HNER);
  for (int s = threadIdx.x; s < 16 * 300; s += 320) {
    int r = s / 300, k = s - r * 300;
    hx[k * 16 + r] = src[(long)(lb0 + r) * 300 + k];
  }
  __syncthreads();
  const int o = threadIdx.x;
  if (o < 300) {
    float accA[16], accB[16];
#pragma unroll
    for (int r = 0; r < 16; ++r) { accA[r] = 0.f; accB[r] = 0.f; }
    const float* w1 = ws + (u ? O_W1RT : O_W1NT);
    const float* wA = w1 + o;
    const float* wB = w1 + 300L * 300 + o;
    for (int k = 0; k < 300; ++k) {
      float wa = wA[(long)k * 300], wb = wB[(long)k * 300];
#pragma unroll
      for (int r = 0; r < 16; ++r) {
        float xv = hx[k * 16 + r];
        accA[r] += wa * xv;
        accB[r] += wb * xv;
      }
    }
#pragma unroll
    for (int r = 0; r < 16; ++r) {
      ws[O_AU + (long)u * 240000 + (long)(lb0 + r) * 300 + o] = accA[r];
      ws[O_BU + (long)u * 240000 + (long)(lb0 + r) * 300 + o] = accB[r];
    }
  }
}

// ---------------- fused pair scoring: LN -> elu -> @W2 -> sigmoid*mask ----------------
template <int NOUT, bool TRI>
__global__ __launch_bounds__(512) void k_pairs(float* ws, void* dout, long obase,
    long uofs, long w2ofs, long b2ofs, long gofs, long beofs, long cofs) {
  const int it = blockIdx.x, jt = blockIdx.y, b = blockIdx.z;
  const int j0 = jt * 32;
  const int f32 = ((const int*)ws)[0];
  __shared__ float bS[32 * 300];
  __shared__ float mjS[32];
  const float* BUp = ws + O_BU + uofs;
  for (int s = threadIdx.x; s < 32 * 300; s += 512) {
    int jj = s / 300, oo = s - jj * 300;
    int j = j0 + jj;
    bS[s] = (j < 100) ? BUp[((long)j * 8 + b) * 300 + oo] : 0.f;
  }
  if (threadIdx.x < 32) {
    int j = j0 + threadIdx.x;
    mjS[threadIdx.x] = (j < 100) ? ws[O_MASK + j * 8 + b] : 0.f;
  }
  __syncthreads();
  const int w = threadIdx.x >> 6;
  const int lane = threadIdx.x & 63;
  const int i = it * 8 + w;
  if (i >= 100) return;
  float ac[5], gv[5], bev[5], w2v[NOUT][5];
#pragma unroll
  for (int r = 0; r < 5; ++r) {
    int o = lane + 64 * r;
    bool val = o < 300;
    float a = val ? ws[O_AU + uofs + ((long)i * 8 + b) * 300 + o] : 0.f;
    float cc = val ? ws[cofs + b * 300 + o] : 0.f;
    ac[r] = a + cc;
    gv[r] = val ? ws[gofs + o] : 0.f;
    bev[r] = val ? ws[beofs + o] : 0.f;
#pragma unroll
    for (int q = 0; q < NOUT; ++q) w2v[q][r] = val ? ws[w2ofs + (long)q * 300 + o] : 0.f;
  }
  float b2v[NOUT];
#pragma unroll
  for (int q = 0; q < NOUT; ++q) b2v[q] = ws[b2ofs + q];
  float mi = ws[O_MASK + i * 8 + b];
  const int jmax = (100 - j0 < 32) ? (100 - j0) : 32;
  for (int jj = 0; jj < jmax; ++jj) {
    int j = j0 + jj;
    float vv[5], sum = 0.f, ssq = 0.f;
#pragma unroll
    for (int r = 0; r < 5; ++r) {
      int o = lane + 64 * r;
      float bv = (o < 300) ? bS[jj * 300 + o] : 0.f;
      float v = ac[r] + bv;
      if (o >= 300) v = 0.f;
      vv[r] = v;
      sum += v; ssq += v * v;
    }
#pragma unroll
    for (int of = 32; of >= 1; of >>= 1) {
      sum += __shfl_xor(sum, of, 64);
      ssq += __shfl_xor(ssq, of, 64);
    }
    float mean = sum * (1.f / 300.f);
    float var = ssq * (1.f / 300.f) - mean * mean;
    float inv = rsqrtf(var + EPSV);
    float acc[NOUT];
#pragma unroll
    for (int q = 0; q < NOUT; ++q) acc[q] = 0.f;
#pragma unroll
    for (int r = 0; r < 5; ++r) {
      float xn = (vv[r] - mean) * inv * gv[r] + bev[r];
      float e = xn > 0.f ? xn : (__expf(xn) - 1.f);
      if (lane + 64 * r >= 300) e = 0.f;
#pragma unroll
      for (int q = 0; q < NOUT; ++q) acc[q] += e * w2v[q][r];
    }
#pragma unroll
    for (int q = 0; q < NOUT; ++q) {
#pragma unroll
      for (int of = 32; of >= 1; of >>= 1) acc[q] += __shfl_xor(acc[q], of, 64);
    }
    if (lane == 0) {
      float mv = mi * mjS[jj];
      if (TRI && j < i) mv = 0.f;
      long base = obase + (((long)i * 100 + j) * 8 + b) * NOUT;
#pragma unroll
      for (int q = 0; q < NOUT; ++q) {
        float s = mv / (1.f + __expf(-(acc[q] + b2v[q])));
        stout(dout, base + q, s, f32);
      }
    }
  }
}

// ---------------- host ----------------
extern "C" void kernel_launch(void* const* d_in, const int* in_sizes, int n_in,
                              void* d_out, int out_size, void* d_ws, size_t ws_size,
                              hipStream_t stream) {
  (void)in_sizes; (void)n_in; (void)out_size; (void)ws_size;
  float* ws = (float*)d_ws;
  k_init<<<dim3(8), dim3(1024), 0, stream>>>(ws, d_in[1]);
  k_transpose<<<dim3(480, 5), dim3(256), 0, stream>>>(ws,
      d_in[2], d_in[8], d_in[16], d_in[10], d_in[18]);
  k_pack<<<dim3(1407), dim3(256), 0, stream>>>(ws, d_in[4], d_in[6]);
  k_misc<<<dim3(1024), dim3(256), 0, stream>>>(ws,
      d_in[0], d_in[1], d_in[3], d_in[5], d_in[7],
      d_in[9], d_in[11], d_in[12], d_in[13], d_in[14], d_in[15],
      d_in[17], d_in[19], d_in[20], d_in[21], d_in[22], d_in[23]);
  k_xg<<<dim3(50, 6), dim3(256), 0, stream>>>(ws);
  k_scan<<<dim3(10), dim3(768), 0, stream>>>(ws);
  k_g3a<<<dim3(50, 2), dim3(320), 0, stream>>>(ws, d_out);
  k_g3c<<<dim3(50, 2), dim3(320), 0, stream>>>(ws);
  k_g3b<<<dim3(16), dim3(320), 0, stream>>>(ws);
  k_pairs<8, true><<<dim3(13, 4, 8), dim3(512), 0, stream>>>(ws, d_out,
      0L, 0L, O_W2N, O_B2N, O_GN, O_BEN, O_CU);
  k_pairs<12, false><<<dim3(13, 4, 8), dim3(512), 0, stream>>>(ws, d_out,
      640000L, 240000L, O_W2R, O_B2R, O_GR, O_BER, O_CU + 2400);
}

// Round 4
// 1050.490 us; speedup vs baseline: 1.9986x; 1.9986x over previous
//
#include <hip/hip_runtime.h>
#include <hip/hip_bf16.h>

#define EPSV 1e-5f

typedef _Float16 f16x2 __attribute__((ext_vector_type(2)));

// ---------------- workspace layout (float offsets) ----------------
static constexpr long O_WIT = 1024;                 // [768][1500] f32
static constexpr long O_WHT = O_WIT + 1152000;      // packed f16-pair Wh: 225000 uints
static constexpr long O_WTT = O_WHT + 450000;       // packed f16-pair Wt: 135000 uints
static constexpr long O_WNT = O_WTT + 270000;       // [600][300] f32
static constexpr long O_WRT = O_WNT + 180000;       // [600][300] f32
static constexpr long O_W1NT= O_WRT + 180000;       // [900][300] f32
static constexpr long O_W1RT= O_W1NT + 270000;      // [900][300] f32
static constexpr long O_XF  = O_W1RT + 270000;      // [800][768]
static constexpr long O_XG  = O_XF + 614400;        // [800][1500]
static constexpr long O_PUB = O_XG + 1200000;       // cs[8][1504], h[8][304], c[8][304], counters
static constexpr long O_HNER= O_PUB + 19296;        // [800][300]
static constexpr long O_HRE = O_HNER + 240000;
static constexpr long O_HSH = O_HRE + 240000;
static constexpr long O_TG  = O_HSH + 240000;       // [2][800][300]
static constexpr long O_AU  = O_TG + 480000;        // [2][800][300]
static constexpr long O_BU  = O_AU + 480000;
static constexpr long O_CU  = O_BU + 480000;        // [2][8][300]
static constexpr long O_MASK= O_CU + 4800;          // [100][8]
static constexpr long O_BI  = O_MASK + 800;
static constexpr long O_BH  = O_BI + 1504;
static constexpr long O_BT  = O_BH + 1504;
static constexpr long O_BN  = O_BT + 304;
static constexpr long O_B1N = O_BN + 304;
static constexpr long O_GN  = O_B1N + 304;
static constexpr long O_BEN = O_GN + 304;
static constexpr long O_W2N = O_BEN + 304;          // [8][300]
static constexpr long O_B2N = O_W2N + 2400;
static constexpr long O_BR  = O_B2N + 16;
static constexpr long O_B1R = O_BR + 304;
static constexpr long O_GR  = O_B1R + 304;
static constexpr long O_BER = O_GR + 304;
static constexpr long O_W2R = O_BER + 304;          // [12][300]
static constexpr long O_B2R = O_W2R + 3600;

__device__ __forceinline__ float ldin(const void* p, long i, int f32) {
  if (f32) return ((const float*)p)[i];
  unsigned int w = ((unsigned int)(((const unsigned short*)p)[i])) << 16;
  return __uint_as_float(w);
}
__device__ __forceinline__ void stout(void* p, long i, float v, int f32) {
  if (f32) ((float*)p)[i] = v;
  else ((__hip_bfloat16*)p)[i] = __float2bfloat16(v);
}
__device__ __forceinline__ unsigned packf16(float a, float b) {
  union { _Float16 h[2]; unsigned u; } x;
  x.h[0] = (_Float16)a; x.h[1] = (_Float16)b;
  return x.u;
}
__device__ __forceinline__ float dot2(unsigned wu, unsigned xu, float acc) {
  return __builtin_amdgcn_fdot2(__builtin_bit_cast(f16x2, wu),
                                __builtin_bit_cast(f16x2, xu), acc, false);
}

// MALL-coherent cross-XCD transfer: relaxed agent atomics, no L2 flush
__device__ __forceinline__ void pubst(float* p, float v) {
  __hip_atomic_store(p, v, __ATOMIC_RELAXED, __HIP_MEMORY_SCOPE_AGENT);
}
__device__ __forceinline__ float publd(const float* p) {
  return __hip_atomic_load(p, __ATOMIC_RELAXED, __HIP_MEMORY_SCOPE_AGENT);
}
__device__ __forceinline__ void arrive_wait(int* cnt, int target) {
  asm volatile("s_waitcnt vmcnt(0)" ::: "memory");
  __syncthreads();
  if (threadIdx.x == 0) {
    __hip_atomic_fetch_add(cnt, 1, __ATOMIC_RELAXED, __HIP_MEMORY_SCOPE_AGENT);
    int it = 0;
    while (__hip_atomic_load(cnt, __ATOMIC_RELAXED, __HIP_MEMORY_SCOPE_AGENT) < target &&
           it < (1 << 20)) { ++it; __builtin_amdgcn_s_sleep(1); }
  }
  __syncthreads();
}

// ---------------- init: dtype flag + zero pub state/counters ----------------
__global__ void k_init(float* ws, const void* mask) {
  if (blockIdx.x == 0 && threadIdx.x == 0) {
    unsigned int u = *((const unsigned int*)mask);
    ((int*)ws)[0] = (u == 0x3F800000u) ? 1 : 0;     // f32 vs bf16 input
  }
  for (long i = blockIdx.x * 1024 + threadIdx.x; i < 5200; i += (long)gridDim.x * 1024)
    ws[O_PUB + 12032 + i] = 0.f;                    // h_pub, c_pub, counters
}

// ---------------- transpose f32 weights (non-scan) ----------------
__global__ __launch_bounds__(256) void k_transpose(float* ws,
    const void* w0, const void* w1, const void* w2, const void* w3, const void* w4) {
  __shared__ float ts[32][33];
  const int m = blockIdx.y;
  int R, C; long D; const void* src;
  switch (m) {
    case 0: src = w0; R = 1500; C = 768; D = O_WIT; break;
    case 1: src = w1; R = 300; C = 600; D = O_WNT; break;
    case 2: src = w2; R = 300; C = 600; D = O_WRT; break;
    case 3: src = w3; R = 300; C = 900; D = O_W1NT; break;
    default: src = w4; R = 300; C = 900; D = O_W1RT; break;
  }
  const int f32 = ((const int*)ws)[0];
  const int tC = (C + 31) >> 5, tR = (R + 31) >> 5;
  const int tx = threadIdx.x & 31, ty = threadIdx.x >> 5;
  for (int tile = blockIdx.x; tile < tC * tR; tile += gridDim.x) {
    int tr = tile / tC, tc = tile - tr * tC;
    int r0 = tr * 32, c0 = tc * 32;
    __syncthreads();
#pragma unroll
    for (int k = 0; k < 4; k++) {
      int r = r0 + ty + 8 * k, c = c0 + tx;
      ts[ty + 8 * k][tx] = (r < R && c < C) ? ldin(src, (long)r * C + c, f32) : 0.f;
    }
    __syncthreads();
#pragma unroll
    for (int k = 0; k < 4; k++) {
      int c = c0 + ty + 8 * k, r = r0 + tx;
      if (c < C && r < R) ws[D + (long)c * R + r] = ts[tx][ty + 8 * k];
    }
  }
}

// ---------------- pack scan weights: per-thread-register f16-pair layout ----------------
// W1P[q], q = g*45000 + hh*22500 + i*450 + t : t=(kc*150+o2), row=g*300+2*o2+hh,
//   kpair = kc*50+i -> {Wh[row][2kp], Wh[row][2kp+1]} as f16 pair.
// W2P[q], q = g*27000 + hh*13500 + j*450 + t : t=(kc*30+o2), row=g*60+2*o2+hh,
//   kpair = kc*30+j -> {Wt[row][2kp], Wt[row][2kp+1]}.
__global__ __launch_bounds__(256) void k_pack(float* ws, const void* wh, const void* wt) {
  const int f32 = ((const int*)ws)[0];
  int q = blockIdx.x * 256 + threadIdx.x;
  if (q < 225000) {
    int g = q / 45000, r = q % 45000;
    int hh = r / 22500, r2 = r % 22500;
    int i = r2 / 450, t = r2 % 450;
    int o2 = t % 150, kc = t / 150;
    int row = g * 300 + 2 * o2 + hh;
    int k0 = 2 * (kc * 50 + i);
    float lo = ldin(wh, (long)row * 300 + k0, f32);
    float hi = ldin(wh, (long)row * 300 + k0 + 1, f32);
    ((unsigned*)(ws + O_WHT))[q] = packf16(lo, hi);
  } else if (q < 360000) {
    int q2 = q - 225000;
    int g = q2 / 27000, r = q2 % 27000;
    int hh = r / 13500, r2 = r % 13500;
    int j = r2 / 450, t = r2 % 450;
    int o2 = t % 30, kc = t / 30;
    int row = g * 60 + 2 * o2 + hh;
    int k0 = 2 * (kc * 30 + j);
    float lo = ldin(wt, (long)row * 900 + k0, f32);
    float hi = ldin(wt, (long)row * 900 + k0 + 1, f32);
    ((unsigned*)(ws + O_WTT))[q2] = packf16(lo, hi);
  }
}

// ---------------- copy x / mask / biases to f32 ----------------
__global__ void k_misc(float* ws, const void* x, const void* mask,
    const void* bi, const void* bh, const void* bt,
    const void* bn, const void* b1n, const void* gn, const void* ben,
    const void* w2n, const void* b2n,
    const void* br, const void* b1r, const void* gr, const void* ber,
    const void* w2r, const void* b2r) {
  const int f32 = ((const int*)ws)[0];
  long i = (long)blockIdx.x * blockDim.x + threadIdx.x;
  long stride = (long)gridDim.x * blockDim.x;
  for (; i < 626920; i += stride) {
    long idx = i; const void* s; long d;
    if (idx < 614400)            { s = x;   d = O_XF; }
    else if ((idx -= 614400) < 800)  { s = mask; d = O_MASK; }
    else if ((idx -= 800) < 1500)    { s = bi;  d = O_BI; }
    else if ((idx -= 1500) < 1500)   { s = bh;  d = O_BH; }
    else if ((idx -= 1500) < 300)    { s = bt;  d = O_BT; }
    else if ((idx -= 300) < 300)     { s = bn;  d = O_BN; }
    else if ((idx -= 300) < 300)     { s = b1n; d = O_B1N; }
    else if ((idx -= 300) < 300)     { s = gn;  d = O_GN; }
    else if ((idx -= 300) < 300)     { s = ben; d = O_BEN; }
    else if ((idx -= 300) < 2400)    { s = w2n; d = O_W2N; }
    else if ((idx -= 2400) < 8)      { s = b2n; d = O_B2N; }
    else if ((idx -= 8) < 300)       { s = br;  d = O_BR; }
    else if ((idx -= 300) < 300)     { s = b1r; d = O_B1R; }
    else if ((idx -= 300) < 300)     { s = gr;  d = O_GR; }
    else if ((idx -= 300) < 300)     { s = ber; d = O_BER; }
    else if ((idx -= 300) < 3600)    { s = w2r; d = O_W2R; }
    else { idx -= 3600; s = b2r; d = O_B2R; }
    ws[d + idx] = ldin(s, idx, f32);
  }
}

// ---------------- xg = x @ WiT + bi : [800][1500] ----------------
__global__ __launch_bounds__(256) void k_xg(float* ws) {
  __shared__ float xs[768 * 16];             // [d][r]
  const int m0 = blockIdx.x * 16;
  const int col = blockIdx.y * 256 + threadIdx.x;
  for (int s = threadIdx.x; s < 768 * 16; s += 256) {
    int rr = s / 768, dd = s - rr * 768;
    xs[dd * 16 + rr] = ws[O_XF + (long)(m0 + rr) * 768 + dd];
  }
  __syncthreads();
  if (col < 1500) {
    float acc[16];
#pragma unroll
    for (int r = 0; r < 16; ++r) acc[r] = 0.f;
    const float* wp = ws + O_WIT + col;
    for (int d = 0; d < 768; ++d) {
      float w = wp[(long)d * 1500];
#pragma unroll
      for (int r = 0; r < 16; ++r) acc[r] += w * xs[d * 16 + r];
    }
    float bv = ws[O_BI + col];
#pragma unroll
    for (int r = 0; r < 16; ++r)
      ws[O_XG + (long)(m0 + r) * 1500 + col] = acc[r] + bv;
  }
}

// ---------------- the recurrent scan: 40 WGs = (batch, group), weights in VGPRs ----------------
__global__ __launch_bounds__(512, 2) void k_scan(float* ws) {
  const int w = blockIdx.x;            // 40
  const int b = w & 7, g = w >> 3;     // batch, gate-group/output-slice
  const int t = threadIdx.x;
  const int lane = t & 63, wid = t >> 6;
  const unsigned* W1 = (const unsigned*)(ws + O_WHT) + g * 45000;
  const unsigned* W2 = (const unsigned*)(ws + O_WTT) + g * 27000;
  const float* xg = ws + O_XG;
  const float* bhp = ws + O_BH;
  const float* btp = ws + O_BT;
  float* cs_pub = ws + O_PUB + (long)b * 1504;
  float* h_pub  = ws + O_PUB + 12032 + (long)b * 304;
  float* c_pub  = ws + O_PUB + 14464 + (long)b * 304;
  int* cntA = (int*)(ws + O_PUB + 16900) + b * 16;
  int* cntB = cntA + 128;
  float* HN = ws + O_HNER + b * 300;
  float* HR = ws + O_HRE + b * 300;
  float* HS = ws + O_HSH + b * 300;

  // persistent weights in registers (f16 pairs along k)
  unsigned wA0[50], wA1[50], wB0[30], wB1[30];
  if (t < 450) {
#pragma unroll
    for (int i = 0; i < 50; ++i) { wA0[i] = W1[i * 450 + t]; wA1[i] = W1[22500 + i * 450 + t]; }
#pragma unroll
    for (int j = 0; j < 30; ++j) { wB0[j] = W2[j * 450 + t]; wB1[j] = W2[13500 + j * 450 + t]; }
  }

  __shared__ __align__(16) unsigned h2[152];     // h as f16 pairs
  __shared__ __align__(16) float cf[304];        // c(l-1) f32
  __shared__ __align__(16) float gatef[304];
  __shared__ __align__(16) float pacc[3][304];
  __shared__ __align__(16) float csL[1504];
  __shared__ __align__(16) float catf[912];
  __shared__ __align__(16) unsigned cat2[456];
  __shared__ __align__(16) float pacc2[15][64];

  const int o2a = t % 150, kca = t / 150;        // phase-A tile
  const int o2b = t % 30,  kcb = t / 30;         // phase-B tile

  for (int l = 0; l < 100; ++l) {
    // ---- phase A: gather h,c; gate slice = Wh_g@h + xg + bh; cumsoftmax; publish cs ----
    if (t < 150) {
      float e = publd(h_pub + 2 * t), o = publd(h_pub + 2 * t + 1);
      h2[t] = packf16(e, o);
    } else if (t < 450) {
      cf[t - 150] = publd(c_pub + (t - 150));
    }
    __syncthreads();
    if (t < 450) {
      float a0 = 0.f, a1 = 0.f;
      const unsigned* hp = h2 + kca * 50;
#pragma unroll
      for (int i = 0; i < 50; ++i) {
        unsigned hv = hp[i];
        a0 = dot2(wA0[i], hv, a0);
        a1 = dot2(wA1[i], hv, a1);
      }
      pacc[kca][2 * o2a] = a0; pacc[kca][2 * o2a + 1] = a1;
    }
    __syncthreads();
    if (t < 300)
      gatef[t] = pacc[0][t] + pacc[1][t] + pacc[2][t]
               + xg[((long)l * 8 + b) * 1500 + g * 300 + t] + bhp[g * 300 + t];
    __syncthreads();
    if (g == 0) {
      if (t < 300) pubst(cs_pub + t, tanhf(gatef[t]));
    } else if (wid == 0) {
      const int base = lane * 5;
      float e0 = 0.f, e1 = 0.f, e2 = 0.f, e3 = 0.f, e4 = 0.f, m = -3.0e38f;
      if (lane < 60) {
        e0 = gatef[base]; e1 = gatef[base + 1]; e2 = gatef[base + 2];
        e3 = gatef[base + 3]; e4 = gatef[base + 4];
        m = fmaxf(fmaxf(fmaxf(e0, e1), fmaxf(e2, e3)), e4);
      }
#pragma unroll
      for (int of = 32; of >= 1; of >>= 1) m = fmaxf(m, __shfl_xor(m, of, 64));
      float s0 = 0.f, s1 = 0.f, s2 = 0.f, s3 = 0.f, s4 = 0.f, tot = 0.f;
      if (lane < 60) {
        e0 = __expf(e0 - m); e1 = __expf(e1 - m); e2 = __expf(e2 - m);
        e3 = __expf(e3 - m); e4 = __expf(e4 - m);
        s0 = e0; s1 = s0 + e1; s2 = s1 + e2; s3 = s2 + e3; s4 = s3 + e4;
        tot = s4;
      }
      float sc = tot;
#pragma unroll
      for (int of = 1; of < 64; of <<= 1) {
        float u = __shfl_up(sc, of, 64);
        if (lane >= of) sc += u;
      }
      float total = __shfl(sc, 63);
      if (lane < 60) {
        float ex = sc - tot, inv = 1.f / total;
        pubst(cs_pub + g * 300 + base + 0, (ex + s0) * inv);
        pubst(cs_pub + g * 300 + base + 1, (ex + s1) * inv);
        pubst(cs_pub + g * 300 + base + 2, (ex + s2) * inv);
        pubst(cs_pub + g * 300 + base + 3, (ex + s3) * inv);
        pubst(cs_pub + g * 300 + base + 4, (ex + s4) * inv);
      }
    }
    arrive_wait(cntA, 5 * (l + 1));

    // ---- phase B: gather cs; combine -> cat; h-slice = Wt_rows@cat; publish h,c ----
    for (int i = t; i < 1500; i += 512) csL[i] = publd(cs_pub + i);
    __syncthreads();
    if (t < 300) {
      float cgv = csL[t];
      float egi = 1.f - csL[300 + t];
      float rgi = csL[600 + t];
      float egc = 1.f - csL[900 + t];
      float rgc = csL[1200 + t];
      float cin = cf[t];
      float ovc = rgc * egc, upc = rgc - ovc, dnc = egc - ovc;
      float ovi = rgi * egi, upi = rgi - ovi, dni = egi - ovi;
      float sh = ovi * cin + ovc * cgv;
      float cre = upi * cin + upc * cgv + sh;
      float cner = dni * cin + dnc * cgv + sh;
      catf[t] = cre; catf[300 + t] = cner; catf[600 + t] = sh;
      if (g == 0) {
        long ob = (long)l * 2400 + t;
        HN[ob] = tanhf(cner); HR[ob] = tanhf(cre); HS[ob] = tanhf(sh);
      }
    }
    __syncthreads();
    if (t < 450) cat2[t] = packf16(catf[2 * t], catf[2 * t + 1]);
    __syncthreads();
    if (t < 450) {
      float a0 = 0.f, a1 = 0.f;
      const unsigned* cp = cat2 + kcb * 30;
#pragma unroll
      for (int j = 0; j < 30; ++j) {
        unsigned cv = cp[j];
        a0 = dot2(wB0[j], cv, a0);
        a1 = dot2(wB1[j], cv, a1);
      }
      pacc2[kcb][2 * o2b] = a0; pacc2[kcb][2 * o2b + 1] = a1;
    }
    __syncthreads();
    if (t < 60) {
      float s = btp[g * 60 + t];
#pragma unroll
      for (int kc = 0; kc < 15; ++kc) s += pacc2[kc][t];
      pubst(h_pub + g * 60 + t, tanhf(s));
      pubst(c_pub + g * 60 + t, s);
    }
    arrive_wait(cntB, 5 * (l + 1));
  }
}

// ---------------- pooled units: tG = tanh(cat(h_share,h_x)@WT + b) ----------------
__global__ __launch_bounds__(320) void k_g3a(float* ws, void* dout) {
  const int u = blockIdx.y;
  const int lb0 = blockIdx.x * 16;
  const int f32 = ((const int*)ws)[0];
  __shared__ float csm[600 * 16];
  const float* h1 = ws + O_HSH;
  const float* h2p = ws + (u ? O_HRE : O_HNER);
  const float* WT = ws + (u ? O_WRT : O_WNT);
  const float* bias = ws + (u ? O_BR : O_BN);
  for (int s = threadIdx.x; s < 16 * 300; s += 320) {
    int r = s / 300, k = s - r * 300;
    csm[k * 16 + r] = h1[(long)(lb0 + r) * 300 + k];
    csm[(300 + k) * 16 + r] = h2p[(long)(lb0 + r) * 300 + k];
  }
  __syncthreads();
  const int o = threadIdx.x;
  if (o < 300) {
    float acc[16];
#pragma unroll
    for (int r = 0; r < 16; ++r) acc[r] = 0.f;
    const float* wp = WT + o;
    for (int k = 0; k < 600; ++k) {
      float w = wp[(long)k * 300];
#pragma unroll
      for (int r = 0; r < 16; ++r) acc[r] += w * csm[k * 16 + r];
    }
    float bb = bias[o];
#pragma unroll
    for (int r = 0; r < 16; ++r) {
      float tv = tanhf(acc[r] + bb);
      ws[O_TG + (long)u * 240000 + (long)(lb0 + r) * 300 + o] = tv;
      if (u == 1) stout(dout, 1600000L + (long)(lb0 + r) * 300 + o, tv, f32);
    }
  }
}

// ---------------- max over L + global projection c ----------------
__global__ __launch_bounds__(320) void k_g3b(float* ws) {
  const int u = blockIdx.x >> 3, b = blockIdx.x & 7;
  __shared__ float hs[304];
  const int o = threadIdx.x;
  const float* tg = ws + O_TG + (long)u * 240000;
  if (o < 300) {
    float m = -3e38f;
    for (int l = 0; l < 100; ++l) m = fmaxf(m, tg[((long)l * 8 + b) * 300 + o]);
    hs[o] = m;
  }
  __syncthreads();
  if (o < 300) {
    const float* w1 = ws + (u ? O_W1RT : O_W1NT);
    float acc = ws[(u ? O_B1R : O_B1N) + o];
    for (int k = 0; k < 300; ++k) acc += hs[k] * w1[(long)(600 + k) * 300 + o];
    ws[O_CU + (long)u * 2400 + b * 300 + o] = acc;
  }
}

// ---------------- start/end token projections a,b ----------------
__global__ __launch_bounds__(320) void k_g3c(float* ws) {
  const int u = blockIdx.y;
  const int lb0 = blockIdx.x * 16;
  __shared__ float hx[300 * 16];
  const float* src = ws + (u ? O_HRE : O_HNER);
  for (int s = threadIdx.x; s < 16 * 300; s += 320) {
    int r = s / 300, k = s - r * 300;
    hx[k * 16 + r] = src[(long)(lb0 + r) * 300 + k];
  }
  __syncthreads();
  const int o = threadIdx.x;
  if (o < 300) {
    float accA[16], accB[16];
#pragma unroll
    for (int r = 0; r < 16; ++r) { accA[r] = 0.f; accB[r] = 0.f; }
    const float* w1 = ws + (u ? O_W1RT : O_W1NT);
    const float* wA = w1 + o;
    const float* wB = w1 + 300L * 300 + o;
    for (int k = 0; k < 300; ++k) {
      float wa = wA[(long)k * 300], wb = wB[(long)k * 300];
#pragma unroll
      for (int r = 0; r < 16; ++r) {
        float xv = hx[k * 16 + r];
        accA[r] += wa * xv;
        accB[r] += wb * xv;
      }
    }
#pragma unroll
    for (int r = 0; r < 16; ++r) {
      ws[O_AU + (long)u * 240000 + (long)(lb0 + r) * 300 + o] = accA[r];
      ws[O_BU + (long)u * 240000 + (long)(lb0 + r) * 300 + o] = accB[r];
    }
  }
}

// ---------------- fused pair scoring: LN -> elu -> @W2 -> sigmoid*mask ----------------
template <int NOUT, bool TRI>
__global__ __launch_bounds__(512) void k_pairs(float* ws, void* dout, long obase,
    long uofs, long w2ofs, long b2ofs, long gofs, long beofs, long cofs) {
  const int it = blockIdx.x, jt = blockIdx.y, b = blockIdx.z;
  const int j0 = jt * 32;
  const int f32 = ((const int*)ws)[0];
  __shared__ float bS[32 * 300];
  __shared__ float mjS[32];
  const float* BUp = ws + O_BU + uofs;
  for (int s = threadIdx.x; s < 32 * 300; s += 512) {
    int jj = s / 300, oo = s - jj * 300;
    int j = j0 + jj;
    bS[s] = (j < 100) ? BUp[((long)j * 8 + b) * 300 + oo] : 0.f;
  }
  if (threadIdx.x < 32) {
    int j = j0 + threadIdx.x;
    mjS[threadIdx.x] = (j < 100) ? ws[O_MASK + j * 8 + b] : 0.f;
  }
  __syncthreads();
  const int w = threadIdx.x >> 6;
  const int lane = threadIdx.x & 63;
  const int i = it * 8 + w;
  if (i >= 100) return;
  float ac[5], gv[5], bev[5], w2v[NOUT][5];
#pragma unroll
  for (int r = 0; r < 5; ++r) {
    int o = lane + 64 * r;
    bool val = o < 300;
    float a = val ? ws[O_AU + uofs + ((long)i * 8 + b) * 300 + o] : 0.f;
    float cc = val ? ws[cofs + b * 300 + o] : 0.f;
    ac[r] = a + cc;
    gv[r] = val ? ws[gofs + o] : 0.f;
    bev[r] = val ? ws[beofs + o] : 0.f;
#pragma unroll
    for (int q = 0; q < NOUT; ++q) w2v[q][r] = val ? ws[w2ofs + (long)q * 300 + o] : 0.f;
  }
  float b2v[NOUT];
#pragma unroll
  for (int q = 0; q < NOUT; ++q) b2v[q] = ws[b2ofs + q];
  float mi = ws[O_MASK + i * 8 + b];
  const int jmax = (100 - j0 < 32) ? (100 - j0) : 32;
  for (int jj = 0; jj < jmax; ++jj) {
    int j = j0 + jj;
    float vv[5], sum = 0.f, ssq = 0.f;
#pragma unroll
    for (int r = 0; r < 5; ++r) {
      int o = lane + 64 * r;
      float bv = (o < 300) ? bS[jj * 300 + o] : 0.f;
      float v = ac[r] + bv;
      if (o >= 300) v = 0.f;
      vv[r] = v;
      sum += v; ssq += v * v;
    }
#pragma unroll
    for (int of = 32; of >= 1; of >>= 1) {
      sum += __shfl_xor(sum, of, 64);
      ssq += __shfl_xor(ssq, of, 64);
    }
    float mean = sum * (1.f / 300.f);
    float var = ssq * (1.f / 300.f) - mean * mean;
    float inv = rsqrtf(var + EPSV);
    float acc[NOUT];
#pragma unroll
    for (int q = 0; q < NOUT; ++q) acc[q] = 0.f;
#pragma unroll
    for (int r = 0; r < 5; ++r) {
      float xn = (vv[r] - mean) * inv * gv[r] + bev[r];
      float e = xn > 0.f ? xn : (__expf(xn) - 1.f);
      if (lane + 64 * r >= 300) e = 0.f;
#pragma unroll
      for (int q = 0; q < NOUT; ++q) acc[q] += e * w2v[q][r];
    }
#pragma unroll
    for (int q = 0; q < NOUT; ++q) {
#pragma unroll
      for (int of = 32; of >= 1; of >>= 1) acc[q] += __shfl_xor(acc[q], of, 64);
    }
    if (lane == 0) {
      float mv = mi * mjS[jj];
      if (TRI && j < i) mv = 0.f;
      long base = obase + (((long)i * 100 + j) * 8 + b) * NOUT;
#pragma unroll
      for (int q = 0; q < NOUT; ++q) {
        float s = mv / (1.f + __expf(-(acc[q] + b2v[q])));
        stout(dout, base + q, s, f32);
      }
    }
  }
}

// ---------------- host ----------------
extern "C" void kernel_launch(void* const* d_in, const int* in_sizes, int n_in,
                              void* d_out, int out_size, void* d_ws, size_t ws_size,
                              hipStream_t stream) {
  (void)in_sizes; (void)n_in; (void)out_size; (void)ws_size;
  float* ws = (float*)d_ws;
  k_init<<<dim3(8), dim3(1024), 0, stream>>>(ws, d_in[1]);
  k_transpose<<<dim3(480, 5), dim3(256), 0, stream>>>(ws,
      d_in[2], d_in[8], d_in[16], d_in[10], d_in[18]);
  k_pack<<<dim3(1407), dim3(256), 0, stream>>>(ws, d_in[4], d_in[6]);
  k_misc<<<dim3(1024), dim3(256), 0, stream>>>(ws,
      d_in[0], d_in[1], d_in[3], d_in[5], d_in[7],
      d_in[9], d_in[11], d_in[12], d_in[13], d_in[14], d_in[15],
      d_in[17], d_in[19], d_in[20], d_in[21], d_in[22], d_in[23]);
  k_xg<<<dim3(50, 6), dim3(256), 0, stream>>>(ws);
  k_scan<<<dim3(40), dim3(512), 0, stream>>>(ws);
  k_g3a<<<dim3(50, 2), dim3(320), 0, stream>>>(ws, d_out);
  k_g3c<<<dim3(50, 2), dim3(320), 0, stream>>>(ws);
  k_g3b<<<dim3(16), dim3(320), 0, stream>>>(ws);
  k_pairs<8, true><<<dim3(13, 4, 8), dim3(512), 0, stream>>>(ws, d_out,
      0L, 0L, O_W2N, O_B2N, O_GN, O_BEN, O_CU);
  k_pairs<12, false><<<dim3(13, 4, 8), dim3(512), 0, stream>>>(ws, d_out,
      640000L, 240000L, O_W2R, O_B2R, O_GR, O_BER, O_CU + 2400);
}

// Round 5
// 858.938 us; speedup vs baseline: 2.4443x; 1.2230x over previous
//
#include <hip/hip_runtime.h>
#include <hip/hip_bf16.h>

#define EPSV 1e-5f

typedef _Float16 f16x2 __attribute__((ext_vector_type(2)));
typedef short bf16x8 __attribute__((ext_vector_type(8)));
typedef float f32x4 __attribute__((ext_vector_type(4)));

// ---------------- workspace layout (float offsets) ----------------
static constexpr long O_WHT = 1024;                  // scan Wh f16-pairs: 225000 uints
static constexpr long O_WTT = O_WHT + 225000;        // scan Wt f16-pairs: 135000 uints
static constexpr long O_W1NT= O_WTT + 135000;        // f32 [900][300] (g3b)
static constexpr long O_W1RT= O_W1NT + 270000;       // f32 [900][300]
static constexpr long O_XB  = O_W1RT + 270000;       // bf16 [800][768]
static constexpr long O_WIB = O_XB + 307200;         // bf16 [1500][768]
static constexpr long O_WNB = O_WIB + 576000;        // bf16 2x[300][600]
static constexpr long O_W1B = O_WNB + 180000;        // bf16 2x[300][912] (3x304 sub)
static constexpr long O_XG  = O_W1B + 273600;        // f32 [800][1500]
static constexpr long O_PUB = O_XG + 1200000;        // cs[8][1504], h[8][304], c[8][304], flags
static constexpr long O_HN2 = O_PUB + 19000;         // bf16 [800][320]
static constexpr long O_HR2 = O_HN2 + 128000;
static constexpr long O_HS2 = O_HR2 + 128000;
static constexpr long O_TG  = O_HS2 + 128000;        // f32 [2][800][300]
static constexpr long O_AU  = O_TG + 480000;         // f32 [2][800][300]
static constexpr long O_BU  = O_AU + 480000;
static constexpr long O_CU  = O_BU + 480000;         // f32 [2][8][300]
static constexpr long O_MASK= O_CU + 4800;           // [100][8]
static constexpr long O_BI  = O_MASK + 800;          // 1500
static constexpr long O_BH  = O_BI + 1504;           // 1500
static constexpr long O_BT  = O_BH + 1504;           // 300
static constexpr long O_BN  = O_BT + 304;
static constexpr long O_B1N = O_BN + 304;
static constexpr long O_GN  = O_B1N + 304;
static constexpr long O_BEN = O_GN + 304;
static constexpr long O_W2N = O_BEN + 304;           // [8][300]
static constexpr long O_B2N = O_W2N + 2400;          // 8
static constexpr long O_BR  = O_B2N + 16;
static constexpr long O_B1R = O_BR + 304;
static constexpr long O_GR  = O_B1R + 304;
static constexpr long O_BER = O_GR + 304;
static constexpr long O_W2R = O_BER + 304;           // [12][300]
static constexpr long O_B2R = O_W2R + 3600;          // 12
static constexpr long O_W2NT= O_B2R + 16;            // [300][8]
static constexpr long O_GBEN= O_W2NT + 2400;         // [300][2]
static constexpr long O_W2RT= O_GBEN + 608;          // [300][12]
static constexpr long O_GBER= O_W2RT + 3600;         // [300][2]
// end ~= 5,305,416 floats = 21.2 MB

__device__ __forceinline__ float ldin(const void* p, long i, int f32) {
  if (f32) return ((const float*)p)[i];
  unsigned int w = ((unsigned int)(((const unsigned short*)p)[i])) << 16;
  return __uint_as_float(w);
}
__device__ __forceinline__ unsigned short inbitsb(const void* p, long i, int f32) {
  if (!f32) return ((const unsigned short*)p)[i];
  __hip_bfloat16 hb = __float2bfloat16(((const float*)p)[i]);
  return *reinterpret_cast<unsigned short*>(&hb);
}
__device__ __forceinline__ unsigned short bfbits(float v) {
  __hip_bfloat16 hb = __float2bfloat16(v);
  return *reinterpret_cast<unsigned short*>(&hb);
}
__device__ __forceinline__ void stout(void* p, long i, float v, int f32) {
  if (f32) ((float*)p)[i] = v;
  else ((__hip_bfloat16*)p)[i] = __float2bfloat16(v);
}
__device__ __forceinline__ unsigned packf16(float a, float b) {
  union { _Float16 h[2]; unsigned u; } x;
  x.h[0] = (_Float16)a; x.h[1] = (_Float16)b;
  return x.u;
}
__device__ __forceinline__ float dot2(unsigned wu, unsigned xu, float acc) {
  return __builtin_amdgcn_fdot2(__builtin_bit_cast(f16x2, wu),
                                __builtin_bit_cast(f16x2, xu), acc, false);
}

// MALL-coherent cross-XCD transfer: relaxed agent atomics, no L2 flush
__device__ __forceinline__ void pubst(float* p, float v) {
  __hip_atomic_store(p, v, __ATOMIC_RELAXED, __HIP_MEMORY_SCOPE_AGENT);
}
__device__ __forceinline__ float publd(const float* p) {
  return __hip_atomic_load(p, __ATOMIC_RELAXED, __HIP_MEMORY_SCOPE_AGENT);
}
__device__ __forceinline__ void poll5(int* f, int target) {
  int it = 0;
  for (;;) {
    int a0 = __hip_atomic_load(f + 0, __ATOMIC_RELAXED, __HIP_MEMORY_SCOPE_AGENT);
    int a1 = __hip_atomic_load(f + 1, __ATOMIC_RELAXED, __HIP_MEMORY_SCOPE_AGENT);
    int a2 = __hip_atomic_load(f + 2, __ATOMIC_RELAXED, __HIP_MEMORY_SCOPE_AGENT);
    int a3 = __hip_atomic_load(f + 3, __ATOMIC_RELAXED, __HIP_MEMORY_SCOPE_AGENT);
    int a4 = __hip_atomic_load(f + 4, __ATOMIC_RELAXED, __HIP_MEMORY_SCOPE_AGENT);
    int m = min(min(min(a0, a1), min(a2, a3)), a4);
    if (m >= target || ++it > (1 << 20)) break;
  }
}

// ---------------- init: dtype flag + zero pub state/flags ----------------
__global__ void k_init(float* ws, const void* mask) {
  if (blockIdx.x == 0 && threadIdx.x == 0) {
    unsigned int u = *((const unsigned int*)mask);
    ((int*)ws)[0] = (u == 0x3F800000u) ? 1 : 0;     // f32 vs bf16 input
  }
  for (long i = blockIdx.x * 1024 + threadIdx.x; i < 5888; i += (long)gridDim.x * 1024)
    ws[O_PUB + 12032 + i] = 0.f;                    // h_pub, c_pub, flags
}

// ---------------- transpose f32 W1 (for g3b) ----------------
__global__ __launch_bounds__(256) void k_transpose(float* ws, const void* w0, const void* w1) {
  __shared__ float ts[32][33];
  const int m = blockIdx.y;
  const int R = 300, C = 900;
  const void* src = m ? w1 : w0;
  const long D = m ? O_W1RT : O_W1NT;
  const int f32 = ((const int*)ws)[0];
  const int tC = (C + 31) >> 5, tR = (R + 31) >> 5;
  const int tx = threadIdx.x & 31, ty = threadIdx.x >> 5;
  for (int tile = blockIdx.x; tile < tC * tR; tile += gridDim.x) {
    int tr = tile / tC, tc = tile - tr * tC;
    int r0 = tr * 32, c0 = tc * 32;
    __syncthreads();
#pragma unroll
    for (int k = 0; k < 4; k++) {
      int r = r0 + ty + 8 * k, c = c0 + tx;
      ts[ty + 8 * k][tx] = (r < R && c < C) ? ldin(src, (long)r * C + c, f32) : 0.f;
    }
    __syncthreads();
#pragma unroll
    for (int k = 0; k < 4; k++) {
      int c = c0 + ty + 8 * k, r = r0 + tx;
      if (c < C && r < R) ws[D + (long)c * R + r] = ts[tx][ty + 8 * k];
    }
  }
}

// ---------------- pack scan weights: per-thread-register f16-pair layout ----------------
__global__ __launch_bounds__(256) void k_pack(float* ws, const void* wh, const void* wt) {
  const int f32 = ((const int*)ws)[0];
  int q = blockIdx.x * 256 + threadIdx.x;
  if (q < 225000) {
    int g = q / 45000, r = q % 45000;
    int hh = r / 22500, r2 = r % 22500;
    int i = r2 / 450, t = r2 % 450;
    int o2 = t % 150, kc = t / 150;
    int row = g * 300 + 2 * o2 + hh;
    int k0 = 2 * (kc * 50 + i);
    float lo = ldin(wh, (long)row * 300 + k0, f32);
    float hi = ldin(wh, (long)row * 300 + k0 + 1, f32);
    ((unsigned*)(ws + O_WHT))[q] = packf16(lo, hi);
  } else if (q < 360000) {
    int q2 = q - 225000;
    int g = q2 / 27000, r = q2 % 27000;
    int hh = r / 13500, r2 = r % 13500;
    int j = r2 / 450, t = r2 % 450;
    int o2 = t % 30, kc = t / 30;
    int row = g * 60 + 2 * o2 + hh;
    int k0 = 2 * (kc * 30 + j);
    float lo = ldin(wt, (long)row * 900 + k0, f32);
    float hi = ldin(wt, (long)row * 900 + k0 + 1, f32);
    ((unsigned*)(ws + O_WTT))[q2] = packf16(lo, hi);
  }
}

// ---------------- bf16 operand copies for MFMA stages ----------------
__global__ void k_cvt(float* ws, const void* x, const void* wi,
                      const void* wn, const void* wr, const void* w1n, const void* w1r) {
  const int f32 = ((const int*)ws)[0];
  unsigned short* XB = (unsigned short*)(ws + O_XB);
  unsigned short* WIB = (unsigned short*)(ws + O_WIB);
  unsigned short* WNB = (unsigned short*)(ws + O_WNB);
  unsigned short* W1B = (unsigned short*)(ws + O_W1B);
  long i = (long)blockIdx.x * blockDim.x + threadIdx.x;
  long stride = (long)gridDim.x * blockDim.x;
  for (; i < 2673600; i += stride) {
    long idx = i;
    if (idx < 614400) { XB[idx] = inbitsb(x, idx, f32); continue; }
    idx -= 614400;
    if (idx < 1152000) { WIB[idx] = inbitsb(wi, idx, f32); continue; }
    idx -= 1152000;
    if (idx < 360000) {
      int u = idx / 180000, r = idx % 180000;
      WNB[idx] = inbitsb(u ? wr : wn, r, f32);
      continue;
    }
    idx -= 360000;   // W1B: 2 x [300][912], sub-blocks of 304 per projection
    int u = idx / 273600, r = idx % 273600;
    int n = r / 912, kk = r % 912;
    int p = kk / 304, k = kk - p * 304;
    unsigned short v = 0;
    if (k < 300) v = inbitsb(u ? w1r : w1n, (long)n * 900 + p * 300 + k, f32);
    W1B[idx] = v;
  }
}

// ---------------- copy mask / biases / tiny transposes to f32 ----------------
__global__ void k_misc(float* ws, const void* mask,
    const void* bi, const void* bh, const void* bt,
    const void* bn, const void* b1n, const void* gn, const void* ben,
    const void* w2n, const void* b2n,
    const void* br, const void* b1r, const void* gr, const void* ber,
    const void* w2r, const void* b2r) {
  const int f32 = ((const int*)ws)[0];
  long i = (long)blockIdx.x * blockDim.x + threadIdx.x;
  long stride = (long)gridDim.x * blockDim.x;
  for (; i < 19720; i += stride) {
    long idx = i; const void* s; long d; float v;
    if (idx < 800)                   { s = mask; d = O_MASK; }
    else if ((idx -= 800) < 1500)    { s = bi;  d = O_BI; }
    else if ((idx -= 1500) < 1500)   { s = bh;  d = O_BH; }
    else if ((idx -= 1500) < 300)    { s = bt;  d = O_BT; }
    else if ((idx -= 300) < 300)     { s = bn;  d = O_BN; }
    else if ((idx -= 300) < 300)     { s = b1n; d = O_B1N; }
    else if ((idx -= 300) < 300)     { s = gn;  d = O_GN; }
    else if ((idx -= 300) < 300)     { s = ben; d = O_BEN; }
    else if ((idx -= 300) < 2400)    { s = w2n; d = O_W2N; }
    else if ((idx -= 2400) < 8)      { s = b2n; d = O_B2N; }
    else if ((idx -= 8) < 300)       { s = br;  d = O_BR; }
    else if ((idx -= 300) < 300)     { s = b1r; d = O_B1R; }
    else if ((idx -= 300) < 300)     { s = gr;  d = O_GR; }
    else if ((idx -= 300) < 300)     { s = ber; d = O_BER; }
    else if ((idx -= 300) < 3600)    { s = w2r; d = O_W2R; }
    else if ((idx -= 3600) < 12)     { s = b2r; d = O_B2R; }
    else if ((idx -= 12) < 2400) {   // W2NT [300][8]
      int o = idx >> 3, q = idx & 7;
      ws[O_W2NT + idx] = ldin(w2n, (long)q * 300 + o, f32);
      continue;
    }
    else if ((idx -= 2400) < 600) {  // GBEN [300][2]
      int o = idx >> 1;
      ws[O_GBEN + idx] = ldin((idx & 1) ? ben : gn, o, f32);
      continue;
    }
    else if ((idx -= 600) < 3600) {  // W2RT [300][12]
      int o = idx / 12, q = idx % 12;
      ws[O_W2RT + idx] = ldin(w2r, (long)q * 300 + o, f32);
      continue;
    }
    else {                           // GBER [300][2]
      idx -= 3600;
      int o = idx >> 1;
      ws[O_GBER + idx] = ldin((idx & 1) ? ber : gr, o, f32);
      continue;
    }
    v = ldin(s, idx, f32);
    ws[d + idx] = v;
  }
}

// ---------------- xg = x @ WiT + bi via MFMA: [800][1500] ----------------
__global__ __launch_bounds__(256) void k_xg(float* ws) {
  const unsigned short* X = (const unsigned short*)(ws + O_XB);
  const unsigned short* W = (const unsigned short*)(ws + O_WIB);
  const int m0 = blockIdx.x * 16;
  const int w = threadIdx.x >> 6, lane = threadIdx.x & 63;
  const int n0 = blockIdx.y * 256 + w * 64;
  const int rA = lane & 15, kq = (lane >> 4) * 8;
  const unsigned short* ax = X + (long)(m0 + rA) * 768 + kq;
  const unsigned short* bx = W + (long)(n0 + rA) * 768 + kq;
  f32x4 acc[4] = {};
  for (int kt = 0; kt < 24; ++kt) {
    bf16x8 af = *(const bf16x8*)(ax + kt * 32);
#pragma unroll
    for (int nf = 0; nf < 4; ++nf) {
      bf16x8 bf = *(const bf16x8*)(bx + (long)nf * 16 * 768 + kt * 32);
      acc[nf] = __builtin_amdgcn_mfma_f32_16x16x32_bf16(af, bf, acc[nf], 0, 0, 0);
    }
  }
  const int rD = m0 + (lane >> 4) * 4, cD = lane & 15;
#pragma unroll
  for (int nf = 0; nf < 4; ++nf) {
    int col = n0 + nf * 16 + cD;
    if (col < 1500) {
      float bv = ws[O_BI + col];
#pragma unroll
      for (int q = 0; q < 4; ++q)
        ws[O_XG + (long)(rD + q) * 1500 + col] = acc[nf][q] + bv;
    }
  }
}

// ---------------- the recurrent scan: 40 WGs = (batch, group), weights in VGPRs ----------------
__global__ __launch_bounds__(512, 2) void k_scan(float* ws) {
  const int w = blockIdx.x;            // 40
  const int b = w & 7, g = w >> 3;     // batch, gate-group/output-slice
  const int t = threadIdx.x;
  const int lane = t & 63, wid = t >> 6;
  const unsigned* W1 = (const unsigned*)(ws + O_WHT) + g * 45000;
  const unsigned* W2 = (const unsigned*)(ws + O_WTT) + g * 27000;
  const float* xg = ws + O_XG;
  const float* bhp = ws + O_BH;
  const float* btp = ws + O_BT;
  float* cs_pub = ws + O_PUB + (long)b * 1504;
  float* h_pub  = ws + O_PUB + 12032 + (long)b * 304;
  float* c_pub  = ws + O_PUB + 14464 + (long)b * 304;
  int* flagA = (int*)(ws + O_PUB + 16896) + b * 16;
  int* flagB = (int*)(ws + O_PUB + 16896) + 512 + b * 16;
  unsigned short* HN2 = (unsigned short*)(ws + O_HN2);
  unsigned short* HR2 = (unsigned short*)(ws + O_HR2);
  unsigned short* HS2 = (unsigned short*)(ws + O_HS2);

  // persistent weights in registers (f16 pairs along k)
  unsigned wA0[50], wA1[50], wB0[30], wB1[30];
  if (t < 450) {
#pragma unroll
    for (int i = 0; i < 50; ++i) { wA0[i] = W1[i * 450 + t]; wA1[i] = W1[22500 + i * 450 + t]; }
#pragma unroll
    for (int j = 0; j < 30; ++j) { wB0[j] = W2[j * 450 + t]; wB1[j] = W2[13500 + j * 450 + t]; }
  }

  __shared__ __align__(16) unsigned h2[152];     // h as f16 pairs
  __shared__ __align__(16) float cf[304];        // c(l-1) f32
  __shared__ __align__(16) float gatef[304];
  __shared__ __align__(16) float pacc[3][304];
  __shared__ __align__(16) float csL[1504];
  __shared__ __align__(16) float catf[912];
  __shared__ __align__(16) unsigned cat2[456];
  __shared__ __align__(16) float pacc2[15][64];

  const int o2a = t % 150, kca = t / 150;        // phase-A tile
  const int o2b = t % 30,  kcb = t / 30;         // phase-B tile

  for (int l = 0; l < 100; ++l) {
    // ---- wait h,c from step l-1; gather ----
    if (t == 64) poll5(flagB, l);
    __syncthreads();
    if (t < 150) {
      float e = publd(h_pub + 2 * t), o = publd(h_pub + 2 * t + 1);
      h2[t] = packf16(e, o);
    } else if (t < 450) {
      cf[t - 150] = publd(c_pub + (t - 150));
    }
    __syncthreads();
    // ---- phase A: gate slice = Wh_g@h + xg + bh; cumsoftmax; publish cs ----
    if (t < 450) {
      float a0 = 0.f, a1 = 0.f;
      const unsigned* hp = h2 + kca * 50;
#pragma unroll
      for (int i = 0; i < 50; ++i) {
        unsigned hv = hp[i];
        a0 = dot2(wA0[i], hv, a0);
        a1 = dot2(wA1[i], hv, a1);
      }
      pacc[kca][2 * o2a] = a0; pacc[kca][2 * o2a + 1] = a1;
    }
    __syncthreads();
    if (t < 300)
      gatef[t] = pacc[0][t] + pacc[1][t] + pacc[2][t]
               + xg[((long)l * 8 + b) * 1500 + g * 300 + t] + bhp[g * 300 + t];
    __syncthreads();
    if (g == 0) {
      if (t < 300) pubst(cs_pub + t, tanhf(gatef[t]));
    } else if (wid == 0) {
      const int base = lane * 5;
      float e0 = 0.f, e1 = 0.f, e2 = 0.f, e3 = 0.f, e4 = 0.f, m = -3.0e38f;
      if (lane < 60) {
        e0 = gatef[base]; e1 = gatef[base + 1]; e2 = gatef[base + 2];
        e3 = gatef[base + 3]; e4 = gatef[base + 4];
        m = fmaxf(fmaxf(fmaxf(e0, e1), fmaxf(e2, e3)), e4);
      }
#pragma unroll
      for (int of = 32; of >= 1; of >>= 1) m = fmaxf(m, __shfl_xor(m, of, 64));
      float s0 = 0.f, s1 = 0.f, s2 = 0.f, s3 = 0.f, s4 = 0.f, tot = 0.f;
      if (lane < 60) {
        e0 = __expf(e0 - m); e1 = __expf(e1 - m); e2 = __expf(e2 - m);
        e3 = __expf(e3 - m); e4 = __expf(e4 - m);
        s0 = e0; s1 = s0 + e1; s2 = s1 + e2; s3 = s2 + e3; s4 = s3 + e4;
        tot = s4;
      }
      float sc = tot;
#pragma unroll
      for (int of = 1; of < 64; of <<= 1) {
        float u = __shfl_up(sc, of, 64);
        if (lane >= of) sc += u;
      }
      float total = __shfl(sc, 63);
      if (lane < 60) {
        float ex = sc - tot, inv = 1.f / total;
        pubst(cs_pub + g * 300 + base + 0, (ex + s0) * inv);
        pubst(cs_pub + g * 300 + base + 1, (ex + s1) * inv);
        pubst(cs_pub + g * 300 + base + 2, (ex + s2) * inv);
        pubst(cs_pub + g * 300 + base + 3, (ex + s3) * inv);
        pubst(cs_pub + g * 300 + base + 4, (ex + s4) * inv);
      }
    }
    asm volatile("s_waitcnt vmcnt(0)" ::: "memory");
    __syncthreads();
    if (t == 0) __hip_atomic_store(flagA + g, l + 1, __ATOMIC_RELAXED, __HIP_MEMORY_SCOPE_AGENT);
    if (t == 64) poll5(flagA, l + 1);
    __syncthreads();

    // ---- phase B: gather cs; combine -> cat; h-slice = Wt_rows@cat; publish h,c ----
    for (int i = t; i < 1500; i += 512) csL[i] = publd(cs_pub + i);
    __syncthreads();
    if (t < 300) {
      float cgv = csL[t];
      float egi = 1.f - csL[300 + t];
      float rgi = csL[600 + t];
      float egc = 1.f - csL[900 + t];
      float rgc = csL[1200 + t];
      float cin = cf[t];
      float ovc = rgc * egc, upc = rgc - ovc, dnc = egc - ovc;
      float ovi = rgi * egi, upi = rgi - ovi, dni = egi - ovi;
      float sh = ovi * cin + ovc * cgv;
      float cre = upi * cin + upc * cgv + sh;
      float cner = dni * cin + dnc * cgv + sh;
      catf[t] = cre; catf[300 + t] = cner; catf[600 + t] = sh;
      if (g == 0) {
        long rb = ((long)l * 8 + b) * 320;
        HN2[rb + t] = bfbits(tanhf(cner));
        HR2[rb + t] = bfbits(tanhf(cre));
        HS2[rb + t] = bfbits(tanhf(sh));
      }
    } else if (g == 0 && t < 320) {
      long rb = ((long)l * 8 + b) * 320;
      HN2[rb + t] = 0; HR2[rb + t] = 0; HS2[rb + t] = 0;
    }
    __syncthreads();
    if (t < 450) cat2[t] = packf16(catf[2 * t], catf[2 * t + 1]);
    __syncthreads();
    if (t < 450) {
      float a0 = 0.f, a1 = 0.f;
      const unsigned* cp = cat2 + kcb * 30;
#pragma unroll
      for (int j = 0; j < 30; ++j) {
        unsigned cv = cp[j];
        a0 = dot2(wB0[j], cv, a0);
        a1 = dot2(wB1[j], cv, a1);
      }
      pacc2[kcb][2 * o2b] = a0; pacc2[kcb][2 * o2b + 1] = a1;
    }
    __syncthreads();
    if (t < 60) {
      float s = btp[g * 60 + t];
#pragma unroll
      for (int kc = 0; kc < 15; ++kc) s += pacc2[kc][t];
      pubst(h_pub + g * 60 + t, tanhf(s));
      pubst(c_pub + g * 60 + t, s);
    }
    asm volatile("s_waitcnt vmcnt(0)" ::: "memory");
    __syncthreads();
    if (t == 0) __hip_atomic_store(flagB + g, l + 1, __ATOMIC_RELAXED, __HIP_MEMORY_SCOPE_AGENT);
  }
}

// ---------------- pooled units via MFMA: tG = tanh(cat(h_share,h_x)@WT + b) ----------------
__global__ __launch_bounds__(256) void k_g3a(float* ws, void* dout) {
  const int u = blockIdx.z;
  const int m0 = blockIdx.x * 16;
  const int w = threadIdx.x >> 6, lane = threadIdx.x & 63;
  const int n0 = blockIdx.y * 256 + w * 64;
  if (n0 >= 300) return;
  const int f32 = ((const int*)ws)[0];
  const unsigned short* A0 = (const unsigned short*)(ws + O_HS2);
  const unsigned short* A1 = (const unsigned short*)(ws + (u ? O_HR2 : O_HN2));
  const unsigned short* B = (const unsigned short*)(ws + O_WNB) + (long)u * 180000;
  const int rA = lane & 15, kq = (lane >> 4) * 8;
  const unsigned short* a0p = A0 + (long)(m0 + rA) * 320 + kq;
  const unsigned short* a1p = A1 + (long)(m0 + rA) * 320 + kq;
  const unsigned short* bp = B + (long)(n0 + rA) * 600 + kq;
  f32x4 acc[4] = {};
  for (int kt = 0; kt < 10; ++kt) {
    bf16x8 af = *(const bf16x8*)(a0p + kt * 32);
#pragma unroll
    for (int nf = 0; nf < 4; ++nf) {
      bf16x8 bf = *(const bf16x8*)(bp + (long)nf * 16 * 600 + kt * 32);
      acc[nf] = __builtin_amdgcn_mfma_f32_16x16x32_bf16(af, bf, acc[nf], 0, 0, 0);
    }
  }
  for (int kt = 0; kt < 10; ++kt) {
    bf16x8 af = *(const bf16x8*)(a1p + kt * 32);
#pragma unroll
    for (int nf = 0; nf < 4; ++nf) {
      bf16x8 bf = *(const bf16x8*)(bp + (long)nf * 16 * 600 + 300 + kt * 32);
      acc[nf] = __builtin_amdgcn_mfma_f32_16x16x32_bf16(af, bf, acc[nf], 0, 0, 0);
    }
  }
  const int rD = m0 + (lane >> 4) * 4, cD = lane & 15;
#pragma unroll
  for (int nf = 0; nf < 4; ++nf) {
    int col = n0 + nf * 16 + cD;
    if (col < 300) {
      float bv = ws[(u ? O_BR : O_BN) + col];
#pragma unroll
      for (int q = 0; q < 4; ++q) {
        float tv = tanhf(acc[nf][q] + bv);
        long idx = (long)(rD + q) * 300 + col;
        ws[O_TG + (long)u * 240000 + idx] = tv;
        if (u == 1) stout(dout, 1600000L + idx, tv, f32);
      }
    }
  }
}

// ---------------- start/end token projections a,b via MFMA ----------------
__global__ __launch_bounds__(256) void k_g3c(float* ws) {
  const int u = blockIdx.z >> 1, proj = blockIdx.z & 1;
  const int m0 = blockIdx.x * 16;
  const int w = threadIdx.x >> 6, lane = threadIdx.x & 63;
  const int n0 = blockIdx.y * 256 + w * 64;
  if (n0 >= 300) return;
  const unsigned short* A = (const unsigned short*)(ws + (u ? O_HR2 : O_HN2));
  const unsigned short* B = (const unsigned short*)(ws + O_W1B) + (long)u * 273600;
  const int rA = lane & 15, kq = (lane >> 4) * 8;
  const unsigned short* ap = A + (long)(m0 + rA) * 320 + kq;
  const unsigned short* bp = B + (long)(n0 + rA) * 912 + proj * 304 + kq;
  f32x4 acc[4] = {};
  for (int kt = 0; kt < 10; ++kt) {
    bf16x8 af = *(const bf16x8*)(ap + kt * 32);
#pragma unroll
    for (int nf = 0; nf < 4; ++nf) {
      bf16x8 bf = *(const bf16x8*)(bp + (long)nf * 16 * 912 + kt * 32);
      acc[nf] = __builtin_amdgcn_mfma_f32_16x16x32_bf16(af, bf, acc[nf], 0, 0, 0);
    }
  }
  const int rD = m0 + (lane >> 4) * 4, cD = lane & 15;
  const long dst = (proj ? O_BU : O_AU) + (long)u * 240000;
#pragma unroll
  for (int nf = 0; nf < 4; ++nf) {
    int col = n0 + nf * 16 + cD;
    if (col < 300) {
#pragma unroll
      for (int q = 0; q < 4; ++q)
        ws[dst + (long)(rD + q) * 300 + col] = acc[nf][q];
    }
  }
}

// ---------------- max over L + global projection c ----------------
__global__ __launch_bounds__(320) void k_g3b(float* ws) {
  const int u = blockIdx.x >> 3, b = blockIdx.x & 7;
  __shared__ float hs[304];
  const int o = threadIdx.x;
  const float* tg = ws + O_TG + (long)u * 240000;
  if (o < 300) {
    float m = -3e38f;
    for (int l = 0; l < 100; ++l) m = fmaxf(m, tg[((long)l * 8 + b) * 300 + o]);
    hs[o] = m;
  }
  __syncthreads();
  if (o < 300) {
    const float* w1 = ws + (u ? O_W1RT : O_W1NT);
    float acc = ws[(u ? O_B1R : O_B1N) + o];
    for (int k = 0; k < 300; ++k) acc += hs[k] * w1[(long)(600 + k) * 300 + o];
    ws[O_CU + (long)u * 2400 + b * 300 + o] = acc;
  }
}

// ---------------- fused pair scoring: lane-per-pair LN -> elu -> @W2 -> sigmoid*mask ----------------
template <int NOUT, bool TRI>
__global__ __launch_bounds__(512) void k_pairs(float* ws, void* dout, long obase,
    long uofs, long w2tofs, long b2ofs, long gbeofs, long cofs) {
  const int i0 = blockIdx.x * 16, j0 = blockIdx.y * 32, b = blockIdx.z;
  const int f32 = ((const int*)ws)[0];
  __shared__ float aS[16 * 305];
  __shared__ float bS[32 * 305];
  __shared__ float miS[16], mjS[32];
  const int t = threadIdx.x;
  for (int s = t; s < 16 * 300; s += 512) {
    int r = s / 300, o = s - r * 300;
    int i = i0 + r;
    float v = 0.f;
    if (i < 100) v = ws[O_AU + uofs + ((long)i * 8 + b) * 300 + o] + ws[cofs + b * 300 + o];
    aS[r * 305 + o] = v;
  }
  for (int s = t; s < 32 * 300; s += 512) {
    int r = s / 300, o = s - r * 300;
    int j = j0 + r;
    bS[r * 305 + o] = (j < 100) ? ws[O_BU + uofs + ((long)j * 8 + b) * 300 + o] : 0.f;
  }
  if (t < 16) miS[t] = (i0 + t < 100) ? ws[O_MASK + (i0 + t) * 8 + b] : 0.f;
  else if (t < 48) mjS[t - 16] = (j0 + t - 16 < 100) ? ws[O_MASK + (j0 + t - 16) * 8 + b] : 0.f;
  __syncthreads();
  const int wid = t >> 6, lane = t & 63;
  const int ii = wid * 2 + (lane >> 5);
  const int jj = lane & 31;
  const int i = i0 + ii, j = j0 + jj;
  if (i >= 100 || j >= 100) return;
  long base = obase + (((long)i * 100 + j) * 8 + b) * NOUT;
  // whole-wave lower-triangle skip (all 64 pair-slots have j < i)
  if (TRI && (j0 + 31 < i0 + wid * 2)) {
#pragma unroll
    for (int q = 0; q < NOUT; ++q) stout(dout, base + q, 0.f, f32);
    return;
  }
  const float* ap = aS + ii * 305;
  const float* bp = bS + jj * 305;
  float sum = 0.f, ssq = 0.f;
#pragma unroll 4
  for (int o = 0; o < 300; ++o) {
    float v = ap[o] + bp[o];
    sum += v;
    ssq = fmaf(v, v, ssq);
  }
  float mean = sum * (1.f / 300.f);
  float inv = rsqrtf(ssq * (1.f / 300.f) - mean * mean + EPSV);
  float acc[NOUT];
#pragma unroll
  for (int q = 0; q < NOUT; ++q) acc[q] = 0.f;
  const float* gbe = ws + gbeofs;
  const float* w2t = ws + w2tofs;
#pragma unroll 2
  for (int o = 0; o < 300; ++o) {
    float v = ap[o] + bp[o];
    float xn = fmaf((v - mean) * inv, gbe[2 * o], gbe[2 * o + 1]);
    float e = xn > 0.f ? xn : (__expf(xn) - 1.f);
#pragma unroll
    for (int q = 0; q < NOUT; ++q) acc[q] = fmaf(e, w2t[o * NOUT + q], acc[q]);
  }
  float mv = miS[ii] * mjS[jj];
  if (TRI && j < i) mv = 0.f;
#pragma unroll
  for (int q = 0; q < NOUT; ++q) {
    float b2v = ws[b2ofs + q];
    stout(dout, base + q, mv / (1.f + __expf(-(acc[q] + b2v))), f32);
  }
}

// ---------------- host ----------------
extern "C" void kernel_launch(void* const* d_in, const int* in_sizes, int n_in,
                              void* d_out, int out_size, void* d_ws, size_t ws_size,
                              hipStream_t stream) {
  (void)in_sizes; (void)n_in; (void)out_size; (void)ws_size;
  float* ws = (float*)d_ws;
  k_init<<<dim3(8), dim3(1024), 0, stream>>>(ws, d_in[1]);
  k_cvt<<<dim3(2048), dim3(256), 0, stream>>>(ws,
      d_in[0], d_in[2], d_in[8], d_in[16], d_in[10], d_in[18]);
  k_transpose<<<dim3(128, 2), dim3(256), 0, stream>>>(ws, d_in[10], d_in[18]);
  k_pack<<<dim3(1407), dim3(256), 0, stream>>>(ws, d_in[4], d_in[6]);
  k_misc<<<dim3(80), dim3(256), 0, stream>>>(ws,
      d_in[1], d_in[3], d_in[5], d_in[7],
      d_in[9], d_in[11], d_in[12], d_in[13], d_in[14], d_in[15],
      d_in[17], d_in[19], d_in[20], d_in[21], d_in[22], d_in[23]);
  k_xg<<<dim3(50, 6), dim3(256), 0, stream>>>(ws);
  k_scan<<<dim3(40), dim3(512), 0, stream>>>(ws);
  k_g3a<<<dim3(50, 2, 2), dim3(256), 0, stream>>>(ws, d_out);
  k_g3c<<<dim3(50, 2, 4), dim3(256), 0, stream>>>(ws);
  k_g3b<<<dim3(16), dim3(320), 0, stream>>>(ws);
  k_pairs<8, true><<<dim3(7, 4, 8), dim3(512), 0, stream>>>(ws, d_out,
      0L, 0L, O_W2NT, O_B2N, O_GBEN, O_CU);
  k_pairs<12, false><<<dim3(7, 4, 8), dim3(512), 0, stream>>>(ws, d_out,
      640000L, 240000L, O_W2RT, O_B2R, O_GBER, O_CU + 2400);
}

// Round 7
// 737.366 us; speedup vs baseline: 2.8473x; 1.1649x over previous
//
#include <hip/hip_runtime.h>
#include <hip/hip_bf16.h>

#define EPSV 1e-5f

typedef _Float16 f16x2 __attribute__((ext_vector_type(2)));
typedef short bf16x8 __attribute__((ext_vector_type(8)));
typedef float f32x4 __attribute__((ext_vector_type(4)));

// ---------------- workspace layout (float offsets) ----------------
static constexpr long O_WHT = 1024;                  // scan Wh f16-pairs: 225000 uints
static constexpr long O_WTT = O_WHT + 225000;        // scan Wt f16-pairs: 135000 uints
static constexpr long O_W1NT= O_WTT + 135000;        // f32 [900][300] (g3b)
static constexpr long O_W1RT= O_W1NT + 270000;       // f32 [900][300]
static constexpr long O_XB  = O_W1RT + 270000;       // bf16 [800][768] (f32 fallback only)
static constexpr long O_WIB = O_XB + 307200;         // bf16 [1500][768] (f32 fallback only)
static constexpr long O_WNB = O_WIB + 576000;        // bf16 2x[300][600]
static constexpr long O_W1B = O_WNB + 180000;        // bf16 2x[300][912] (3x304 sub)
static constexpr long O_XG  = O_W1B + 273600;        // f32 [800][1500]
static constexpr long O_PUB = O_XG + 1200000;        // cs[8][1504], h[8][304], c[8][304], flags
static constexpr long O_HN2 = O_PUB + 19000;         // bf16 [800][320]
static constexpr long O_HR2 = O_HN2 + 128000;
static constexpr long O_HS2 = O_HR2 + 128000;
static constexpr long O_TG  = O_HS2 + 128000;        // f32 [2][800][300]
static constexpr long O_AU  = O_TG + 480000;         // f32 [2][800][300]
static constexpr long O_BU  = O_AU + 480000;
static constexpr long O_CU  = O_BU + 480000;         // f32 [2][8][300]
static constexpr long O_MASK= O_CU + 4800;           // [100][8]
static constexpr long O_BI  = O_MASK + 800;          // 1500
static constexpr long O_BH  = O_BI + 1504;           // 1500
static constexpr long O_BT  = O_BH + 1504;           // 300
static constexpr long O_BN  = O_BT + 304;
static constexpr long O_B1N = O_BN + 304;
static constexpr long O_GN  = O_B1N + 304;
static constexpr long O_BEN = O_GN + 304;
static constexpr long O_W2N = O_BEN + 304;           // [8][300]
static constexpr long O_B2N = O_W2N + 2400;          // 8
static constexpr long O_BR  = O_B2N + 16;
static constexpr long O_B1R = O_BR + 304;
static constexpr long O_GR  = O_B1R + 304;
static constexpr long O_BER = O_GR + 304;
static constexpr long O_W2R = O_BER + 304;           // [12][300]
static constexpr long O_B2R = O_W2R + 3600;          // 12
static constexpr long O_W2NT= O_B2R + 16;            // [300][8]
static constexpr long O_GBEN= O_W2NT + 2400;         // [300][2]
static constexpr long O_W2RT= O_GBEN + 608;          // [300][12]
static constexpr long O_GBER= O_W2RT + 3600;         // [300][2]

__device__ __forceinline__ int is_f32(const void* mask) {
  return *((const unsigned*)mask) == 0x3F800000u;    // f32 1.0f vs bf16 {1,1}=0x3F803F80
}
__device__ __forceinline__ float ldin(const void* p, long i, int f32) {
  if (f32) return ((const float*)p)[i];
  unsigned int w = ((unsigned int)(((const unsigned short*)p)[i])) << 16;
  return __uint_as_float(w);
}
__device__ __forceinline__ unsigned short inbitsb(const void* p, long i, int f32) {
  if (!f32) return ((const unsigned short*)p)[i];
  __hip_bfloat16 hb = __float2bfloat16(((const float*)p)[i]);
  return *reinterpret_cast<unsigned short*>(&hb);
}
__device__ __forceinline__ unsigned short bfbits(float v) {
  __hip_bfloat16 hb = __float2bfloat16(v);
  return *reinterpret_cast<unsigned short*>(&hb);
}
__device__ __forceinline__ void stout(void* p, long i, float v, int f32) {
  if (f32) ((float*)p)[i] = v;
  else ((__hip_bfloat16*)p)[i] = __float2bfloat16(v);
}
__device__ __forceinline__ unsigned packf16(float a, float b) {
  union { _Float16 h[2]; unsigned u; } x;
  x.h[0] = (_Float16)a; x.h[1] = (_Float16)b;
  return x.u;
}
__device__ __forceinline__ float dot2(unsigned wu, unsigned xu, float acc) {
  return __builtin_amdgcn_fdot2(__builtin_bit_cast(f16x2, wu),
                                __builtin_bit_cast(f16x2, xu), acc, false);
}

// MALL-coherent cross-XCD transfer: relaxed agent atomics, no L2 flush (proven R5 path)
__device__ __forceinline__ void pubst(float* p, float v) {
  __hip_atomic_store(p, v, __ATOMIC_RELAXED, __HIP_MEMORY_SCOPE_AGENT);
}
__device__ __forceinline__ float publd(const float* p) {
  return __hip_atomic_load(p, __ATOMIC_RELAXED, __HIP_MEMORY_SCOPE_AGENT);
}
__device__ __forceinline__ void poll5(int* f, int target) {
  long it = 0;
  for (;;) {
    int a0 = __hip_atomic_load(f + 0, __ATOMIC_RELAXED, __HIP_MEMORY_SCOPE_AGENT);
    int a1 = __hip_atomic_load(f + 1, __ATOMIC_RELAXED, __HIP_MEMORY_SCOPE_AGENT);
    int a2 = __hip_atomic_load(f + 2, __ATOMIC_RELAXED, __HIP_MEMORY_SCOPE_AGENT);
    int a3 = __hip_atomic_load(f + 3, __ATOMIC_RELAXED, __HIP_MEMORY_SCOPE_AGENT);
    int a4 = __hip_atomic_load(f + 4, __ATOMIC_RELAXED, __HIP_MEMORY_SCOPE_AGENT);
    int m = min(min(min(a0, a1), min(a2, a3)), a4);
    if (m >= target || ++it > (1L << 22)) break;
  }
}

// ---------------- one prep kernel: pack + transpose + misc + cvt (blockIdx ranges) ----------------
__global__ __launch_bounds__(256) void k_prep(float* ws, const void* mask,
    const void* x, const void* wi, const void* wh, const void* wt,
    const void* wn, const void* wr, const void* w1n, const void* w1r,
    const void* bi, const void* bh, const void* bt,
    const void* bn, const void* b1n, const void* gn, const void* ben,
    const void* w2n, const void* b2n, const void* br, const void* b1r,
    const void* gr, const void* ber, const void* w2r, const void* b2r) {
  const int f32 = is_f32(mask);
  const int blk = blockIdx.x, t = threadIdx.x;

  if (blk < 1407) {                       // ---- scan-weight f16-pair pack ----
    int q = blk * 256 + t;
    if (q < 225000) {
      int g = q / 45000, r = q % 45000;
      int hh = r / 22500, r2 = r % 22500;
      int i = r2 / 450, tt = r2 % 450;
      int o2 = tt % 150, kc = tt / 150;
      int row = g * 300 + 2 * o2 + hh;
      int k0 = 2 * (kc * 50 + i);
      float lo = ldin(wh, (long)row * 300 + k0, f32);
      float hi = ldin(wh, (long)row * 300 + k0 + 1, f32);
      ((unsigned*)(ws + O_WHT))[q] = packf16(lo, hi);
    } else if (q < 360000) {
      int q2 = q - 225000;
      int g = q2 / 27000, r = q2 % 27000;
      int hh = r / 13500, r2 = r % 13500;
      int j = r2 / 450, tt = r2 % 450;
      int o2 = tt % 30, kc = tt / 30;
      int row = g * 60 + 2 * o2 + hh;
      int k0 = 2 * (kc * 30 + j);
      float lo = ldin(wt, (long)row * 900 + k0, f32);
      float hi = ldin(wt, (long)row * 900 + k0 + 1, f32);
      ((unsigned*)(ws + O_WTT))[q2] = packf16(lo, hi);
    }
    return;
  }
  if (blk < 1987) {                       // ---- W1 f32 transposes (580 tiles) ----
    __shared__ float ts[32][33];
    int tile = blk - 1407;
    int m = tile >= 290; int ti = tile - m * 290;
    const void* src = m ? w1r : w1n;
    const long D = m ? O_W1RT : O_W1NT;
    const int R = 300, C = 900;
    int tr = ti / 29, tc = ti % 29;
    int r0 = tr * 32, c0 = tc * 32;
    const int tx = t & 31, ty = t >> 5;
#pragma unroll
    for (int k = 0; k < 4; k++) {
      int r = r0 + ty + 8 * k, c = c0 + tx;
      ts[ty + 8 * k][tx] = (r < R && c < C) ? ldin(src, (long)r * C + c, f32) : 0.f;
    }
    __syncthreads();
#pragma unroll
    for (int k = 0; k < 4; k++) {
      int c = c0 + ty + 8 * k, r = r0 + tx;
      if (c < C && r < R) ws[D + (long)c * R + r] = ts[tx][ty + 8 * k];
    }
    return;
  }
  if (blk < 2088) {                       // ---- misc biases/transposes + PUB zero ----
    long i = (long)(blk - 1987) * 256 + t;
    if (i >= 25608) return;
    if (i >= 19720) { ws[O_PUB + 12032 + (i - 19720)] = 0.f; return; }
    long idx = i; const void* s; long d; float v;
    if (idx < 800)                   { s = mask; d = O_MASK; }
    else if ((idx -= 800) < 1500)    { s = bi;  d = O_BI; }
    else if ((idx -= 1500) < 1500)   { s = bh;  d = O_BH; }
    else if ((idx -= 1500) < 300)    { s = bt;  d = O_BT; }
    else if ((idx -= 300) < 300)     { s = bn;  d = O_BN; }
    else if ((idx -= 300) < 300)     { s = b1n; d = O_B1N; }
    else if ((idx -= 300) < 300)     { s = gn;  d = O_GN; }
    else if ((idx -= 300) < 300)     { s = ben; d = O_BEN; }
    else if ((idx -= 300) < 2400)    { s = w2n; d = O_W2N; }
    else if ((idx -= 2400) < 8)      { s = b2n; d = O_B2N; }
    else if ((idx -= 8) < 300)       { s = br;  d = O_BR; }
    else if ((idx -= 300) < 300)     { s = b1r; d = O_B1R; }
    else if ((idx -= 300) < 300)     { s = gr;  d = O_GR; }
    else if ((idx -= 300) < 300)     { s = ber; d = O_BER; }
    else if ((idx -= 300) < 3600)    { s = w2r; d = O_W2R; }
    else if ((idx -= 3600) < 12)     { s = b2r; d = O_B2R; }
    else if ((idx -= 12) < 2400) {   // W2NT [300][8]
      int o = idx >> 3, q = idx & 7;
      ws[O_W2NT + idx] = ldin(w2n, (long)q * 300 + o, f32);
      return;
    }
    else if ((idx -= 2400) < 600) {  // GBEN [300][2]
      int o = idx >> 1;
      ws[O_GBEN + idx] = ldin((idx & 1) ? ben : gn, o, f32);
      return;
    }
    else if ((idx -= 600) < 3600) {  // W2RT [300][12]
      int o = idx / 12, q = idx % 12;
      ws[O_W2RT + idx] = ldin(w2r, (long)q * 300 + o, f32);
      return;
    }
    else {                           // GBER [300][2]
      idx -= 3600;
      int o = idx >> 1;
      ws[O_GBER + idx] = ldin((idx & 1) ? ber : gr, o, f32);
      return;
    }
    v = ldin(s, idx, f32);
    ws[d + idx] = v;
    return;
  }
  if (blk < 5632) {                       // ---- WNB / W1B bf16 operand fill ----
    long idx = (long)(blk - 2088) * 256 + t;
    if (idx >= 907200) return;
    if (idx < 360000) {
      int u = idx / 180000; long r = idx % 180000;
      ((unsigned short*)(ws + O_WNB))[idx] = inbitsb(u ? wr : wn, r, f32);
    } else {
      long r2 = idx - 360000;              // 2 x [300][912], 3x304 k-sub-blocks
      int u = r2 / 273600; long rr = r2 % 273600;
      int n = rr / 912, kk = rr % 912;
      int p = kk / 304, k = kk - p * 304;
      unsigned short v = 0;
      if (k < 300) v = inbitsb(u ? w1r : w1n, (long)n * 900 + p * 300 + k, f32);
      ((unsigned short*)(ws + O_W1B))[r2] = v;
    }
    return;
  }
  // ---- XB / WIB conversion: needed only when inputs are f32 ----
  if (!f32) return;
  long idx = (long)(blk - 5632) * 256 + t;
  if (idx >= 1766400) return;
  if (idx < 614400) ((unsigned short*)(ws + O_XB))[idx] = inbitsb(x, idx, 1);
  else ((unsigned short*)(ws + O_WIB))[idx - 614400] = inbitsb(wi, idx - 614400, 1);
}

// ---------------- xg = x @ WiT + bi via MFMA: [800][1500] ----------------
__global__ __launch_bounds__(256) void k_xg(float* ws, const void* xin, const void* wiin,
                                            const void* mask) {
  const int f32 = is_f32(mask);
  const unsigned short* X = f32 ? (const unsigned short*)(ws + O_XB)
                                : (const unsigned short*)xin;
  const unsigned short* W = f32 ? (const unsigned short*)(ws + O_WIB)
                                : (const unsigned short*)wiin;
  const int m0 = blockIdx.x * 16;
  const int w = threadIdx.x >> 6, lane = threadIdx.x & 63;
  const int n0 = blockIdx.y * 256 + w * 64;
  const int rA = lane & 15, kq = (lane >> 4) * 8;
  const unsigned short* ax = X + (long)(m0 + rA) * 768 + kq;
  const unsigned short* bx = W + (long)(n0 + rA) * 768 + kq;
  f32x4 acc[4] = {};
  for (int kt = 0; kt < 24; ++kt) {
    bf16x8 af = *(const bf16x8*)(ax + kt * 32);
#pragma unroll
    for (int nf = 0; nf < 4; ++nf) {
      bf16x8 bf = *(const bf16x8*)(bx + (long)nf * 16 * 768 + kt * 32);
      acc[nf] = __builtin_amdgcn_mfma_f32_16x16x32_bf16(af, bf, acc[nf], 0, 0, 0);
    }
  }
  const int rD = m0 + (lane >> 4) * 4, cD = lane & 15;
#pragma unroll
  for (int nf = 0; nf < 4; ++nf) {
    int col = n0 + nf * 16 + cD;
    if (col < 1500) {
      float bv = ws[O_BI + col];
#pragma unroll
      for (int q = 0; q < 4; ++q)
        ws[O_XG + (long)(rD + q) * 1500 + col] = acc[nf][q] + bv;
    }
  }
}

// ---------------- the recurrent scan: 40 WGs = (batch, group), weights in VGPRs ----------------
__global__ __launch_bounds__(512, 2) void k_scan(float* ws) {
  const int w = blockIdx.x;            // 40
  const int b = w & 7, g = w >> 3;     // batch, gate-group/output-slice
  const int t = threadIdx.x;
  const int lane = t & 63, wid = t >> 6;
  const unsigned* W1 = (const unsigned*)(ws + O_WHT) + g * 45000;
  const unsigned* W2 = (const unsigned*)(ws + O_WTT) + g * 27000;
  const float* xg = ws + O_XG;
  const float* bhp = ws + O_BH;
  const float* btp = ws + O_BT;
  float* cs_pub = ws + O_PUB + (long)b * 1504;
  float* h_pub  = ws + O_PUB + 12032 + (long)b * 304;
  float* c_pub  = ws + O_PUB + 14464 + (long)b * 304;
  int* flagA = (int*)(ws + O_PUB + 16896) + b * 16;
  int* flagB = (int*)(ws + O_PUB + 16896) + 512 + b * 16;
  unsigned short* HN2 = (unsigned short*)(ws + O_HN2);
  unsigned short* HR2 = (unsigned short*)(ws + O_HR2);
  unsigned short* HS2 = (unsigned short*)(ws + O_HS2);

  // persistent weights in registers (f16 pairs along k)
  unsigned wA0[50], wA1[50], wB0[30], wB1[30];
  if (t < 450) {
#pragma unroll
    for (int i = 0; i < 50; ++i) { wA0[i] = W1[i * 450 + t]; wA1[i] = W1[22500 + i * 450 + t]; }
#pragma unroll
    for (int j = 0; j < 30; ++j) { wB0[j] = W2[j * 450 + t]; wB1[j] = W2[13500 + j * 450 + t]; }
  }

  __shared__ __align__(16) unsigned h2[152];     // h as f16 pairs
  __shared__ __align__(16) float cf[304];        // c(l-1) f32
  __shared__ __align__(16) float gatef[304];
  __shared__ __align__(16) float pacc[3][304];
  __shared__ __align__(16) float csL[1504];
  __shared__ __align__(16) float catf[912];
  __shared__ __align__(16) unsigned cat2[456];
  __shared__ __align__(16) float pacc2[15][64];

  const int o2a = t % 150, kca = t / 150;        // phase-A tile
  const int o2b = t % 30,  kcb = t / 30;         // phase-B tile

  for (int l = 0; l < 100; ++l) {
    // ---- wait h,c from step l-1; gather ----
    if (t == 64) poll5(flagB, l);
    __syncthreads();
    if (t < 150) {
      float e = publd(h_pub + 2 * t), o = publd(h_pub + 2 * t + 1);
      h2[t] = packf16(e, o);
    } else if (t < 450) {
      cf[t - 150] = publd(c_pub + (t - 150));
    }
    __syncthreads();
    // ---- phase A: gate slice = Wh_g@h + xg + bh; cumsoftmax; publish cs ----
    if (t < 450) {
      float a0 = 0.f, a1 = 0.f;
      const unsigned* hp = h2 + kca * 50;
#pragma unroll
      for (int i = 0; i < 50; ++i) {
        unsigned hv = hp[i];
        a0 = dot2(wA0[i], hv, a0);
        a1 = dot2(wA1[i], hv, a1);
      }
      pacc[kca][2 * o2a] = a0; pacc[kca][2 * o2a + 1] = a1;
    }
    __syncthreads();
    if (t < 300)
      gatef[t] = pacc[0][t] + pacc[1][t] + pacc[2][t]
               + xg[((long)l * 8 + b) * 1500 + g * 300 + t] + bhp[g * 300 + t];
    __syncthreads();
    if (g == 0) {
      if (t < 300) pubst(cs_pub + t, tanhf(gatef[t]));
    } else if (wid == 0) {
      const int base = lane * 5;
      float e0 = 0.f, e1 = 0.f, e2 = 0.f, e3 = 0.f, e4 = 0.f, m = -3.0e38f;
      if (lane < 60) {
        e0 = gatef[base]; e1 = gatef[base + 1]; e2 = gatef[base + 2];
        e3 = gatef[base + 3]; e4 = gatef[base + 4];
        m = fmaxf(fmaxf(fmaxf(e0, e1), fmaxf(e2, e3)), e4);
      }
#pragma unroll
      for (int of = 32; of >= 1; of >>= 1) m = fmaxf(m, __shfl_xor(m, of, 64));
      float s0 = 0.f, s1 = 0.f, s2 = 0.f, s3 = 0.f, s4 = 0.f, tot = 0.f;
      if (lane < 60) {
        e0 = __expf(e0 - m); e1 = __expf(e1 - m); e2 = __expf(e2 - m);
        e3 = __expf(e3 - m); e4 = __expf(e4 - m);
        s0 = e0; s1 = s0 + e1; s2 = s1 + e2; s3 = s2 + e3; s4 = s3 + e4;
        tot = s4;
      }
      float sc = tot;
#pragma unroll
      for (int of = 1; of < 64; of <<= 1) {
        float u = __shfl_up(sc, of, 64);
        if (lane >= of) sc += u;
      }
      float total = __shfl(sc, 63);
      if (lane < 60) {
        float ex = sc - tot, inv = 1.f / total;
        pubst(cs_pub + g * 300 + base + 0, (ex + s0) * inv);
        pubst(cs_pub + g * 300 + base + 1, (ex + s1) * inv);
        pubst(cs_pub + g * 300 + base + 2, (ex + s2) * inv);
        pubst(cs_pub + g * 300 + base + 3, (ex + s3) * inv);
        pubst(cs_pub + g * 300 + base + 4, (ex + s4) * inv);
      }
    }
    asm volatile("s_waitcnt vmcnt(0)" ::: "memory");
    __syncthreads();
    if (t == 0) __hip_atomic_store(flagA + g, l + 1, __ATOMIC_RELAXED, __HIP_MEMORY_SCOPE_AGENT);
    if (t == 64) poll5(flagA, l + 1);
    __syncthreads();

    // ---- phase B: gather cs; combine -> cat; h-slice = Wt_rows@cat; publish h,c ----
    for (int i = t; i < 1500; i += 512) csL[i] = publd(cs_pub + i);
    __syncthreads();
    if (t < 300) {
      float cgv = csL[t];
      float egi = 1.f - csL[300 + t];
      float rgi = csL[600 + t];
      float egc = 1.f - csL[900 + t];
      float rgc = csL[1200 + t];
      float cin = cf[t];
      float ovc = rgc * egc, upc = rgc - ovc, dnc = egc - ovc;
      float ovi = rgi * egi, upi = rgi - ovi, dni = egi - ovi;
      float sh = ovi * cin + ovc * cgv;
      float cre = upi * cin + upc * cgv + sh;
      float cner = dni * cin + dnc * cgv + sh;
      catf[t] = cre; catf[300 + t] = cner; catf[600 + t] = sh;
      if (g == 0) {
        long rb = ((long)l * 8 + b) * 320;
        HN2[rb + t] = bfbits(tanhf(cner));
        HR2[rb + t] = bfbits(tanhf(cre));
        HS2[rb + t] = bfbits(tanhf(sh));
      }
    } else if (g == 0 && t < 320) {
      long rb = ((long)l * 8 + b) * 320;
      HN2[rb + t] = 0; HR2[rb + t] = 0; HS2[rb + t] = 0;
    }
    __syncthreads();
    if (t < 450) cat2[t] = packf16(catf[2 * t], catf[2 * t + 1]);
    __syncthreads();
    if (t < 450) {
      float a0 = 0.f, a1 = 0.f;
      const unsigned* cp = cat2 + kcb * 30;
#pragma unroll
      for (int j = 0; j < 30; ++j) {
        unsigned cv = cp[j];
        a0 = dot2(wB0[j], cv, a0);
        a1 = dot2(wB1[j], cv, a1);
      }
      pacc2[kcb][2 * o2b] = a0; pacc2[kcb][2 * o2b + 1] = a1;
    }
    __syncthreads();
    if (t < 60) {
      float s = btp[g * 60 + t];
#pragma unroll
      for (int kc = 0; kc < 15; ++kc) s += pacc2[kc][t];
      pubst(h_pub + g * 60 + t, tanhf(s));
      pubst(c_pub + g * 60 + t, s);
    }
    asm volatile("s_waitcnt vmcnt(0)" ::: "memory");
    __syncthreads();
    if (t == 0) __hip_atomic_store(flagB + g, l + 1, __ATOMIC_RELAXED, __HIP_MEMORY_SCOPE_AGENT);
  }
}

// ---------------- merged g3a + g3c via MFMA (blockIdx.z dispatch) ----------------
__global__ __launch_bounds__(256) void k_g3ac(float* ws, void* dout, const void* mask) {
  const int z = blockIdx.z;
  const int m0 = blockIdx.x * 16;
  const int w = threadIdx.x >> 6, lane = threadIdx.x & 63;
  const int n0 = blockIdx.y * 256 + w * 64;
  if (n0 >= 300) return;
  const int rA = lane & 15, kq = (lane >> 4) * 8;
  const int rD = m0 + (lane >> 4) * 4, cD = lane & 15;

  if (z < 2) {                 // ---- g3a: tG = tanh(cat(h_share,h_x)@WT + b) ----
    const int u = z;
    const int f32 = is_f32(mask);
    const unsigned short* A0 = (const unsigned short*)(ws + O_HS2);
    const unsigned short* A1 = (const unsigned short*)(ws + (u ? O_HR2 : O_HN2));
    const unsigned short* B = (const unsigned short*)(ws + O_WNB) + (long)u * 180000;
    const unsigned short* a0p = A0 + (long)(m0 + rA) * 320 + kq;
    const unsigned short* a1p = A1 + (long)(m0 + rA) * 320 + kq;
    const unsigned short* bp = B + (long)(n0 + rA) * 600 + kq;
    f32x4 acc[4] = {};
    for (int kt = 0; kt < 10; ++kt) {
      bf16x8 af = *(const bf16x8*)(a0p + kt * 32);
#pragma unroll
      for (int nf = 0; nf < 4; ++nf) {
        bf16x8 bf = *(const bf16x8*)(bp + (long)nf * 16 * 600 + kt * 32);
        acc[nf] = __builtin_amdgcn_mfma_f32_16x16x32_bf16(af, bf, acc[nf], 0, 0, 0);
      }
    }
    for (int kt = 0; kt < 10; ++kt) {
      bf16x8 af = *(const bf16x8*)(a1p + kt * 32);
#pragma unroll
      for (int nf = 0; nf < 4; ++nf) {
        bf16x8 bf = *(const bf16x8*)(bp + (long)nf * 16 * 600 + 300 + kt * 32);
        acc[nf] = __builtin_amdgcn_mfma_f32_16x16x32_bf16(af, bf, acc[nf], 0, 0, 0);
      }
    }
#pragma unroll
    for (int nf = 0; nf < 4; ++nf) {
      int col = n0 + nf * 16 + cD;
      if (col < 300) {
        float bv = ws[(u ? O_BR : O_BN) + col];
#pragma unroll
        for (int q = 0; q < 4; ++q) {
          float tv = tanhf(acc[nf][q] + bv);
          long idx = (long)(rD + q) * 300 + col;
          ws[O_TG + (long)u * 240000 + idx] = tv;
          if (u == 1) stout(dout, 1600000L + idx, tv, f32);
        }
      }
    }
  } else {                     // ---- g3c: start/end token projections a,b ----
    const int u = (z - 2) >> 1, proj = (z - 2) & 1;
    const unsigned short* A = (const unsigned short*)(ws + (u ? O_HR2 : O_HN2));
    const unsigned short* B = (const unsigned short*)(ws + O_W1B) + (long)u * 273600;
    const unsigned short* ap = A + (long)(m0 + rA) * 320 + kq;
    const unsigned short* bp = B + (long)(n0 + rA) * 912 + proj * 304 + kq;
    f32x4 acc[4] = {};
    for (int kt = 0; kt < 10; ++kt) {
      bf16x8 af = *(const bf16x8*)(ap + kt * 32);
#pragma unroll
      for (int nf = 0; nf < 4; ++nf) {
        bf16x8 bf = *(const bf16x8*)(bp + (long)nf * 16 * 912 + kt * 32);
        acc[nf] = __builtin_amdgcn_mfma_f32_16x16x32_bf16(af, bf, acc[nf], 0, 0, 0);
      }
    }
    const long dst = (proj ? O_BU : O_AU) + (long)u * 240000;
#pragma unroll
    for (int nf = 0; nf < 4; ++nf) {
      int col = n0 + nf * 16 + cD;
      if (col < 300) {
#pragma unroll
        for (int q = 0; q < 4; ++q)
          ws[dst + (long)(rD + q) * 300 + col] = acc[nf][q];
      }
    }
  }
}

// ---------------- max over L + global projection c ----------------
__global__ __launch_bounds__(320) void k_g3b(float* ws) {
  const int u = blockIdx.x >> 3, b = blockIdx.x & 7;
  __shared__ float hs[304];
  const int o = threadIdx.x;
  const float* tg = ws + O_TG + (long)u * 240000;
  if (o < 300) {
    float m = -3e38f;
    for (int l = 0; l < 100; ++l) m = fmaxf(m, tg[((long)l * 8 + b) * 300 + o]);
    hs[o] = m;
  }
  __syncthreads();
  if (o < 300) {
    const float* w1 = ws + (u ? O_W1RT : O_W1NT);
    float acc = ws[(u ? O_B1R : O_B1N) + o];
    for (int k = 0; k < 300; ++k) acc += hs[k] * w1[(long)(600 + k) * 300 + o];
    ws[O_CU + (long)u * 2400 + b * 300 + o] = acc;
  }
}

// ---------------- fused pair scoring: lane-per-pair LN -> elu -> @W2 -> sigmoid*mask ----------------
template <int NOUT, bool TRI>
__device__ __forceinline__ void pair_body(float* ws, void* dout, int f32, int b,
    long obase, long uofs, long w2tofs, long b2ofs, long gbeofs, long cofs,
    float* aS, float* bS, float* miS, float* mjS) {
  const int i0 = blockIdx.x * 16, j0 = blockIdx.y * 32;
  const int t = threadIdx.x;
  for (int s = t; s < 16 * 300; s += 512) {
    int r = s / 300, o = s - r * 300;
    int i = i0 + r;
    float v = 0.f;
    if (i < 100) v = ws[O_AU + uofs + ((long)i * 8 + b) * 300 + o] + ws[cofs + b * 300 + o];
    aS[r * 305 + o] = v;
  }
  for (int s = t; s < 32 * 300; s += 512) {
    int r = s / 300, o = s - r * 300;
    int j = j0 + r;
    bS[r * 305 + o] = (j < 100) ? ws[O_BU + uofs + ((long)j * 8 + b) * 300 + o] : 0.f;
  }
  if (t < 16) miS[t] = (i0 + t < 100) ? ws[O_MASK + (i0 + t) * 8 + b] : 0.f;
  else if (t < 48) mjS[t - 16] = (j0 + t - 16 < 100) ? ws[O_MASK + (j0 + t - 16) * 8 + b] : 0.f;
  __syncthreads();
  const int wid = t >> 6, lane = t & 63;
  const int ii = wid * 2 + (lane >> 5);
  const int jj = lane & 31;
  const int i = i0 + ii, j = j0 + jj;
  if (i >= 100 || j >= 100) return;
  long base = obase + (((long)i * 100 + j) * 8 + b) * NOUT;
  // whole-wave lower-triangle skip (all 64 pair-slots have j < i)
  if (TRI && (j0 + 31 < i0 + wid * 2)) {
#pragma unroll
    for (int q = 0; q < NOUT; ++q) stout(dout, base + q, 0.f, f32);
    return;
  }
  const float* ap = aS + ii * 305;
  const float* bp = bS + jj * 305;
  float sum = 0.f, ssq = 0.f;
#pragma unroll 4
  for (int o = 0; o < 300; ++o) {
    float v = ap[o] + bp[o];
    sum += v;
    ssq = fmaf(v, v, ssq);
  }
  float mean = sum * (1.f / 300.f);
  float inv = rsqrtf(ssq * (1.f / 300.f) - mean * mean + EPSV);
  float acc[NOUT];
#pragma unroll
  for (int q = 0; q < NOUT; ++q) acc[q] = 0.f;
  const float* gbe = ws + gbeofs;
  const float* w2t = ws + w2tofs;
#pragma unroll 2
  for (int o = 0; o < 300; ++o) {
    float v = ap[o] + bp[o];
    float xn = fmaf((v - mean) * inv, gbe[2 * o], gbe[2 * o + 1]);
    float e = xn > 0.f ? xn : (__expf(xn) - 1.f);
#pragma unroll
    for (int q = 0; q < NOUT; ++q) acc[q] = fmaf(e, w2t[o * NOUT + q], acc[q]);
  }
  float mv = miS[ii] * mjS[jj];
  if (TRI && j < i) mv = 0.f;
#pragma unroll
  for (int q = 0; q < NOUT; ++q) {
    float b2v = ws[b2ofs + q];
    stout(dout, base + q, mv / (1.f + __expf(-(acc[q] + b2v))), f32);
  }
}

__global__ __launch_bounds__(512) void k_pairs2(float* ws, void* dout, const void* mask) {
  __shared__ float aS[16 * 305];
  __shared__ float bS[32 * 305];
  __shared__ float miS[16], mjS[32];
  const int f32 = is_f32(mask);
  const int z = blockIdx.z;
  if (z < 8)
    pair_body<8, true>(ws, dout, f32, z, 0L, 0L, O_W2NT, O_B2N, O_GBEN, O_CU,
                       aS, bS, miS, mjS);
  else
    pair_body<12, false>(ws, dout, f32, z - 8, 640000L, 240000L, O_W2RT, O_B2R, O_GBER,
                         O_CU + 2400, aS, bS, miS, mjS);
}

// ---------------- host ----------------
extern "C" void kernel_launch(void* const* d_in, const int* in_sizes, int n_in,
                              void* d_out, int out_size, void* d_ws, size_t ws_size,
                              hipStream_t stream) {
  (void)in_sizes; (void)n_in; (void)out_size; (void)ws_size;
  float* ws = (float*)d_ws;
  const void* mask = d_in[1];
  k_prep<<<dim3(12533), dim3(256), 0, stream>>>(ws, mask,
      d_in[0], d_in[2], d_in[4], d_in[6],
      d_in[8], d_in[16], d_in[10], d_in[18],
      d_in[3], d_in[5], d_in[7],
      d_in[9], d_in[11], d_in[12], d_in[13], d_in[14], d_in[15],
      d_in[17], d_in[19], d_in[20], d_in[21], d_in[22], d_in[23]);
  k_xg<<<dim3(50, 6), dim3(256), 0, stream>>>(ws, d_in[0], d_in[2], mask);
  k_scan<<<dim3(40), dim3(512), 0, stream>>>(ws);
  k_g3ac<<<dim3(50, 2, 6), dim3(256), 0, stream>>>(ws, d_out, mask);
  k_g3b<<<dim3(16), dim3(320), 0, stream>>>(ws);
  k_pairs2<<<dim3(7, 4, 16), dim3(512), 0, stream>>>(ws, d_out, mask);
}

// Round 8
// 729.264 us; speedup vs baseline: 2.8789x; 1.0111x over previous
//
#include <hip/hip_runtime.h>
#include <hip/hip_bf16.h>

#define EPSV 1e-5f

typedef _Float16 f16x2 __attribute__((ext_vector_type(2)));
typedef short bf16x8 __attribute__((ext_vector_type(8)));
typedef float f32x4 __attribute__((ext_vector_type(4)));
typedef unsigned long long ull;

// ---------------- workspace layout (float offsets) ----------------
static constexpr long O_WHT = 1024;                  // scan Wh f16-pairs: 225000 uints
static constexpr long O_WTT = O_WHT + 225000;        // scan Wt f16-pairs: 135000 uints
static constexpr long O_W1NT= O_WTT + 135000;        // f32 [900][300] (g3b)
static constexpr long O_W1RT= O_W1NT + 270000;       // f32 [900][300]
static constexpr long O_XB  = O_W1RT + 270000;       // bf16 [800][768] (f32 fallback only)
static constexpr long O_WIB = O_XB + 307200;         // bf16 [1500][768] (f32 fallback only)
static constexpr long O_WNB = O_WIB + 576000;        // bf16 2x[300][600]
static constexpr long O_W1B = O_WNB + 180000;        // bf16 2x[300][912] (3x304 sub)
static constexpr long O_XG  = O_W1B + 273600;        // f32 [800][1500]
static constexpr long O_PUB = O_XG + 1200000;        // seq-embedded ulongs:
//   cs64 [8][1504] ulong = 24064 f;  h64 [8][304] = 4864 f;  c64 [8][304] = 4864 f
static constexpr long O_H64 = O_PUB + 24064;
static constexpr long O_C64 = O_H64 + 4864;
static constexpr long PUBSZ = 33792;
static constexpr long O_HN2 = O_PUB + PUBSZ;         // bf16 [800][320]
static constexpr long O_HR2 = O_HN2 + 128000;
static constexpr long O_HS2 = O_HR2 + 128000;
static constexpr long O_TG  = O_HS2 + 128000;        // f32 [2][800][300]
static constexpr long O_AU  = O_TG + 480000;         // f32 [2][800][300]
static constexpr long O_BU  = O_AU + 480000;
static constexpr long O_CU  = O_BU + 480000;         // f32 [2][8][300]
static constexpr long O_MASK= O_CU + 4800;           // [100][8]
static constexpr long O_BI  = O_MASK + 800;          // 1500
static constexpr long O_BH  = O_BI + 1504;           // 1500
static constexpr long O_BT  = O_BH + 1504;           // 300
static constexpr long O_BN  = O_BT + 304;
static constexpr long O_B1N = O_BN + 304;
static constexpr long O_GN  = O_B1N + 304;
static constexpr long O_BEN = O_GN + 304;
static constexpr long O_W2N = O_BEN + 304;           // [8][300]
static constexpr long O_B2N = O_W2N + 2400;          // 8
static constexpr long O_BR  = O_B2N + 16;
static constexpr long O_B1R = O_BR + 304;
static constexpr long O_GR  = O_B1R + 304;
static constexpr long O_BER = O_GR + 304;
static constexpr long O_W2R = O_BER + 304;           // [12][300]
static constexpr long O_B2R = O_W2R + 3600;          // 12
static constexpr long O_W2NT= O_B2R + 16;            // [300][8]
static constexpr long O_GBEN= O_W2NT + 2400;         // [300][2]
static constexpr long O_W2RT= O_GBEN + 608;          // [300][12]
static constexpr long O_GBER= O_W2RT + 3600;         // [300][2]

__device__ __forceinline__ int is_f32(const void* mask) {
  return *((const unsigned*)mask) == 0x3F800000u;    // f32 1.0f vs bf16 {1,1}=0x3F803F80
}
__device__ __forceinline__ float ldin(const void* p, long i, int f32) {
  if (f32) return ((const float*)p)[i];
  unsigned int w = ((unsigned int)(((const unsigned short*)p)[i])) << 16;
  return __uint_as_float(w);
}
__device__ __forceinline__ unsigned short inbitsb(const void* p, long i, int f32) {
  if (!f32) return ((const unsigned short*)p)[i];
  __hip_bfloat16 hb = __float2bfloat16(((const float*)p)[i]);
  return *reinterpret_cast<unsigned short*>(&hb);
}
__device__ __forceinline__ unsigned short bfbits(float v) {
  __hip_bfloat16 hb = __float2bfloat16(v);
  return *reinterpret_cast<unsigned short*>(&hb);
}
__device__ __forceinline__ void stout(void* p, long i, float v, int f32) {
  if (f32) ((float*)p)[i] = v;
  else ((__hip_bfloat16*)p)[i] = __float2bfloat16(v);
}
__device__ __forceinline__ unsigned packf16(float a, float b) {
  union { _Float16 h[2]; unsigned u; } x;
  x.h[0] = (_Float16)a; x.h[1] = (_Float16)b;
  return x.u;
}
__device__ __forceinline__ float dot2(unsigned wu, unsigned xu, float acc) {
  return __builtin_amdgcn_fdot2(__builtin_bit_cast(f16x2, wu),
                                __builtin_bit_cast(f16x2, xu), acc, false);
}

// ---- seq-embedded MALL exchange: one 8B relaxed atomic = (f32 bits <<32) | seq ----
__device__ __forceinline__ void pub64(ull* p, float v, unsigned seq) {
  ull w = ((ull)__float_as_uint(v) << 32) | (ull)seq;
  __hip_atomic_store(p, w, __ATOMIC_RELAXED, __HIP_MEMORY_SCOPE_AGENT);
}
__device__ __forceinline__ ull ld64(const ull* p) {
  return __hip_atomic_load(p, __ATOMIC_RELAXED, __HIP_MEMORY_SCOPE_AGENT);
}
__device__ __forceinline__ float val64(ull w) {
  return __uint_as_float((unsigned)(w >> 32));
}
__device__ __forceinline__ float wait64(const ull* p, unsigned seq) {
  ull w = ld64(p);
  long it = 0;
  while ((unsigned)w != seq && ++it < (1L << 22)) w = ld64(p);
  return val64(w);
}

// ---------------- one prep kernel: pack + transpose + misc + zero + cvt ----------------
__global__ __launch_bounds__(256) void k_prep(float* ws, const void* mask,
    const void* x, const void* wi, const void* wh, const void* wt,
    const void* wn, const void* wr, const void* w1n, const void* w1r,
    const void* bi, const void* bh, const void* bt,
    const void* bn, const void* b1n, const void* gn, const void* ben,
    const void* w2n, const void* b2n, const void* br, const void* b1r,
    const void* gr, const void* ber, const void* w2r, const void* b2r) {
  const int f32 = is_f32(mask);
  const int blk = blockIdx.x, t = threadIdx.x;

  if (blk < 1407) {                       // ---- scan-weight f16-pair pack ----
    int q = blk * 256 + t;
    if (q < 225000) {
      int g = q / 45000, r = q % 45000;
      int hh = r / 22500, r2 = r % 22500;
      int i = r2 / 450, tt = r2 % 450;
      int o2 = tt % 150, kc = tt / 150;
      int row = g * 300 + 2 * o2 + hh;
      int k0 = 2 * (kc * 50 + i);
      float lo = ldin(wh, (long)row * 300 + k0, f32);
      float hi = ldin(wh, (long)row * 300 + k0 + 1, f32);
      ((unsigned*)(ws + O_WHT))[q] = packf16(lo, hi);
    } else if (q < 360000) {
      int q2 = q - 225000;
      int g = q2 / 27000, r = q2 % 27000;
      int hh = r / 13500, r2 = r % 13500;
      int j = r2 / 450, tt = r2 % 450;
      int o2 = tt % 30, kc = tt / 30;
      int row = g * 60 + 2 * o2 + hh;
      int k0 = 2 * (kc * 30 + j);
      float lo = ldin(wt, (long)row * 900 + k0, f32);
      float hi = ldin(wt, (long)row * 900 + k0 + 1, f32);
      ((unsigned*)(ws + O_WTT))[q2] = packf16(lo, hi);
    }
    return;
  }
  if (blk < 1987) {                       // ---- W1 f32 transposes (580 tiles) ----
    __shared__ float ts[32][33];
    int tile = blk - 1407;
    int m = tile >= 290; int ti = tile - m * 290;
    const void* src = m ? w1r : w1n;
    const long D = m ? O_W1RT : O_W1NT;
    const int R = 300, C = 900;
    int tr = ti / 29, tc = ti % 29;
    int r0 = tr * 32, c0 = tc * 32;
    const int tx = t & 31, ty = t >> 5;
#pragma unroll
    for (int k = 0; k < 4; k++) {
      int r = r0 + ty + 8 * k, c = c0 + tx;
      ts[ty + 8 * k][tx] = (r < R && c < C) ? ldin(src, (long)r * C + c, f32) : 0.f;
    }
    __syncthreads();
#pragma unroll
    for (int k = 0; k < 4; k++) {
      int c = c0 + ty + 8 * k, r = r0 + tx;
      if (c < C && r < R) ws[D + (long)c * R + r] = ts[tx][ty + 8 * k];
    }
    return;
  }
  if (blk < 2197) {                       // ---- misc + FULL pub zero (replay safety!) ----
    long i = (long)(blk - 1987) * 256 + t;
    if (i >= 19720 + PUBSZ) return;
    if (i >= 19720) { ws[O_PUB + (i - 19720)] = 0.f; return; }
    long idx = i; const void* s; long d; float v;
    if (idx < 800)                   { s = mask; d = O_MASK; }
    else if ((idx -= 800) < 1500)    { s = bi;  d = O_BI; }
    else if ((idx -= 1500) < 1500)   { s = bh;  d = O_BH; }
    else if ((idx -= 1500) < 300)    { s = bt;  d = O_BT; }
    else if ((idx -= 300) < 300)     { s = bn;  d = O_BN; }
    else if ((idx -= 300) < 300)     { s = b1n; d = O_B1N; }
    else if ((idx -= 300) < 300)     { s = gn;  d = O_GN; }
    else if ((idx -= 300) < 300)     { s = ben; d = O_BEN; }
    else if ((idx -= 300) < 2400)    { s = w2n; d = O_W2N; }
    else if ((idx -= 2400) < 8)      { s = b2n; d = O_B2N; }
    else if ((idx -= 8) < 300)       { s = br;  d = O_BR; }
    else if ((idx -= 300) < 300)     { s = b1r; d = O_B1R; }
    else if ((idx -= 300) < 300)     { s = gr;  d = O_GR; }
    else if ((idx -= 300) < 300)     { s = ber; d = O_BER; }
    else if ((idx -= 300) < 3600)    { s = w2r; d = O_W2R; }
    else if ((idx -= 3600) < 12)     { s = b2r; d = O_B2R; }
    else if ((idx -= 12) < 2400) {   // W2NT [300][8]
      int o = idx >> 3, q = idx & 7;
      ws[O_W2NT + idx] = ldin(w2n, (long)q * 300 + o, f32);
      return;
    }
    else if ((idx -= 2400) < 600) {  // GBEN [300][2]
      int o = idx >> 1;
      ws[O_GBEN + idx] = ldin((idx & 1) ? ben : gn, o, f32);
      return;
    }
    else if ((idx -= 600) < 3600) {  // W2RT [300][12]
      int o = idx / 12, q = idx % 12;
      ws[O_W2RT + idx] = ldin(w2r, (long)q * 300 + o, f32);
      return;
    }
    else {                           // GBER [300][2]
      idx -= 3600;
      int o = idx >> 1;
      ws[O_GBER + idx] = ldin((idx & 1) ? ber : gr, o, f32);
      return;
    }
    v = ldin(s, idx, f32);
    ws[d + idx] = v;
    return;
  }
  if (blk < 5741) {                       // ---- WNB / W1B bf16 operand fill ----
    long idx = (long)(blk - 2197) * 256 + t;
    if (idx >= 907200) return;
    if (idx < 360000) {
      int u = idx / 180000; long r = idx % 180000;
      ((unsigned short*)(ws + O_WNB))[idx] = inbitsb(u ? wr : wn, r, f32);
    } else {
      long r2 = idx - 360000;              // 2 x [300][912], 3x304 k-sub-blocks
      int u = r2 / 273600; long rr = r2 % 273600;
      int n = rr / 912, kk = rr % 912;
      int p = kk / 304, k = kk - p * 304;
      unsigned short v = 0;
      if (k < 300) v = inbitsb(u ? w1r : w1n, (long)n * 900 + p * 300 + k, f32);
      ((unsigned short*)(ws + O_W1B))[r2] = v;
    }
    return;
  }
  // ---- XB / WIB conversion: needed only when inputs are f32 ----
  if (!f32) return;
  long idx = (long)(blk - 5741) * 256 + t;
  if (idx >= 1766400) return;
  if (idx < 614400) ((unsigned short*)(ws + O_XB))[idx] = inbitsb(x, idx, 1);
  else ((unsigned short*)(ws + O_WIB))[idx - 614400] = inbitsb(wi, idx - 614400, 1);
}

// ---------------- xg = x @ WiT + bi via MFMA: [800][1500] ----------------
__global__ __launch_bounds__(256) void k_xg(float* ws, const void* xin, const void* wiin,
                                            const void* mask) {
  const int f32 = is_f32(mask);
  const unsigned short* X = f32 ? (const unsigned short*)(ws + O_XB)
                                : (const unsigned short*)xin;
  const unsigned short* W = f32 ? (const unsigned short*)(ws + O_WIB)
                                : (const unsigned short*)wiin;
  const int m0 = blockIdx.x * 16;
  const int w = threadIdx.x >> 6, lane = threadIdx.x & 63;
  const int n0 = blockIdx.y * 256 + w * 64;
  const int rA = lane & 15, kq = (lane >> 4) * 8;
  const unsigned short* ax = X + (long)(m0 + rA) * 768 + kq;
  const unsigned short* bx = W + (long)(n0 + rA) * 768 + kq;
  f32x4 acc[4] = {};
  for (int kt = 0; kt < 24; ++kt) {
    bf16x8 af = *(const bf16x8*)(ax + kt * 32);
#pragma unroll
    for (int nf = 0; nf < 4; ++nf) {
      bf16x8 bf = *(const bf16x8*)(bx + (long)nf * 16 * 768 + kt * 32);
      acc[nf] = __builtin_amdgcn_mfma_f32_16x16x32_bf16(af, bf, acc[nf], 0, 0, 0);
    }
  }
  const int rD = m0 + (lane >> 4) * 4, cD = lane & 15;
#pragma unroll
  for (int nf = 0; nf < 4; ++nf) {
    int col = n0 + nf * 16 + cD;
    if (col < 1500) {
      float bv = ws[O_BI + col];
#pragma unroll
      for (int q = 0; q < 4; ++q)
        ws[O_XG + (long)(rD + q) * 1500 + col] = acc[nf][q] + bv;
    }
  }
}

// ---------------- the recurrent scan: 40 WGs, flag-free seq-embedded sync ----------------
__global__ __launch_bounds__(512, 2) void k_scan(float* ws) {
  const int w = blockIdx.x;            // 40
  const int b = w & 7, g = w >> 3;     // batch, gate-group/output-slice
  const int t = threadIdx.x;
  const int lane = t & 63, wid = t >> 6;
  const unsigned* W1 = (const unsigned*)(ws + O_WHT) + g * 45000;
  const unsigned* W2 = (const unsigned*)(ws + O_WTT) + g * 27000;
  const float* xg = ws + O_XG;
  const float* bhp = ws + O_BH;
  const float* btp = ws + O_BT;
  ull* cs64 = (ull*)(ws + O_PUB) + (long)b * 1504;
  ull* h64  = (ull*)(ws + O_H64) + (long)b * 304;
  ull* c64  = (ull*)(ws + O_C64) + (long)b * 304;
  unsigned short* HN2 = (unsigned short*)(ws + O_HN2);
  unsigned short* HR2 = (unsigned short*)(ws + O_HR2);
  unsigned short* HS2 = (unsigned short*)(ws + O_HS2);

  // persistent weights in registers (f16 pairs along k)
  unsigned wA0[50], wA1[50], wB0[30], wB1[30];
  if (t < 450) {
#pragma unroll
    for (int i = 0; i < 50; ++i) { wA0[i] = W1[i * 450 + t]; wA1[i] = W1[22500 + i * 450 + t]; }
#pragma unroll
    for (int j = 0; j < 30; ++j) { wB0[j] = W2[j * 450 + t]; wB1[j] = W2[13500 + j * 450 + t]; }
  }

  __shared__ __align__(16) unsigned h2[152];     // h as f16 pairs
  __shared__ __align__(16) float cf[304];        // c(l-1) f32
  __shared__ __align__(16) float gatef[304];
  __shared__ __align__(16) float pacc[3][304];
  __shared__ __align__(16) float csL[1504];
  __shared__ __align__(16) float catf[912];
  __shared__ __align__(16) unsigned cat2[456];
  __shared__ __align__(16) float pacc2[15][64];

  const int o2a = t % 150, kca = t / 150;        // phase-A tile
  const int o2b = t % 30,  kcb = t / 30;         // phase-B tile

  for (int l = 0; l < 100; ++l) {
    // ---- gather h,c of step l-1: poll seq==l directly on data ----
    if (t < 150) {
      float e = wait64(h64 + 2 * t, (unsigned)l);
      float o = wait64(h64 + 2 * t + 1, (unsigned)l);
      h2[t] = packf16(e, o);
    } else if (t < 450) {
      cf[t - 150] = wait64(c64 + (t - 150), (unsigned)l);
    }
    __syncthreads();
    // ---- phase A: gate slice = Wh_g@h + xg + bh; cumsoftmax; publish cs (seq l+1) ----
    if (t < 450) {
      float a0 = 0.f, a1 = 0.f;
      const unsigned* hp = h2 + kca * 50;
#pragma unroll
      for (int i = 0; i < 50; ++i) {
        unsigned hv = hp[i];
        a0 = dot2(wA0[i], hv, a0);
        a1 = dot2(wA1[i], hv, a1);
      }
      pacc[kca][2 * o2a] = a0; pacc[kca][2 * o2a + 1] = a1;
    }
    __syncthreads();
    if (t < 300)
      gatef[t] = pacc[0][t] + pacc[1][t] + pacc[2][t]
               + xg[((long)l * 8 + b) * 1500 + g * 300 + t] + bhp[g * 300 + t];
    __syncthreads();
    if (g == 0) {
      if (t < 300) {
        float v = tanhf(gatef[t]);
        csL[t] = v;
        pub64(cs64 + t, v, (unsigned)(l + 1));
      }
    } else if (wid == 0) {
      const int base = lane * 5;
      float e0 = 0.f, e1 = 0.f, e2 = 0.f, e3 = 0.f, e4 = 0.f, m = -3.0e38f;
      if (lane < 60) {
        e0 = gatef[base]; e1 = gatef[base + 1]; e2 = gatef[base + 2];
        e3 = gatef[base + 3]; e4 = gatef[base + 4];
        m = fmaxf(fmaxf(fmaxf(e0, e1), fmaxf(e2, e3)), e4);
      }
#pragma unroll
      for (int of = 32; of >= 1; of >>= 1) m = fmaxf(m, __shfl_xor(m, of, 64));
      float s0 = 0.f, s1 = 0.f, s2 = 0.f, s3 = 0.f, s4 = 0.f, tot = 0.f;
      if (lane < 60) {
        e0 = __expf(e0 - m); e1 = __expf(e1 - m); e2 = __expf(e2 - m);
        e3 = __expf(e3 - m); e4 = __expf(e4 - m);
        s0 = e0; s1 = s0 + e1; s2 = s1 + e2; s3 = s2 + e3; s4 = s3 + e4;
        tot = s4;
      }
      float sc = tot;
#pragma unroll
      for (int of = 1; of < 64; of <<= 1) {
        float u = __shfl_up(sc, of, 64);
        if (lane >= of) sc += u;
      }
      float total = __shfl(sc, 63);
      if (lane < 60) {
        float ex = sc - tot, inv = 1.f / total;
        float v0 = (ex + s0) * inv, v1 = (ex + s1) * inv, v2 = (ex + s2) * inv;
        float v3 = (ex + s3) * inv, v4 = (ex + s4) * inv;
        const int o0 = g * 300 + base;
        csL[o0] = v0; csL[o0 + 1] = v1; csL[o0 + 2] = v2; csL[o0 + 3] = v3; csL[o0 + 4] = v4;
        pub64(cs64 + o0 + 0, v0, (unsigned)(l + 1));
        pub64(cs64 + o0 + 1, v1, (unsigned)(l + 1));
        pub64(cs64 + o0 + 2, v2, (unsigned)(l + 1));
        pub64(cs64 + o0 + 3, v3, (unsigned)(l + 1));
        pub64(cs64 + o0 + 4, v4, (unsigned)(l + 1));
      }
    }
    // no drain, no flag: stores are self-validating

    // ---- phase B: gather cs (poll seq==l+1), skipping own slice ----
    for (int i = t; i < 1500; i += 512) {
      if (i / 300 != g) csL[i] = wait64(cs64 + i, (unsigned)(l + 1));
    }
    __syncthreads();
    if (t < 300) {
      float cgv = csL[t];
      float egi = 1.f - csL[300 + t];
      float rgi = csL[600 + t];
      float egc = 1.f - csL[900 + t];
      float rgc = csL[1200 + t];
      float cin = cf[t];
      float ovc = rgc * egc, upc = rgc - ovc, dnc = egc - ovc;
      float ovi = rgi * egi, upi = rgi - ovi, dni = egi - ovi;
      float sh = ovi * cin + ovc * cgv;
      float cre = upi * cin + upc * cgv + sh;
      float cner = dni * cin + dnc * cgv + sh;
      catf[t] = cre; catf[300 + t] = cner; catf[600 + t] = sh;
      if (g == 0) {
        long rb = ((long)l * 8 + b) * 320;
        HN2[rb + t] = bfbits(tanhf(cner));
        HR2[rb + t] = bfbits(tanhf(cre));
        HS2[rb + t] = bfbits(tanhf(sh));
      }
    } else if (g == 0 && t < 320) {
      long rb = ((long)l * 8 + b) * 320;
      HN2[rb + t] = 0; HR2[rb + t] = 0; HS2[rb + t] = 0;
    }
    __syncthreads();
    if (t < 450) cat2[t] = packf16(catf[2 * t], catf[2 * t + 1]);
    __syncthreads();
    if (t < 450) {
      float a0 = 0.f, a1 = 0.f;
      const unsigned* cp = cat2 + kcb * 30;
#pragma unroll
      for (int j = 0; j < 30; ++j) {
        unsigned cv = cp[j];
        a0 = dot2(wB0[j], cv, a0);
        a1 = dot2(wB1[j], cv, a1);
      }
      pacc2[kcb][2 * o2b] = a0; pacc2[kcb][2 * o2b + 1] = a1;
    }
    __syncthreads();
    if (t < 60) {
      float s = btp[g * 60 + t];
#pragma unroll
      for (int kc = 0; kc < 15; ++kc) s += pacc2[kc][t];
      pub64(h64 + g * 60 + t, tanhf(s), (unsigned)(l + 1));
      pub64(c64 + g * 60 + t, s, (unsigned)(l + 1));
    }
    // no drain, no flag
  }
}

// ---------------- merged g3a + g3c via MFMA (blockIdx.z dispatch) ----------------
__global__ __launch_bounds__(256) void k_g3ac(float* ws, void* dout, const void* mask) {
  const int z = blockIdx.z;
  const int m0 = blockIdx.x * 16;
  const int w = threadIdx.x >> 6, lane = threadIdx.x & 63;
  const int n0 = blockIdx.y * 256 + w * 64;
  if (n0 >= 300) return;
  const int rA = lane & 15, kq = (lane >> 4) * 8;
  const int rD = m0 + (lane >> 4) * 4, cD = lane & 15;

  if (z < 2) {                 // ---- g3a: tG = tanh(cat(h_share,h_x)@WT + b) ----
    const int u = z;
    const int f32 = is_f32(mask);
    const unsigned short* A0 = (const unsigned short*)(ws + O_HS2);
    const unsigned short* A1 = (const unsigned short*)(ws + (u ? O_HR2 : O_HN2));
    const unsigned short* B = (const unsigned short*)(ws + O_WNB) + (long)u * 180000;
    const unsigned short* a0p = A0 + (long)(m0 + rA) * 320 + kq;
    const unsigned short* a1p = A1 + (long)(m0 + rA) * 320 + kq;
    const unsigned short* bp = B + (long)(n0 + rA) * 600 + kq;
    f32x4 acc[4] = {};
    for (int kt = 0; kt < 10; ++kt) {
      bf16x8 af = *(const bf16x8*)(a0p + kt * 32);
#pragma unroll
      for (int nf = 0; nf < 4; ++nf) {
        bf16x8 bf = *(const bf16x8*)(bp + (long)nf * 16 * 600 + kt * 32);
        acc[nf] = __builtin_amdgcn_mfma_f32_16x16x32_bf16(af, bf, acc[nf], 0, 0, 0);
      }
    }
    for (int kt = 0; kt < 10; ++kt) {
      bf16x8 af = *(const bf16x8*)(a1p + kt * 32);
#pragma unroll
      for (int nf = 0; nf < 4; ++nf) {
        bf16x8 bf = *(const bf16x8*)(bp + (long)nf * 16 * 600 + 300 + kt * 32);
        acc[nf] = __builtin_amdgcn_mfma_f32_16x16x32_bf16(af, bf, acc[nf], 0, 0, 0);
      }
    }
#pragma unroll
    for (int nf = 0; nf < 4; ++nf) {
      int col = n0 + nf * 16 + cD;
      if (col < 300) {
        float bv = ws[(u ? O_BR : O_BN) + col];
#pragma unroll
        for (int q = 0; q < 4; ++q) {
          float tv = tanhf(acc[nf][q] + bv);
          long idx = (long)(rD + q) * 300 + col;
          ws[O_TG + (long)u * 240000 + idx] = tv;
          if (u == 1) stout(dout, 1600000L + idx, tv, f32);
        }
      }
    }
  } else {                     // ---- g3c: start/end token projections a,b ----
    const int u = (z - 2) >> 1, proj = (z - 2) & 1;
    const unsigned short* A = (const unsigned short*)(ws + (u ? O_HR2 : O_HN2));
    const unsigned short* B = (const unsigned short*)(ws + O_W1B) + (long)u * 273600;
    const unsigned short* ap = A + (long)(m0 + rA) * 320 + kq;
    const unsigned short* bp = B + (long)(n0 + rA) * 912 + proj * 304 + kq;
    f32x4 acc[4] = {};
    for (int kt = 0; kt < 10; ++kt) {
      bf16x8 af = *(const bf16x8*)(ap + kt * 32);
#pragma unroll
      for (int nf = 0; nf < 4; ++nf) {
        bf16x8 bf = *(const bf16x8*)(bp + (long)nf * 16 * 912 + kt * 32);
        acc[nf] = __builtin_amdgcn_mfma_f32_16x16x32_bf16(af, bf, acc[nf], 0, 0, 0);
      }
    }
    const long dst = (proj ? O_BU : O_AU) + (long)u * 240000;
#pragma unroll
    for (int nf = 0; nf < 4; ++nf) {
      int col = n0 + nf * 16 + cD;
      if (col < 300) {
#pragma unroll
        for (int q = 0; q < 4; ++q)
          ws[dst + (long)(rD + q) * 300 + col] = acc[nf][q];
      }
    }
  }
}

// ---------------- max over L + global projection c ----------------
__global__ __launch_bounds__(320) void k_g3b(float* ws) {
  const int u = blockIdx.x >> 3, b = blockIdx.x & 7;
  __shared__ float hs[304];
  const int o = threadIdx.x;
  const float* tg = ws + O_TG + (long)u * 240000;
  if (o < 300) {
    float m = -3e38f;
    for (int l = 0; l < 100; ++l) m = fmaxf(m, tg[((long)l * 8 + b) * 300 + o]);
    hs[o] = m;
  }
  __syncthreads();
  if (o < 300) {
    const float* w1 = ws + (u ? O_W1RT : O_W1NT);
    float acc = ws[(u ? O_B1R : O_B1N) + o];
    for (int k = 0; k < 300; ++k) acc += hs[k] * w1[(long)(600 + k) * 300 + o];
    ws[O_CU + (long)u * 2400 + b * 300 + o] = acc;
  }
}

// ---------------- fused pair scoring: lane-per-pair LN -> elu -> @W2 -> sigmoid*mask ----------------
template <int NOUT, bool TRI>
__device__ __forceinline__ void pair_body(float* ws, void* dout, int f32, int b,
    long obase, long uofs, long w2tofs, long b2ofs, long gbeofs, long cofs,
    float* aS, float* bS, float* miS, float* mjS) {
  const int i0 = blockIdx.x * 16, j0 = blockIdx.y * 32;
  const int t = threadIdx.x;
  for (int s = t; s < 16 * 300; s += 512) {
    int r = s / 300, o = s - r * 300;
    int i = i0 + r;
    float v = 0.f;
    if (i < 100) v = ws[O_AU + uofs + ((long)i * 8 + b) * 300 + o] + ws[cofs + b * 300 + o];
    aS[r * 305 + o] = v;
  }
  for (int s = t; s < 32 * 300; s += 512) {
    int r = s / 300, o = s - r * 300;
    int j = j0 + r;
    bS[r * 305 + o] = (j < 100) ? ws[O_BU + uofs + ((long)j * 8 + b) * 300 + o] : 0.f;
  }
  if (t < 16) miS[t] = (i0 + t < 100) ? ws[O_MASK + (i0 + t) * 8 + b] : 0.f;
  else if (t < 48) mjS[t - 16] = (j0 + t - 16 < 100) ? ws[O_MASK + (j0 + t - 16) * 8 + b] : 0.f;
  __syncthreads();
  const int wid = t >> 6, lane = t & 63;
  const int ii = wid * 2 + (lane >> 5);
  const int jj = lane & 31;
  const int i = i0 + ii, j = j0 + jj;
  if (i >= 100 || j >= 100) return;
  long base = obase + (((long)i * 100 + j) * 8 + b) * NOUT;
  // whole-wave lower-triangle skip (all 64 pair-slots have j < i)
  if (TRI && (j0 + 31 < i0 + wid * 2)) {
#pragma unroll
    for (int q = 0; q < NOUT; ++q) stout(dout, base + q, 0.f, f32);
    return;
  }
  const float* ap = aS + ii * 305;
  const float* bp = bS + jj * 305;
  float sum = 0.f, ssq = 0.f;
#pragma unroll 4
  for (int o = 0; o < 300; ++o) {
    float v = ap[o] + bp[o];
    sum += v;
    ssq = fmaf(v, v, ssq);
  }
  float mean = sum * (1.f / 300.f);
  float inv = rsqrtf(ssq * (1.f / 300.f) - mean * mean + EPSV);
  float acc[NOUT];
#pragma unroll
  for (int q = 0; q < NOUT; ++q) acc[q] = 0.f;
  const float* gbe = ws + gbeofs;
  const float* w2t = ws + w2tofs;
#pragma unroll 2
  for (int o = 0; o < 300; ++o) {
    float v = ap[o] + bp[o];
    float xn = fmaf((v - mean) * inv, gbe[2 * o], gbe[2 * o + 1]);
    float e = xn > 0.f ? xn : (__expf(xn) - 1.f);
#pragma unroll
    for (int q = 0; q < NOUT; ++q) acc[q] = fmaf(e, w2t[o * NOUT + q], acc[q]);
  }
  float mv = miS[ii] * mjS[jj];
  if (TRI && j < i) mv = 0.f;
#pragma unroll
  for (int q = 0; q < NOUT; ++q) {
    float b2v = ws[b2ofs + q];
    stout(dout, base + q, mv / (1.f + __expf(-(acc[q] + b2v))), f32);
  }
}

__global__ __launch_bounds__(512) void k_pairs2(float* ws, void* dout, const void* mask) {
  __shared__ float aS[16 * 305];
  __shared__ float bS[32 * 305];
  __shared__ float miS[16], mjS[32];
  const int f32 = is_f32(mask);
  const int z = blockIdx.z;
  if (z < 8)
    pair_body<8, true>(ws, dout, f32, z, 0L, 0L, O_W2NT, O_B2N, O_GBEN, O_CU,
                       aS, bS, miS, mjS);
  else
    pair_body<12, false>(ws, dout, f32, z - 8, 640000L, 240000L, O_W2RT, O_B2R, O_GBER,
                         O_CU + 2400, aS, bS, miS, mjS);
}

// ---------------- host ----------------
extern "C" void kernel_launch(void* const* d_in, const int* in_sizes, int n_in,
                              void* d_out, int out_size, void* d_ws, size_t ws_size,
                              hipStream_t stream) {
  (void)in_sizes; (void)n_in; (void)out_size; (void)ws_size;
  float* ws = (float*)d_ws;
  const void* mask = d_in[1];
  k_prep<<<dim3(12641), dim3(256), 0, stream>>>(ws, mask,
      d_in[0], d_in[2], d_in[4], d_in[6],
      d_in[8], d_in[16], d_in[10], d_in[18],
      d_in[3], d_in[5], d_in[7],
      d_in[9], d_in[11], d_in[12], d_in[13], d_in[14], d_in[15],
      d_in[17], d_in[19], d_in[20], d_in[21], d_in[22], d_in[23]);
  k_xg<<<dim3(50, 6), dim3(256), 0, stream>>>(ws, d_in[0], d_in[2], mask);
  k_scan<<<dim3(40), dim3(512), 0, stream>>>(ws);
  k_g3ac<<<dim3(50, 2, 6), dim3(256), 0, stream>>>(ws, d_out, mask);
  k_g3b<<<dim3(16), dim3(320), 0, stream>>>(ws);
  k_pairs2<<<dim3(7, 4, 16), dim3(512), 0, stream>>>(ws, d_out, mask);
}

// Round 9
// 679.112 us; speedup vs baseline: 3.0915x; 1.0738x over previous
//
#include <hip/hip_runtime.h>
#include <hip/hip_bf16.h>

#define EPSV 1e-5f

typedef _Float16 f16x2 __attribute__((ext_vector_type(2)));
typedef short bf16x8 __attribute__((ext_vector_type(8)));
typedef float f32x4 __attribute__((ext_vector_type(4)));
typedef unsigned long long ull;

// ---------------- workspace layout (float offsets) ----------------
static constexpr long O_WHT = 1024;                  // scan Wh f16-pairs: 225000 uints
static constexpr long O_WTT = O_WHT + 225000;        // scan Wt f16-pairs: 135000 uints
static constexpr long O_W1NT= O_WTT + 135000;        // f32 [900][300] (g3b)
static constexpr long O_W1RT= O_W1NT + 270000;       // f32 [900][300]
static constexpr long O_XB  = O_W1RT + 270000;       // bf16 [800][768] (f32 fallback only)
static constexpr long O_WIB = O_XB + 307200;         // bf16 [1500][768] (f32 fallback only)
static constexpr long O_WNB = O_WIB + 576000;        // bf16 2x[300][600]
static constexpr long O_W1B = O_WNB + 180000;        // bf16 2x[300][912] (3x304 sub)
static constexpr long O_XG  = O_W1B + 273600;        // f32 [800][1500]
static constexpr long O_PUB = O_XG + 1200000;        // seq-embedded ulongs:
//   cs64 [8][1504] ulong = 24064 f;  (h64 slot unused);  c64 [8][304]
static constexpr long O_H64 = O_PUB + 24064;
static constexpr long O_C64 = O_H64 + 4864;
static constexpr long PUBSZ = 33792;
static constexpr long O_HN2 = O_PUB + PUBSZ;         // bf16 [800][320]
static constexpr long O_HR2 = O_HN2 + 128000;
static constexpr long O_HS2 = O_HR2 + 128000;
static constexpr long O_TG  = O_HS2 + 128000;        // f32 [2][800][300]
static constexpr long O_AU  = O_TG + 480000;         // f32 [2][800][300]
static constexpr long O_BU  = O_AU + 480000;
static constexpr long O_CU  = O_BU + 480000;         // f32 [2][8][300]
static constexpr long O_MASK= O_CU + 4800;           // [100][8]
static constexpr long O_BI  = O_MASK + 800;          // 1500
static constexpr long O_BH  = O_BI + 1504;           // 1500
static constexpr long O_BT  = O_BH + 1504;           // 300
static constexpr long O_BN  = O_BT + 304;
static constexpr long O_B1N = O_BN + 304;
static constexpr long O_GN  = O_B1N + 304;
static constexpr long O_BEN = O_GN + 304;
static constexpr long O_W2N = O_BEN + 304;           // [8][300]
static constexpr long O_B2N = O_W2N + 2400;          // 8
static constexpr long O_BR  = O_B2N + 16;
static constexpr long O_B1R = O_BR + 304;
static constexpr long O_GR  = O_B1R + 304;
static constexpr long O_BER = O_GR + 304;
static constexpr long O_W2R = O_BER + 304;           // [12][300]
static constexpr long O_B2R = O_W2R + 3600;          // 12
static constexpr long O_W2NT= O_B2R + 16;            // [300][8]
static constexpr long O_GBEN= O_W2NT + 2400;         // [300][2]
static constexpr long O_W2RT= O_GBEN + 608;          // [300][12]
static constexpr long O_GBER= O_W2RT + 3600;         // [300][2]

__device__ __forceinline__ int is_f32(const void* mask) {
  return *((const unsigned*)mask) == 0x3F800000u;    // f32 1.0f vs bf16 {1,1}=0x3F803F80
}
__device__ __forceinline__ float ldin(const void* p, long i, int f32) {
  if (f32) return ((const float*)p)[i];
  unsigned int w = ((unsigned int)(((const unsigned short*)p)[i])) << 16;
  return __uint_as_float(w);
}
__device__ __forceinline__ unsigned short inbitsb(const void* p, long i, int f32) {
  if (!f32) return ((const unsigned short*)p)[i];
  __hip_bfloat16 hb = __float2bfloat16(((const float*)p)[i]);
  return *reinterpret_cast<unsigned short*>(&hb);
}
__device__ __forceinline__ unsigned short bfbits(float v) {
  __hip_bfloat16 hb = __float2bfloat16(v);
  return *reinterpret_cast<unsigned short*>(&hb);
}
__device__ __forceinline__ void stout(void* p, long i, float v, int f32) {
  if (f32) ((float*)p)[i] = v;
  else ((__hip_bfloat16*)p)[i] = __float2bfloat16(v);
}
__device__ __forceinline__ unsigned packf16(float a, float b) {
  union { _Float16 h[2]; unsigned u; } x;
  x.h[0] = (_Float16)a; x.h[1] = (_Float16)b;
  return x.u;
}
__device__ __forceinline__ float dot2(unsigned wu, unsigned xu, float acc) {
  return __builtin_amdgcn_fdot2(__builtin_bit_cast(f16x2, wu),
                                __builtin_bit_cast(f16x2, xu), acc, false);
}

// ---- seq-embedded MALL exchange: one 8B relaxed atomic = (f32 bits <<32) | seq ----
__device__ __forceinline__ void pub64(ull* p, float v, unsigned seq) {
  ull w = ((ull)__float_as_uint(v) << 32) | (ull)seq;
  __hip_atomic_store(p, w, __ATOMIC_RELAXED, __HIP_MEMORY_SCOPE_AGENT);
}
__device__ __forceinline__ ull ld64(const ull* p) {
  return __hip_atomic_load(p, __ATOMIC_RELAXED, __HIP_MEMORY_SCOPE_AGENT);
}
__device__ __forceinline__ float val64(ull w) {
  return __uint_as_float((unsigned)(w >> 32));
}

// ---------------- one prep kernel: pack + transpose + misc + zero + cvt ----------------
__global__ __launch_bounds__(256) void k_prep(float* ws, const void* mask,
    const void* x, const void* wi, const void* wh, const void* wt,
    const void* wn, const void* wr, const void* w1n, const void* w1r,
    const void* bi, const void* bh, const void* bt,
    const void* bn, const void* b1n, const void* gn, const void* ben,
    const void* w2n, const void* b2n, const void* br, const void* b1r,
    const void* gr, const void* ber, const void* w2r, const void* b2r) {
  const int f32 = is_f32(mask);
  const int blk = blockIdx.x, t = threadIdx.x;

  if (blk < 1407) {                       // ---- scan-weight f16-pair pack ----
    int q = blk * 256 + t;
    if (q < 225000) {
      int g = q / 45000, r = q % 45000;
      int hh = r / 22500, r2 = r % 22500;
      int i = r2 / 450, tt = r2 % 450;
      int o2 = tt % 150, kc = tt / 150;
      int row = g * 300 + 2 * o2 + hh;
      int k0 = 2 * (kc * 50 + i);
      float lo = ldin(wh, (long)row * 300 + k0, f32);
      float hi = ldin(wh, (long)row * 300 + k0 + 1, f32);
      ((unsigned*)(ws + O_WHT))[q] = packf16(lo, hi);
    } else if (q < 360000) {
      int q2 = q - 225000;
      int g = q2 / 27000, r = q2 % 27000;
      int hh = r / 13500, r2 = r % 13500;
      int j = r2 / 450, tt = r2 % 450;
      int o2 = tt % 30, kc = tt / 30;
      int row = g * 60 + 2 * o2 + hh;
      int k0 = 2 * (kc * 30 + j);
      float lo = ldin(wt, (long)row * 900 + k0, f32);
      float hi = ldin(wt, (long)row * 900 + k0 + 1, f32);
      ((unsigned*)(ws + O_WTT))[q2] = packf16(lo, hi);
    }
    return;
  }
  if (blk < 1987) {                       // ---- W1 f32 transposes (580 tiles) ----
    __shared__ float ts[32][33];
    int tile = blk - 1407;
    int m = tile >= 290; int ti = tile - m * 290;
    const void* src = m ? w1r : w1n;
    const long D = m ? O_W1RT : O_W1NT;
    const int R = 300, C = 900;
    int tr = ti / 29, tc = ti % 29;
    int r0 = tr * 32, c0 = tc * 32;
    const int tx = t & 31, ty = t >> 5;
#pragma unroll
    for (int k = 0; k < 4; k++) {
      int r = r0 + ty + 8 * k, c = c0 + tx;
      ts[ty + 8 * k][tx] = (r < R && c < C) ? ldin(src, (long)r * C + c, f32) : 0.f;
    }
    __syncthreads();
#pragma unroll
    for (int k = 0; k < 4; k++) {
      int c = c0 + ty + 8 * k, r = r0 + tx;
      if (c < C && r < R) ws[D + (long)c * R + r] = ts[tx][ty + 8 * k];
    }
    return;
  }
  if (blk < 2197) {                       // ---- misc + FULL pub zero (replay safety!) ----
    long i = (long)(blk - 1987) * 256 + t;
    if (i >= 19720 + PUBSZ) return;
    if (i >= 19720) { ws[O_PUB + (i - 19720)] = 0.f; return; }
    long idx = i; const void* s; long d; float v;
    if (idx < 800)                   { s = mask; d = O_MASK; }
    else if ((idx -= 800) < 1500)    { s = bi;  d = O_BI; }
    else if ((idx -= 1500) < 1500)   { s = bh;  d = O_BH; }
    else if ((idx -= 1500) < 300)    { s = bt;  d = O_BT; }
    else if ((idx -= 300) < 300)     { s = bn;  d = O_BN; }
    else if ((idx -= 300) < 300)     { s = b1n; d = O_B1N; }
    else if ((idx -= 300) < 300)     { s = gn;  d = O_GN; }
    else if ((idx -= 300) < 300)     { s = ben; d = O_BEN; }
    else if ((idx -= 300) < 2400)    { s = w2n; d = O_W2N; }
    else if ((idx -= 2400) < 8)      { s = b2n; d = O_B2N; }
    else if ((idx -= 8) < 300)       { s = br;  d = O_BR; }
    else if ((idx -= 300) < 300)     { s = b1r; d = O_B1R; }
    else if ((idx -= 300) < 300)     { s = gr;  d = O_GR; }
    else if ((idx -= 300) < 300)     { s = ber; d = O_BER; }
    else if ((idx -= 300) < 3600)    { s = w2r; d = O_W2R; }
    else if ((idx -= 3600) < 12)     { s = b2r; d = O_B2R; }
    else if ((idx -= 12) < 2400) {   // W2NT [300][8]
      int o = idx >> 3, q = idx & 7;
      ws[O_W2NT + idx] = ldin(w2n, (long)q * 300 + o, f32);
      return;
    }
    else if ((idx -= 2400) < 600) {  // GBEN [300][2]
      int o = idx >> 1;
      ws[O_GBEN + idx] = ldin((idx & 1) ? ben : gn, o, f32);
      return;
    }
    else if ((idx -= 600) < 3600) {  // W2RT [300][12]
      int o = idx / 12, q = idx % 12;
      ws[O_W2RT + idx] = ldin(w2r, (long)q * 300 + o, f32);
      return;
    }
    else {                           // GBER [300][2]
      idx -= 3600;
      int o = idx >> 1;
      ws[O_GBER + idx] = ldin((idx & 1) ? ber : gr, o, f32);
      return;
    }
    v = ldin(s, idx, f32);
    ws[d + idx] = v;
    return;
  }
  if (blk < 5741) {                       // ---- WNB / W1B bf16 operand fill ----
    long idx = (long)(blk - 2197) * 256 + t;
    if (idx >= 907200) return;
    if (idx < 360000) {
      int u = idx / 180000; long r = idx % 180000;
      ((unsigned short*)(ws + O_WNB))[idx] = inbitsb(u ? wr : wn, r, f32);
    } else {
      long r2 = idx - 360000;              // 2 x [300][912], 3x304 k-sub-blocks
      int u = r2 / 273600; long rr = r2 % 273600;
      int n = rr / 912, kk = rr % 912;
      int p = kk / 304, k = kk - p * 304;
      unsigned short v = 0;
      if (k < 300) v = inbitsb(u ? w1r : w1n, (long)n * 900 + p * 300 + k, f32);
      ((unsigned short*)(ws + O_W1B))[r2] = v;
    }
    return;
  }
  // ---- XB / WIB conversion: needed only when inputs are f32 ----
  if (!f32) return;
  long idx = (long)(blk - 5741) * 256 + t;
  if (idx >= 1766400) return;
  if (idx < 614400) ((unsigned short*)(ws + O_XB))[idx] = inbitsb(x, idx, 1);
  else ((unsigned short*)(ws + O_WIB))[idx - 614400] = inbitsb(wi, idx - 614400, 1);
}

// ---------------- xg = x @ WiT + bi via MFMA: [800][1500] ----------------
__global__ __launch_bounds__(256) void k_xg(float* ws, const void* xin, const void* wiin,
                                            const void* mask) {
  const int f32 = is_f32(mask);
  const unsigned short* X = f32 ? (const unsigned short*)(ws + O_XB)
                                : (const unsigned short*)xin;
  const unsigned short* W = f32 ? (const unsigned short*)(ws + O_WIB)
                                : (const unsigned short*)wiin;
  const int m0 = blockIdx.x * 16;
  const int w = threadIdx.x >> 6, lane = threadIdx.x & 63;
  const int n0 = blockIdx.y * 256 + w * 64;
  const int rA = lane & 15, kq = (lane >> 4) * 8;
  const unsigned short* ax = X + (long)(m0 + rA) * 768 + kq;
  const unsigned short* bx = W + (long)(n0 + rA) * 768 + kq;
  f32x4 acc[4] = {};
  for (int kt = 0; kt < 24; ++kt) {
    bf16x8 af = *(const bf16x8*)(ax + kt * 32);
#pragma unroll
    for (int nf = 0; nf < 4; ++nf) {
      bf16x8 bf = *(const bf16x8*)(bx + (long)nf * 16 * 768 + kt * 32);
      acc[nf] = __builtin_amdgcn_mfma_f32_16x16x32_bf16(af, bf, acc[nf], 0, 0, 0);
    }
  }
  const int rD = m0 + (lane >> 4) * 4, cD = lane & 15;
#pragma unroll
  for (int nf = 0; nf < 4; ++nf) {
    int col = n0 + nf * 16 + cD;
    if (col < 1500) {
      float bv = ws[O_BI + col];
#pragma unroll
      for (int q = 0; q < 4; ++q)
        ws[O_XG + (long)(rD + q) * 1500 + col] = acc[nf][q] + bv;
    }
  }
}

// ---------------- the recurrent scan: 40 WGs, concurrent-batched seq-sync ----------------
__global__ __launch_bounds__(512, 2) void k_scan(float* ws) {
  const int w = blockIdx.x;            // 40
  const int b = w & 7, g = w >> 3;     // batch, gate-group/output-slice
  const int t = threadIdx.x;
  const int lane = t & 63, wid = t >> 6;
  const unsigned* W1 = (const unsigned*)(ws + O_WHT) + g * 45000;
  const unsigned* W2 = (const unsigned*)(ws + O_WTT) + g * 27000;
  const float* xg = ws + O_XG;
  ull* cs64 = (ull*)(ws + O_PUB) + (long)b * 1504;
  ull* c64  = (ull*)(ws + O_C64) + (long)b * 304;
  unsigned short* HN2 = (unsigned short*)(ws + O_HN2);
  unsigned short* HR2 = (unsigned short*)(ws + O_HR2);
  unsigned short* HS2 = (unsigned short*)(ws + O_HS2);

  // persistent weights in registers (f16 pairs along k)
  unsigned wA0[50], wA1[50], wB0[30], wB1[30];
  if (t < 450) {
#pragma unroll
    for (int i = 0; i < 50; ++i) { wA0[i] = W1[i * 450 + t]; wA1[i] = W1[22500 + i * 450 + t]; }
#pragma unroll
    for (int j = 0; j < 30; ++j) { wB0[j] = W2[j * 450 + t]; wB1[j] = W2[13500 + j * 450 + t]; }
  }
  // loop-invariant bias prefetch
  const float bhv = (t < 300) ? ws[O_BH + g * 300 + t] : 0.f;
  const float btv = (t < 60) ? ws[O_BT + g * 60 + t] : 0.f;

  __shared__ __align__(16) unsigned h2[152];     // h as f16 pairs
  __shared__ __align__(16) float cf[304];        // c(l-1) f32
  __shared__ __align__(16) float cfown[64];      // own c slice (skip self-poll)
  __shared__ __align__(16) float gatef[304];
  __shared__ __align__(16) float pacc[3][304];
  __shared__ __align__(16) float csL[1504];
  __shared__ __align__(16) float catf[912];
  __shared__ __align__(16) unsigned cat2[456];
  __shared__ __align__(16) float pacc2[15][64];

  if (t < 64) cfown[t] = 0.f;
  __syncthreads();

  const int o2a = t % 150, kca = t / 150;        // phase-A tile
  const int o2b = t % 30,  kcb = t / 30;         // phase-B tile

  for (int l = 0; l < 100; ++l) {
    const unsigned sl = (unsigned)l, sn = (unsigned)(l + 1);
    // prefetch xg early (L3 latency hides under the c-gather poll)
    float xgv = (t < 300) ? xg[((long)l * 8 + b) * 1500 + g * 300 + t] : 0.f;

    // ---- gather c(l-1): 150 threads, 2 CONCURRENT polls each; h=tanh(c) local ----
    if (t < 150) {
      const int ia = 2 * t;
      float va, vb;
      if (ia / 60 == g) {                        // own slice from LDS
        va = cfown[ia - g * 60]; vb = cfown[ia + 1 - g * 60];
      } else {
        ull wa = ld64(c64 + ia), wb = ld64(c64 + ia + 1);
        long it = 0;
        while ((((unsigned)wa != sl) || ((unsigned)wb != sl)) && ++it < (1L << 22)) {
          if ((unsigned)wa != sl) wa = ld64(c64 + ia);
          if ((unsigned)wb != sl) wb = ld64(c64 + ia + 1);
        }
        va = val64(wa); vb = val64(wb);
      }
      cf[ia] = va; cf[ia + 1] = vb;
      h2[t] = packf16(tanhf(va), tanhf(vb));
    }
    __syncthreads();

    // ---- phase A: gate slice = Wh_g@h + xg + bh; cumsoftmax; publish cs (seq l+1) ----
    if (t < 450) {
      float a0 = 0.f, a1 = 0.f;
      const unsigned* hp = h2 + kca * 50;
#pragma unroll
      for (int i = 0; i < 50; ++i) {
        unsigned hv = hp[i];
        a0 = dot2(wA0[i], hv, a0);
        a1 = dot2(wA1[i], hv, a1);
      }
      pacc[kca][2 * o2a] = a0; pacc[kca][2 * o2a + 1] = a1;
    }
    __syncthreads();
    if (t < 300)
      gatef[t] = pacc[0][t] + pacc[1][t] + pacc[2][t] + xgv + bhv;
    __syncthreads();
    if (g == 0) {
      if (t < 300) {
        float v = tanhf(gatef[t]);
        csL[t] = v;
        pub64(cs64 + t, v, sn);
      }
    } else if (wid == 0) {
      const int base = lane * 5;
      float e0 = 0.f, e1 = 0.f, e2 = 0.f, e3 = 0.f, e4 = 0.f, m = -3.0e38f;
      if (lane < 60) {
        e0 = gatef[base]; e1 = gatef[base + 1]; e2 = gatef[base + 2];
        e3 = gatef[base + 3]; e4 = gatef[base + 4];
        m = fmaxf(fmaxf(fmaxf(e0, e1), fmaxf(e2, e3)), e4);
      }
#pragma unroll
      for (int of = 32; of >= 1; of >>= 1) m = fmaxf(m, __shfl_xor(m, of, 64));
      float s0 = 0.f, s1 = 0.f, s2 = 0.f, s3 = 0.f, s4 = 0.f, tot = 0.f;
      if (lane < 60) {
        e0 = __expf(e0 - m); e1 = __expf(e1 - m); e2 = __expf(e2 - m);
        e3 = __expf(e3 - m); e4 = __expf(e4 - m);
        s0 = e0; s1 = s0 + e1; s2 = s1 + e2; s3 = s2 + e3; s4 = s3 + e4;
        tot = s4;
      }
      float sc = tot;
#pragma unroll
      for (int of = 1; of < 64; of <<= 1) {
        float u = __shfl_up(sc, of, 64);
        if (lane >= of) sc += u;
      }
      float total = __shfl(sc, 63);
      if (lane < 60) {
        float ex = sc - tot, inv = 1.f / total;
        float v0 = (ex + s0) * inv, v1 = (ex + s1) * inv, v2 = (ex + s2) * inv;
        float v3 = (ex + s3) * inv, v4 = (ex + s4) * inv;
        const int o0 = g * 300 + base;
        csL[o0] = v0; csL[o0 + 1] = v1; csL[o0 + 2] = v2; csL[o0 + 3] = v3; csL[o0 + 4] = v4;
        pub64(cs64 + o0 + 0, v0, sn);
        pub64(cs64 + o0 + 1, v1, sn);
        pub64(cs64 + o0 + 2, v2, sn);
        pub64(cs64 + o0 + 3, v3, sn);
        pub64(cs64 + o0 + 4, v4, sn);
      }
    }

    // ---- phase B: gather foreign cs with 3 CONCURRENT polls per thread ----
    {
      const int i0 = t, i1 = t + 512, i2 = t + 1024;
      const bool n0 = (i0 / 300) != g;
      const bool n1 = (i1 < 1500) && ((i1 / 300) != g);
      const bool n2 = (i2 < 1500) && ((i2 / 300) != g);
      ull w0 = n0 ? ld64(cs64 + i0) : 0;
      ull w1 = n1 ? ld64(cs64 + i1) : 0;
      ull w2 = n2 ? ld64(cs64 + i2) : 0;
      long it = 0;
      for (;;) {
        bool s0 = n0 && (unsigned)w0 != sn;
        bool s1 = n1 && (unsigned)w1 != sn;
        bool s2 = n2 && (unsigned)w2 != sn;
        if (!(s0 || s1 || s2) || ++it > (1L << 22)) break;
        if (s0) w0 = ld64(cs64 + i0);
        if (s1) w1 = ld64(cs64 + i1);
        if (s2) w2 = ld64(cs64 + i2);
      }
      if (n0) csL[i0] = val64(w0);
      if (n1) csL[i1] = val64(w1);
      if (n2) csL[i2] = val64(w2);
    }
    __syncthreads();
    if (t < 300) {
      float cgv = csL[t];
      float egi = 1.f - csL[300 + t];
      float rgi = csL[600 + t];
      float egc = 1.f - csL[900 + t];
      float rgc = csL[1200 + t];
      float cin = cf[t];
      float ovc = rgc * egc, upc = rgc - ovc, dnc = egc - ovc;
      float ovi = rgi * egi, upi = rgi - ovi, dni = egi - ovi;
      float sh = ovi * cin + ovc * cgv;
      float cre = upi * cin + upc * cgv + sh;
      float cner = dni * cin + dnc * cgv + sh;
      catf[t] = cre; catf[300 + t] = cner; catf[600 + t] = sh;
      if (g == 0) {
        long rb = ((long)l * 8 + b) * 320;
        HN2[rb + t] = bfbits(tanhf(cner));
        HR2[rb + t] = bfbits(tanhf(cre));
        HS2[rb + t] = bfbits(tanhf(sh));
      }
    } else if (g == 0 && t < 320) {
      long rb = ((long)l * 8 + b) * 320;
      HN2[rb + t] = 0; HR2[rb + t] = 0; HS2[rb + t] = 0;
    }
    __syncthreads();
    if (t < 450) cat2[t] = packf16(catf[2 * t], catf[2 * t + 1]);
    __syncthreads();
    if (t < 450) {
      float a0 = 0.f, a1 = 0.f;
      const unsigned* cp = cat2 + kcb * 30;
#pragma unroll
      for (int j = 0; j < 30; ++j) {
        unsigned cv = cp[j];
        a0 = dot2(wB0[j], cv, a0);
        a1 = dot2(wB1[j], cv, a1);
      }
      pacc2[kcb][2 * o2b] = a0; pacc2[kcb][2 * o2b + 1] = a1;
    }
    __syncthreads();
    if (t < 60) {
      float s = btv;
#pragma unroll
      for (int kc = 0; kc < 15; ++kc) s += pacc2[kc][t];
      pub64(c64 + g * 60 + t, s, sn);    // consumers derive h = tanh(c)
      cfown[t] = s;
    }
    __syncthreads();                     // cfown LDS handoff to next-step gather
  }
}

// ---------------- merged g3a + g3c via MFMA (blockIdx.z dispatch) ----------------
__global__ __launch_bounds__(256) void k_g3ac(float* ws, void* dout, const void* mask) {
  const int z = blockIdx.z;
  const int m0 = blockIdx.x * 16;
  const int w = threadIdx.x >> 6, lane = threadIdx.x & 63;
  const int n0 = blockIdx.y * 256 + w * 64;
  if (n0 >= 300) return;
  const int rA = lane & 15, kq = (lane >> 4) * 8;
  const int rD = m0 + (lane >> 4) * 4, cD = lane & 15;

  if (z < 2) {                 // ---- g3a: tG = tanh(cat(h_share,h_x)@WT + b) ----
    const int u = z;
    const int f32 = is_f32(mask);
    const unsigned short* A0 = (const unsigned short*)(ws + O_HS2);
    const unsigned short* A1 = (const unsigned short*)(ws + (u ? O_HR2 : O_HN2));
    const unsigned short* B = (const unsigned short*)(ws + O_WNB) + (long)u * 180000;
    const unsigned short* a0p = A0 + (long)(m0 + rA) * 320 + kq;
    const unsigned short* a1p = A1 + (long)(m0 + rA) * 320 + kq;
    const unsigned short* bp = B + (long)(n0 + rA) * 600 + kq;
    f32x4 acc[4] = {};
    for (int kt = 0; kt < 10; ++kt) {
      bf16x8 af = *(const bf16x8*)(a0p + kt * 32);
#pragma unroll
      for (int nf = 0; nf < 4; ++nf) {
        bf16x8 bf = *(const bf16x8*)(bp + (long)nf * 16 * 600 + kt * 32);
        acc[nf] = __builtin_amdgcn_mfma_f32_16x16x32_bf16(af, bf, acc[nf], 0, 0, 0);
      }
    }
    for (int kt = 0; kt < 10; ++kt) {
      bf16x8 af = *(const bf16x8*)(a1p + kt * 32);
#pragma unroll
      for (int nf = 0; nf < 4; ++nf) {
        bf16x8 bf = *(const bf16x8*)(bp + (long)nf * 16 * 600 + 300 + kt * 32);
        acc[nf] = __builtin_amdgcn_mfma_f32_16x16x32_bf16(af, bf, acc[nf], 0, 0, 0);
      }
    }
#pragma unroll
    for (int nf = 0; nf < 4; ++nf) {
      int col = n0 + nf * 16 + cD;
      if (col < 300) {
        float bv = ws[(u ? O_BR : O_BN) + col];
#pragma unroll
        for (int q = 0; q < 4; ++q) {
          float tv = tanhf(acc[nf][q] + bv);
          long idx = (long)(rD + q) * 300 + col;
          ws[O_TG + (long)u * 240000 + idx] = tv;
          if (u == 1) stout(dout, 1600000L + idx, tv, f32);
        }
      }
    }
  } else {                     // ---- g3c: start/end token projections a,b ----
    const int u = (z - 2) >> 1, proj = (z - 2) & 1;
    const unsigned short* A = (const unsigned short*)(ws + (u ? O_HR2 : O_HN2));
    const unsigned short* B = (const unsigned short*)(ws + O_W1B) + (long)u * 273600;
    const unsigned short* ap = A + (long)(m0 + rA) * 320 + kq;
    const unsigned short* bp = B + (long)(n0 + rA) * 912 + proj * 304 + kq;
    f32x4 acc[4] = {};
    for (int kt = 0; kt < 10; ++kt) {
      bf16x8 af = *(const bf16x8*)(ap + kt * 32);
#pragma unroll
      for (int nf = 0; nf < 4; ++nf) {
        bf16x8 bf = *(const bf16x8*)(bp + (long)nf * 16 * 912 + kt * 32);
        acc[nf] = __builtin_amdgcn_mfma_f32_16x16x32_bf16(af, bf, acc[nf], 0, 0, 0);
      }
    }
    const long dst = (proj ? O_BU : O_AU) + (long)u * 240000;
#pragma unroll
    for (int nf = 0; nf < 4; ++nf) {
      int col = n0 + nf * 16 + cD;
      if (col < 300) {
#pragma unroll
        for (int q = 0; q < 4; ++q)
          ws[dst + (long)(rD + q) * 300 + col] = acc[nf][q];
      }
    }
  }
}

// ---------------- max over L + global projection c ----------------
__global__ __launch_bounds__(320) void k_g3b(float* ws) {
  const int u = blockIdx.x >> 3, b = blockIdx.x & 7;
  __shared__ float hs[304];
  const int o = threadIdx.x;
  const float* tg = ws + O_TG + (long)u * 240000;
  if (o < 300) {
    float m = -3e38f;
    for (int l = 0; l < 100; ++l) m = fmaxf(m, tg[((long)l * 8 + b) * 300 + o]);
    hs[o] = m;
  }
  __syncthreads();
  if (o < 300) {
    const float* w1 = ws + (u ? O_W1RT : O_W1NT);
    float acc = ws[(u ? O_B1R : O_B1N) + o];
    for (int k = 0; k < 300; ++k) acc += hs[k] * w1[(long)(600 + k) * 300 + o];
    ws[O_CU + (long)u * 2400 + b * 300 + o] = acc;
  }
}

// ---------------- fused pair scoring: lane-per-pair LN -> elu -> @W2 -> sigmoid*mask ----------------
template <int NOUT, bool TRI>
__device__ __forceinline__ void pair_body(float* ws, void* dout, int f32, int b,
    long obase, long uofs, long w2tofs, long b2ofs, long gbeofs, long cofs,
    float* aS, float* bS, float* miS, float* mjS) {
  const int i0 = blockIdx.x * 16, j0 = blockIdx.y * 32;
  const int t = threadIdx.x;
  for (int s = t; s < 16 * 300; s += 512) {
    int r = s / 300, o = s - r * 300;
    int i = i0 + r;
    float v = 0.f;
    if (i < 100) v = ws[O_AU + uofs + ((long)i * 8 + b) * 300 + o] + ws[cofs + b * 300 + o];
    aS[r * 305 + o] = v;
  }
  for (int s = t; s < 32 * 300; s += 512) {
    int r = s / 300, o = s - r * 300;
    int j = j0 + r;
    bS[r * 305 + o] = (j < 100) ? ws[O_BU + uofs + ((long)j * 8 + b) * 300 + o] : 0.f;
  }
  if (t < 16) miS[t] = (i0 + t < 100) ? ws[O_MASK + (i0 + t) * 8 + b] : 0.f;
  else if (t < 48) mjS[t - 16] = (j0 + t - 16 < 100) ? ws[O_MASK + (j0 + t - 16) * 8 + b] : 0.f;
  __syncthreads();
  const int wid = t >> 6, lane = t & 63;
  const int ii = wid * 2 + (lane >> 5);
  const int jj = lane & 31;
  const int i = i0 + ii, j = j0 + jj;
  if (i >= 100 || j >= 100) return;
  long base = obase + (((long)i * 100 + j) * 8 + b) * NOUT;
  // whole-wave lower-triangle skip (all 64 pair-slots have j < i)
  if (TRI && (j0 + 31 < i0 + wid * 2)) {
#pragma unroll
    for (int q = 0; q < NOUT; ++q) stout(dout, base + q, 0.f, f32);
    return;
  }
  const float* ap = aS + ii * 305;
  const float* bp = bS + jj * 305;
  float sum = 0.f, ssq = 0.f;
#pragma unroll 4
  for (int o = 0; o < 300; ++o) {
    float v = ap[o] + bp[o];
    sum += v;
    ssq = fmaf(v, v, ssq);
  }
  float mean = sum * (1.f / 300.f);
  float inv = rsqrtf(ssq * (1.f / 300.f) - mean * mean + EPSV);
  float acc[NOUT];
#pragma unroll
  for (int q = 0; q < NOUT; ++q) acc[q] = 0.f;
  const float* gbe = ws + gbeofs;
  const float* w2t = ws + w2tofs;
#pragma unroll 2
  for (int o = 0; o < 300; ++o) {
    float v = ap[o] + bp[o];
    float xn = fmaf((v - mean) * inv, gbe[2 * o], gbe[2 * o + 1]);
    float e = xn > 0.f ? xn : (__expf(xn) - 1.f);
#pragma unroll
    for (int q = 0; q < NOUT; ++q) acc[q] = fmaf(e, w2t[o * NOUT + q], acc[q]);
  }
  float mv = miS[ii] * mjS[jj];
  if (TRI && j < i) mv = 0.f;
#pragma unroll
  for (int q = 0; q < NOUT; ++q) {
    float b2v = ws[b2ofs + q];
    stout(dout, base + q, mv / (1.f + __expf(-(acc[q] + b2v))), f32);
  }
}

__global__ __launch_bounds__(512) void k_pairs2(float* ws, void* dout, const void* mask) {
  __shared__ float aS[16 * 305];
  __shared__ float bS[32 * 305];
  __shared__ float miS[16], mjS[32];
  const int f32 = is_f32(mask);
  const int z = blockIdx.z;
  if (z < 8)
    pair_body<8, true>(ws, dout, f32, z, 0L, 0L, O_W2NT, O_B2N, O_GBEN, O_CU,
                       aS, bS, miS, mjS);
  else
    pair_body<12, false>(ws, dout, f32, z - 8, 640000L, 240000L, O_W2RT, O_B2R, O_GBER,
                         O_CU + 2400, aS, bS, miS, mjS);
}

// ---------------- host ----------------
extern "C" void kernel_launch(void* const* d_in, const int* in_sizes, int n_in,
                              void* d_out, int out_size, void* d_ws, size_t ws_size,
                              hipStream_t stream) {
  (void)in_sizes; (void)n_in; (void)out_size; (void)ws_size;
  float* ws = (float*)d_ws;
  const void* mask = d_in[1];
  k_prep<<<dim3(12641), dim3(256), 0, stream>>>(ws, mask,
      d_in[0], d_in[2], d_in[4], d_in[6],
      d_in[8], d_in[16], d_in[10], d_in[18],
      d_in[3], d_in[5], d_in[7],
      d_in[9], d_in[11], d_in[12], d_in[13], d_in[14], d_in[15],
      d_in[17], d_in[19], d_in[20], d_in[21], d_in[22], d_in[23]);
  k_xg<<<dim3(50, 6), dim3(256), 0, stream>>>(ws, d_in[0], d_in[2], mask);
  k_scan<<<dim3(40), dim3(512), 0, stream>>>(ws);
  k_g3ac<<<dim3(50, 2, 6), dim3(256), 0, stream>>>(ws, d_out, mask);
  k_g3b<<<dim3(16), dim3(320), 0, stream>>>(ws);
  k_pairs2<<<dim3(7, 4, 16), dim3(512), 0, stream>>>(ws, d_out, mask);
}

// Round 10
// 677.765 us; speedup vs baseline: 3.0977x; 1.0020x over previous
//
#include <hip/hip_runtime.h>
#include <hip/hip_bf16.h>

#define EPSV 1e-5f

typedef _Float16 f16x2 __attribute__((ext_vector_type(2)));
typedef short bf16x8 __attribute__((ext_vector_type(8)));
typedef float f32x4 __attribute__((ext_vector_type(4)));
typedef unsigned long long ull;

// ---------------- workspace layout (float offsets) ----------------
static constexpr long O_WHT = 1024;                  // scan Wh f16-pairs: 225000 uints
static constexpr long O_WTT = O_WHT + 225000;        // scan Wt f16-pairs: 135000 uints
static constexpr long O_W1NT= O_WTT + 135000;        // f32 [900][300] (g3b)
static constexpr long O_W1RT= O_W1NT + 270000;       // f32 [900][300]
static constexpr long O_XB  = O_W1RT + 270000;       // bf16 [800][768] (f32 fallback only)
static constexpr long O_WIB = O_XB + 307200;         // bf16 [1500][768] (f32 fallback only)
static constexpr long O_WNB = O_WIB + 576000;        // bf16 2x[300][600]
static constexpr long O_W1B = O_WNB + 180000;        // bf16 2x[300][912] (3x304 sub)
static constexpr long O_XG  = O_W1B + 273600;        // f32 [800][1500]
static constexpr long O_PUB = O_XG + 1200000;        // seq-embedded ulongs:
//   cs64 [8][1504] ulong = 24064 f;  (h64 slot unused);  c64 [8][304]
static constexpr long O_H64 = O_PUB + 24064;
static constexpr long O_C64 = O_H64 + 4864;
static constexpr long PUBSZ = 33792;
static constexpr long O_HN2 = O_PUB + PUBSZ;         // bf16 [800][320]
static constexpr long O_HR2 = O_HN2 + 128000;
static constexpr long O_HS2 = O_HR2 + 128000;
static constexpr long O_TG  = O_HS2 + 128000;        // f32 [2][800][300]
static constexpr long O_AU  = O_TG + 480000;         // f32 [2][800][300]
static constexpr long O_BU  = O_AU + 480000;
static constexpr long O_CU  = O_BU + 480000;         // f32 [2][8][300]
static constexpr long O_MASK= O_CU + 4800;           // [100][8]
static constexpr long O_BI  = O_MASK + 800;          // 1500
static constexpr long O_BH  = O_BI + 1504;           // 1500
static constexpr long O_BT  = O_BH + 1504;           // 300
static constexpr long O_BN  = O_BT + 304;
static constexpr long O_B1N = O_BN + 304;
static constexpr long O_GN  = O_B1N + 304;
static constexpr long O_BEN = O_GN + 304;
static constexpr long O_W2N = O_BEN + 304;           // [8][300]
static constexpr long O_B2N = O_W2N + 2400;          // 8
static constexpr long O_BR  = O_B2N + 16;
static constexpr long O_B1R = O_BR + 304;
static constexpr long O_GR  = O_B1R + 304;
static constexpr long O_BER = O_GR + 304;
static constexpr long O_W2R = O_BER + 304;           // [12][300]
static constexpr long O_B2R = O_W2R + 3600;          // 12
static constexpr long O_W2NT= O_B2R + 16;            // [300][8]
static constexpr long O_GBEN= O_W2NT + 2400;         // [300][2]
static constexpr long O_W2RT= O_GBEN + 608;          // [300][12]
static constexpr long O_GBER= O_W2RT + 3600;         // [300][2]

__device__ __forceinline__ int is_f32(const void* mask) {
  return *((const unsigned*)mask) == 0x3F800000u;    // f32 1.0f vs bf16 {1,1}=0x3F803F80
}
__device__ __forceinline__ float ldin(const void* p, long i, int f32) {
  if (f32) return ((const float*)p)[i];
  unsigned int w = ((unsigned int)(((const unsigned short*)p)[i])) << 16;
  return __uint_as_float(w);
}
__device__ __forceinline__ unsigned short inbitsb(const void* p, long i, int f32) {
  if (!f32) return ((const unsigned short*)p)[i];
  __hip_bfloat16 hb = __float2bfloat16(((const float*)p)[i]);
  return *reinterpret_cast<unsigned short*>(&hb);
}
__device__ __forceinline__ unsigned short bfbits(float v) {
  __hip_bfloat16 hb = __float2bfloat16(v);
  return *reinterpret_cast<unsigned short*>(&hb);
}
__device__ __forceinline__ void stout(void* p, long i, float v, int f32) {
  if (f32) ((float*)p)[i] = v;
  else ((__hip_bfloat16*)p)[i] = __float2bfloat16(v);
}
__device__ __forceinline__ unsigned packf16(float a, float b) {
  union { _Float16 h[2]; unsigned u; } x;
  x.h[0] = (_Float16)a; x.h[1] = (_Float16)b;
  return x.u;
}
__device__ __forceinline__ float dot2(unsigned wu, unsigned xu, float acc) {
  return __builtin_amdgcn_fdot2(__builtin_bit_cast(f16x2, wu),
                                __builtin_bit_cast(f16x2, xu), acc, false);
}

// ---- seq-embedded MALL exchange: one 8B relaxed atomic = (f32 bits <<32) | seq ----
__device__ __forceinline__ void pub64(ull* p, float v, unsigned seq) {
  ull w = ((ull)__float_as_uint(v) << 32) | (ull)seq;
  __hip_atomic_store(p, w, __ATOMIC_RELAXED, __HIP_MEMORY_SCOPE_AGENT);
}
__device__ __forceinline__ ull ld64(const ull* p) {
  return __hip_atomic_load(p, __ATOMIC_RELAXED, __HIP_MEMORY_SCOPE_AGENT);
}
__device__ __forceinline__ float val64(ull w) {
  return __uint_as_float((unsigned)(w >> 32));
}

// ---------------- one prep kernel, compact grid: 1024 stride blocks + 580 tiles ----------------
__global__ __launch_bounds__(256) void k_prep(float* ws, const void* mask,
    const void* x, const void* wi, const void* wh, const void* wt,
    const void* wn, const void* wr, const void* w1n, const void* w1r,
    const void* bi, const void* bh, const void* bt,
    const void* bn, const void* b1n, const void* gn, const void* ben,
    const void* w2n, const void* b2n, const void* br, const void* b1r,
    const void* gr, const void* ber, const void* w2r, const void* b2r) {
  const int f32 = is_f32(mask);
  const int blk = blockIdx.x, t = threadIdx.x;

  if (blk >= 1024) {                      // ---- W1 f32 transposes (580 tiles) ----
    __shared__ float ts[32][33];
    int tile = blk - 1024;
    int m = tile >= 290; int ti = tile - m * 290;
    const void* src = m ? w1r : w1n;
    const long D = m ? O_W1RT : O_W1NT;
    const int R = 300, C = 900;
    int tr = ti / 29, tc = ti % 29;
    int r0 = tr * 32, c0 = tc * 32;
    const int tx = t & 31, ty = t >> 5;
#pragma unroll
    for (int k = 0; k < 4; k++) {
      int r = r0 + ty + 8 * k, c = c0 + tx;
      ts[ty + 8 * k][tx] = (r < R && c < C) ? ldin(src, (long)r * C + c, f32) : 0.f;
    }
    __syncthreads();
#pragma unroll
    for (int k = 0; k < 4; k++) {
      int c = c0 + ty + 8 * k, r = r0 + tx;
      if (c < C && r < R) ws[D + (long)c * R + r] = ts[tx][ty + 8 * k];
    }
    return;
  }

  // ---- grid-stride flat work: S0 pack | S1 misc+zero | S2 WNB/W1B | S3 XB/WIB (f32 only) ----
  const long NCOPY = f32 ? 3087112L : 1320712L;
  for (long i = (long)blk * 256 + t; i < NCOPY; i += 1024L * 256) {
    if (i < 360000) {                     // S0: scan-weight f16-pair pack
      long q = i;
      if (q < 225000) {
        int g = q / 45000, r = q % 45000;
        int hh = r / 22500, r2 = r % 22500;
        int ii = r2 / 450, tt = r2 % 450;
        int o2 = tt % 150, kc = tt / 150;
        int row = g * 300 + 2 * o2 + hh;
        int k0 = 2 * (kc * 50 + ii);
        float lo = ldin(wh, (long)row * 300 + k0, f32);
        float hi = ldin(wh, (long)row * 300 + k0 + 1, f32);
        ((unsigned*)(ws + O_WHT))[q] = packf16(lo, hi);
      } else {
        long q2 = q - 225000;
        int g = q2 / 27000, r = q2 % 27000;
        int hh = r / 13500, r2 = r % 13500;
        int j = r2 / 450, tt = r2 % 450;
        int o2 = tt % 30, kc = tt / 30;
        int row = g * 60 + 2 * o2 + hh;
        int k0 = 2 * (kc * 30 + j);
        float lo = ldin(wt, (long)row * 900 + k0, f32);
        float hi = ldin(wt, (long)row * 900 + k0 + 1, f32);
        ((unsigned*)(ws + O_WTT))[q2] = packf16(lo, hi);
      }
      continue;
    }
    if (i < 413512) {                     // S1: misc biases/transposes + pub zero
      long idx = i - 360000;
      if (idx >= 19720) { ws[O_PUB + (idx - 19720)] = 0.f; continue; }
      const void* s; long d; float v;
      if (idx < 800)                   { s = mask; d = O_MASK; }
      else if ((idx -= 800) < 1500)    { s = bi;  d = O_BI; }
      else if ((idx -= 1500) < 1500)   { s = bh;  d = O_BH; }
      else if ((idx -= 1500) < 300)    { s = bt;  d = O_BT; }
      else if ((idx -= 300) < 300)     { s = bn;  d = O_BN; }
      else if ((idx -= 300) < 300)     { s = b1n; d = O_B1N; }
      else if ((idx -= 300) < 300)     { s = gn;  d = O_GN; }
      else if ((idx -= 300) < 300)     { s = ben; d = O_BEN; }
      else if ((idx -= 300) < 2400)    { s = w2n; d = O_W2N; }
      else if ((idx -= 2400) < 8)      { s = b2n; d = O_B2N; }
      else if ((idx -= 8) < 300)       { s = br;  d = O_BR; }
      else if ((idx -= 300) < 300)     { s = b1r; d = O_B1R; }
      else if ((idx -= 300) < 300)     { s = gr;  d = O_GR; }
      else if ((idx -= 300) < 300)     { s = ber; d = O_BER; }
      else if ((idx -= 300) < 3600)    { s = w2r; d = O_W2R; }
      else if ((idx -= 3600) < 12)     { s = b2r; d = O_B2R; }
      else if ((idx -= 12) < 2400) {   // W2NT [300][8]
        int o = idx >> 3, q = idx & 7;
        ws[O_W2NT + idx] = ldin(w2n, (long)q * 300 + o, f32);
        continue;
      }
      else if ((idx -= 2400) < 600) {  // GBEN [300][2]
        int o = idx >> 1;
        ws[O_GBEN + idx] = ldin((idx & 1) ? ben : gn, o, f32);
        continue;
      }
      else if ((idx -= 600) < 3600) {  // W2RT [300][12]
        int o = idx / 12, q = idx % 12;
        ws[O_W2RT + idx] = ldin(w2r, (long)q * 300 + o, f32);
        continue;
      }
      else {                           // GBER [300][2]
        idx -= 3600;
        int o = idx >> 1;
        ws[O_GBER + idx] = ldin((idx & 1) ? ber : gr, o, f32);
        continue;
      }
      v = ldin(s, idx, f32);
      ws[d + idx] = v;
      continue;
    }
    if (i < 1320712) {                    // S2: WNB / W1B bf16 operand fill
      long idx = i - 413512;
      if (idx < 360000) {
        int u = idx / 180000; long r = idx % 180000;
        ((unsigned short*)(ws + O_WNB))[idx] = inbitsb(u ? wr : wn, r, f32);
      } else {
        long r2 = idx - 360000;            // 2 x [300][912], 3x304 k-sub-blocks
        int u = r2 / 273600; long rr = r2 % 273600;
        int n = rr / 912, kk = rr % 912;
        int p = kk / 304, k = kk - p * 304;
        unsigned short v = 0;
        if (k < 300) v = inbitsb(u ? w1r : w1n, (long)n * 900 + p * 300 + k, f32);
        ((unsigned short*)(ws + O_W1B))[r2] = v;
      }
      continue;
    }
    // S3: XB / WIB conversion (reached only when f32)
    long idx = i - 1320712;
    if (idx < 614400) ((unsigned short*)(ws + O_XB))[idx] = inbitsb(x, idx, 1);
    else ((unsigned short*)(ws + O_WIB))[idx - 614400] = inbitsb(wi, idx - 614400, 1);
  }
}

// ---------------- xg = x @ WiT + bi via MFMA: [800][1500] ----------------
__global__ __launch_bounds__(256) void k_xg(float* ws, const void* xin, const void* wiin,
                                            const void* mask) {
  const int f32 = is_f32(mask);
  const unsigned short* X = f32 ? (const unsigned short*)(ws + O_XB)
                                : (const unsigned short*)xin;
  const unsigned short* W = f32 ? (const unsigned short*)(ws + O_WIB)
                                : (const unsigned short*)wiin;
  const int m0 = blockIdx.x * 16;
  const int w = threadIdx.x >> 6, lane = threadIdx.x & 63;
  const int n0 = blockIdx.y * 256 + w * 64;
  const int rA = lane & 15, kq = (lane >> 4) * 8;
  const unsigned short* ax = X + (long)(m0 + rA) * 768 + kq;
  const unsigned short* bx = W + (long)(n0 + rA) * 768 + kq;
  f32x4 acc[4] = {};
  for (int kt = 0; kt < 24; ++kt) {
    bf16x8 af = *(const bf16x8*)(ax + kt * 32);
#pragma unroll
    for (int nf = 0; nf < 4; ++nf) {
      bf16x8 bf = *(const bf16x8*)(bx + (long)nf * 16 * 768 + kt * 32);
      acc[nf] = __builtin_amdgcn_mfma_f32_16x16x32_bf16(af, bf, acc[nf], 0, 0, 0);
    }
  }
  const int rD = m0 + (lane >> 4) * 4, cD = lane & 15;
#pragma unroll
  for (int nf = 0; nf < 4; ++nf) {
    int col = n0 + nf * 16 + cD;
    if (col < 1500) {
      float bv = ws[O_BI + col];
#pragma unroll
      for (int q = 0; q < 4; ++q)
        ws[O_XG + (long)(rD + q) * 1500 + col] = acc[nf][q] + bv;
    }
  }
}

// ---------------- the recurrent scan: 40 WGs, concurrent-batched seq-sync (frozen R9) ----------------
__global__ __launch_bounds__(512, 2) void k_scan(float* ws) {
  const int w = blockIdx.x;            // 40
  const int b = w & 7, g = w >> 3;     // batch, gate-group/output-slice
  const int t = threadIdx.x;
  const int lane = t & 63, wid = t >> 6;
  const unsigned* W1 = (const unsigned*)(ws + O_WHT) + g * 45000;
  const unsigned* W2 = (const unsigned*)(ws + O_WTT) + g * 27000;
  const float* xg = ws + O_XG;
  ull* cs64 = (ull*)(ws + O_PUB) + (long)b * 1504;
  ull* c64  = (ull*)(ws + O_C64) + (long)b * 304;
  unsigned short* HN2 = (unsigned short*)(ws + O_HN2);
  unsigned short* HR2 = (unsigned short*)(ws + O_HR2);
  unsigned short* HS2 = (unsigned short*)(ws + O_HS2);

  // persistent weights in registers (f16 pairs along k)
  unsigned wA0[50], wA1[50], wB0[30], wB1[30];
  if (t < 450) {
#pragma unroll
    for (int i = 0; i < 50; ++i) { wA0[i] = W1[i * 450 + t]; wA1[i] = W1[22500 + i * 450 + t]; }
#pragma unroll
    for (int j = 0; j < 30; ++j) { wB0[j] = W2[j * 450 + t]; wB1[j] = W2[13500 + j * 450 + t]; }
  }
  // loop-invariant bias prefetch
  const float bhv = (t < 300) ? ws[O_BH + g * 300 + t] : 0.f;
  const float btv = (t < 60) ? ws[O_BT + g * 60 + t] : 0.f;

  __shared__ __align__(16) unsigned h2[152];     // h as f16 pairs
  __shared__ __align__(16) float cf[304];        // c(l-1) f32
  __shared__ __align__(16) float cfown[64];      // own c slice (skip self-poll)
  __shared__ __align__(16) float gatef[304];
  __shared__ __align__(16) float pacc[3][304];
  __shared__ __align__(16) float csL[1504];
  __shared__ __align__(16) float catf[912];
  __shared__ __align__(16) unsigned cat2[456];
  __shared__ __align__(16) float pacc2[15][64];

  if (t < 64) cfown[t] = 0.f;
  __syncthreads();

  const int o2a = t % 150, kca = t / 150;        // phase-A tile
  const int o2b = t % 30,  kcb = t / 30;         // phase-B tile

  for (int l = 0; l < 100; ++l) {
    const unsigned sl = (unsigned)l, sn = (unsigned)(l + 1);
    // prefetch xg early (L3 latency hides under the c-gather poll)
    float xgv = (t < 300) ? xg[((long)l * 8 + b) * 1500 + g * 300 + t] : 0.f;

    // ---- gather c(l-1): 150 threads, 2 CONCURRENT polls each; h=tanh(c) local ----
    if (t < 150) {
      const int ia = 2 * t;
      float va, vb;
      if (ia / 60 == g) {                        // own slice from LDS
        va = cfown[ia - g * 60]; vb = cfown[ia + 1 - g * 60];
      } else {
        ull wa = ld64(c64 + ia), wb = ld64(c64 + ia + 1);
        long it = 0;
        while ((((unsigned)wa != sl) || ((unsigned)wb != sl)) && ++it < (1L << 22)) {
          if ((unsigned)wa != sl) wa = ld64(c64 + ia);
          if ((unsigned)wb != sl) wb = ld64(c64 + ia + 1);
        }
        va = val64(wa); vb = val64(wb);
      }
      cf[ia] = va; cf[ia + 1] = vb;
      h2[t] = packf16(tanhf(va), tanhf(vb));
    }
    __syncthreads();

    // ---- phase A: gate slice = Wh_g@h + xg + bh; cumsoftmax; publish cs (seq l+1) ----
    if (t < 450) {
      float a0 = 0.f, a1 = 0.f;
      const unsigned* hp = h2 + kca * 50;
#pragma unroll
      for (int i = 0; i < 50; ++i) {
        unsigned hv = hp[i];
        a0 = dot2(wA0[i], hv, a0);
        a1 = dot2(wA1[i], hv, a1);
      }
      pacc[kca][2 * o2a] = a0; pacc[kca][2 * o2a + 1] = a1;
    }
    __syncthreads();
    if (t < 300)
      gatef[t] = pacc[0][t] + pacc[1][t] + pacc[2][t] + xgv + bhv;
    __syncthreads();
    if (g == 0) {
      if (t < 300) {
        float v = tanhf(gatef[t]);
        csL[t] = v;
        pub64(cs64 + t, v, sn);
      }
    } else if (wid == 0) {
      const int base = lane * 5;
      float e0 = 0.f, e1 = 0.f, e2 = 0.f, e3 = 0.f, e4 = 0.f, m = -3.0e38f;
      if (lane < 60) {
        e0 = gatef[base]; e1 = gatef[base + 1]; e2 = gatef[base + 2];
        e3 = gatef[base + 3]; e4 = gatef[base + 4];
        m = fmaxf(fmaxf(fmaxf(e0, e1), fmaxf(e2, e3)), e4);
      }
#pragma unroll
      for (int of = 32; of >= 1; of >>= 1) m = fmaxf(m, __shfl_xor(m, of, 64));
      float s0 = 0.f, s1 = 0.f, s2 = 0.f, s3 = 0.f, s4 = 0.f, tot = 0.f;
      if (lane < 60) {
        e0 = __expf(e0 - m); e1 = __expf(e1 - m); e2 = __expf(e2 - m);
        e3 = __expf(e3 - m); e4 = __expf(e4 - m);
        s0 = e0; s1 = s0 + e1; s2 = s1 + e2; s3 = s2 + e3; s4 = s3 + e4;
        tot = s4;
      }
      float sc = tot;
#pragma unroll
      for (int of = 1; of < 64; of <<= 1) {
        float u = __shfl_up(sc, of, 64);
        if (lane >= of) sc += u;
      }
      float total = __shfl(sc, 63);
      if (lane < 60) {
        float ex = sc - tot, inv = 1.f / total;
        float v0 = (ex + s0) * inv, v1 = (ex + s1) * inv, v2 = (ex + s2) * inv;
        float v3 = (ex + s3) * inv, v4 = (ex + s4) * inv;
        const int o0 = g * 300 + base;
        csL[o0] = v0; csL[o0 + 1] = v1; csL[o0 + 2] = v2; csL[o0 + 3] = v3; csL[o0 + 4] = v4;
        pub64(cs64 + o0 + 0, v0, sn);
        pub64(cs64 + o0 + 1, v1, sn);
        pub64(cs64 + o0 + 2, v2, sn);
        pub64(cs64 + o0 + 3, v3, sn);
        pub64(cs64 + o0 + 4, v4, sn);
      }
    }

    // ---- phase B: gather foreign cs with 3 CONCURRENT polls per thread ----
    {
      const int i0 = t, i1 = t + 512, i2 = t + 1024;
      const bool n0 = (i0 / 300) != g;
      const bool n1 = (i1 < 1500) && ((i1 / 300) != g);
      const bool n2 = (i2 < 1500) && ((i2 / 300) != g);
      ull w0 = n0 ? ld64(cs64 + i0) : 0;
      ull w1 = n1 ? ld64(cs64 + i1) : 0;
      ull w2 = n2 ? ld64(cs64 + i2) : 0;
      long it = 0;
      for (;;) {
        bool s0 = n0 && (unsigned)w0 != sn;
        bool s1 = n1 && (unsigned)w1 != sn;
        bool s2 = n2 && (unsigned)w2 != sn;
        if (!(s0 || s1 || s2) || ++it > (1L << 22)) break;
        if (s0) w0 = ld64(cs64 + i0);
        if (s1) w1 = ld64(cs64 + i1);
        if (s2) w2 = ld64(cs64 + i2);
      }
      if (n0) csL[i0] = val64(w0);
      if (n1) csL[i1] = val64(w1);
      if (n2) csL[i2] = val64(w2);
    }
    __syncthreads();
    if (t < 300) {
      float cgv = csL[t];
      float egi = 1.f - csL[300 + t];
      float rgi = csL[600 + t];
      float egc = 1.f - csL[900 + t];
      float rgc = csL[1200 + t];
      float cin = cf[t];
      float ovc = rgc * egc, upc = rgc - ovc, dnc = egc - ovc;
      float ovi = rgi * egi, upi = rgi - ovi, dni = egi - ovi;
      float sh = ovi * cin + ovc * cgv;
      float cre = upi * cin + upc * cgv + sh;
      float cner = dni * cin + dnc * cgv + sh;
      catf[t] = cre; catf[300 + t] = cner; catf[600 + t] = sh;
      if (g == 0) {
        long rb = ((long)l * 8 + b) * 320;
        HN2[rb + t] = bfbits(tanhf(cner));
        HR2[rb + t] = bfbits(tanhf(cre));
        HS2[rb + t] = bfbits(tanhf(sh));
      }
    } else if (g == 0 && t < 320) {
      long rb = ((long)l * 8 + b) * 320;
      HN2[rb + t] = 0; HR2[rb + t] = 0; HS2[rb + t] = 0;
    }
    __syncthreads();
    if (t < 450) cat2[t] = packf16(catf[2 * t], catf[2 * t + 1]);
    __syncthreads();
    if (t < 450) {
      float a0 = 0.f, a1 = 0.f;
      const unsigned* cp = cat2 + kcb * 30;
#pragma unroll
      for (int j = 0; j < 30; ++j) {
        unsigned cv = cp[j];
        a0 = dot2(wB0[j], cv, a0);
        a1 = dot2(wB1[j], cv, a1);
      }
      pacc2[kcb][2 * o2b] = a0; pacc2[kcb][2 * o2b + 1] = a1;
    }
    __syncthreads();
    if (t < 60) {
      float s = btv;
#pragma unroll
      for (int kc = 0; kc < 15; ++kc) s += pacc2[kc][t];
      pub64(c64 + g * 60 + t, s, sn);    // consumers derive h = tanh(c)
      cfown[t] = s;
    }
    __syncthreads();                     // cfown LDS handoff to next-step gather
  }
}

// ---------------- merged g3a + g3c via MFMA (blockIdx.z dispatch) ----------------
__global__ __launch_bounds__(256) void k_g3ac(float* ws, void* dout, const void* mask) {
  const int z = blockIdx.z;
  const int m0 = blockIdx.x * 16;
  const int w = threadIdx.x >> 6, lane = threadIdx.x & 63;
  const int n0 = blockIdx.y * 256 + w * 64;
  if (n0 >= 300) return;
  const int rA = lane & 15, kq = (lane >> 4) * 8;
  const int rD = m0 + (lane >> 4) * 4, cD = lane & 15;

  if (z < 2) {                 // ---- g3a: tG = tanh(cat(h_share,h_x)@WT + b) ----
    const int u = z;
    const int f32 = is_f32(mask);
    const unsigned short* A0 = (const unsigned short*)(ws + O_HS2);
    const unsigned short* A1 = (const unsigned short*)(ws + (u ? O_HR2 : O_HN2));
    const unsigned short* B = (const unsigned short*)(ws + O_WNB) + (long)u * 180000;
    const unsigned short* a0p = A0 + (long)(m0 + rA) * 320 + kq;
    const unsigned short* a1p = A1 + (long)(m0 + rA) * 320 + kq;
    const unsigned short* bp = B + (long)(n0 + rA) * 600 + kq;
    f32x4 acc[4] = {};
    for (int kt = 0; kt < 10; ++kt) {
      bf16x8 af = *(const bf16x8*)(a0p + kt * 32);
#pragma unroll
      for (int nf = 0; nf < 4; ++nf) {
        bf16x8 bf = *(const bf16x8*)(bp + (long)nf * 16 * 600 + kt * 32);
        acc[nf] = __builtin_amdgcn_mfma_f32_16x16x32_bf16(af, bf, acc[nf], 0, 0, 0);
      }
    }
    for (int kt = 0; kt < 10; ++kt) {
      bf16x8 af = *(const bf16x8*)(a1p + kt * 32);
#pragma unroll
      for (int nf = 0; nf < 4; ++nf) {
        bf16x8 bf = *(const bf16x8*)(bp + (long)nf * 16 * 600 + 300 + kt * 32);
        acc[nf] = __builtin_amdgcn_mfma_f32_16x16x32_bf16(af, bf, acc[nf], 0, 0, 0);
      }
    }
#pragma unroll
    for (int nf = 0; nf < 4; ++nf) {
      int col = n0 + nf * 16 + cD;
      if (col < 300) {
        float bv = ws[(u ? O_BR : O_BN) + col];
#pragma unroll
        for (int q = 0; q < 4; ++q) {
          float tv = tanhf(acc[nf][q] + bv);
          long idx = (long)(rD + q) * 300 + col;
          ws[O_TG + (long)u * 240000 + idx] = tv;
          if (u == 1) stout(dout, 1600000L + idx, tv, f32);
        }
      }
    }
  } else {                     // ---- g3c: start/end token projections a,b ----
    const int u = (z - 2) >> 1, proj = (z - 2) & 1;
    const unsigned short* A = (const unsigned short*)(ws + (u ? O_HR2 : O_HN2));
    const unsigned short* B = (const unsigned short*)(ws + O_W1B) + (long)u * 273600;
    const unsigned short* ap = A + (long)(m0 + rA) * 320 + kq;
    const unsigned short* bp = B + (long)(n0 + rA) * 912 + proj * 304 + kq;
    f32x4 acc[4] = {};
    for (int kt = 0; kt < 10; ++kt) {
      bf16x8 af = *(const bf16x8*)(ap + kt * 32);
#pragma unroll
      for (int nf = 0; nf < 4; ++nf) {
        bf16x8 bf = *(const bf16x8*)(bp + (long)nf * 16 * 912 + kt * 32);
        acc[nf] = __builtin_amdgcn_mfma_f32_16x16x32_bf16(af, bf, acc[nf], 0, 0, 0);
      }
    }
    const long dst = (proj ? O_BU : O_AU) + (long)u * 240000;
#pragma unroll
    for (int nf = 0; nf < 4; ++nf) {
      int col = n0 + nf * 16 + cD;
      if (col < 300) {
#pragma unroll
        for (int q = 0; q < 4; ++q)
          ws[dst + (long)(rD + q) * 300 + col] = acc[nf][q];
      }
    }
  }
}

// ---------------- max over L + global projection c ----------------
__global__ __launch_bounds__(320) void k_g3b(float* ws) {
  const int u = blockIdx.x >> 3, b = blockIdx.x & 7;
  __shared__ float hs[304];
  const int o = threadIdx.x;
  const float* tg = ws + O_TG + (long)u * 240000;
  if (o < 300) {
    float m = -3e38f;
    for (int l = 0; l < 100; ++l) m = fmaxf(m, tg[((long)l * 8 + b) * 300 + o]);
    hs[o] = m;
  }
  __syncthreads();
  if (o < 300) {
    const float* w1 = ws + (u ? O_W1RT : O_W1NT);
    float acc = ws[(u ? O_B1R : O_B1N) + o];
    for (int k = 0; k < 300; ++k) acc += hs[k] * w1[(long)(600 + k) * 300 + o];
    ws[O_CU + (long)u * 2400 + b * 300 + o] = acc;
  }
}

// ---------------- fused pair scoring: lane-per-pair LN -> elu -> @W2 -> sigmoid*mask ----------------
template <int NOUT, bool TRI>
__device__ __forceinline__ void pair_body(float* ws, void* dout, int f32, int b,
    long obase, long uofs, long w2tofs, long b2ofs, long gbeofs, long cofs,
    float* aS, float* bS, float* miS, float* mjS) {
  const int i0 = blockIdx.x * 16, j0 = blockIdx.y * 32;
  const int t = threadIdx.x;
  for (int s = t; s < 16 * 300; s += 512) {
    int r = s / 300, o = s - r * 300;
    int i = i0 + r;
    float v = 0.f;
    if (i < 100) v = ws[O_AU + uofs + ((long)i * 8 + b) * 300 + o] + ws[cofs + b * 300 + o];
    aS[r * 305 + o] = v;
  }
  for (int s = t; s < 32 * 300; s += 512) {
    int r = s / 300, o = s - r * 300;
    int j = j0 + r;
    bS[r * 305 + o] = (j < 100) ? ws[O_BU + uofs + ((long)j * 8 + b) * 300 + o] : 0.f;
  }
  if (t < 16) miS[t] = (i0 + t < 100) ? ws[O_MASK + (i0 + t) * 8 + b] : 0.f;
  else if (t < 48) mjS[t - 16] = (j0 + t - 16 < 100) ? ws[O_MASK + (j0 + t - 16) * 8 + b] : 0.f;
  __syncthreads();
  const int wid = t >> 6, lane = t & 63;
  const int ii = wid * 2 + (lane >> 5);
  const int jj = lane & 31;
  const int i = i0 + ii, j = j0 + jj;
  if (i >= 100 || j >= 100) return;
  long base = obase + (((long)i * 100 + j) * 8 + b) * NOUT;
  // whole-wave lower-triangle skip (all 64 pair-slots have j < i)
  if (TRI && (j0 + 31 < i0 + wid * 2)) {
#pragma unroll
    for (int q = 0; q < NOUT; ++q) stout(dout, base + q, 0.f, f32);
    return;
  }
  const float* ap = aS + ii * 305;
  const float* bp = bS + jj * 305;
  float sum = 0.f, ssq = 0.f;
#pragma unroll 4
  for (int o = 0; o < 300; ++o) {
    float v = ap[o] + bp[o];
    sum += v;
    ssq = fmaf(v, v, ssq);
  }
  float mean = sum * (1.f / 300.f);
  float inv = rsqrtf(ssq * (1.f / 300.f) - mean * mean + EPSV);
  float acc[NOUT];
#pragma unroll
  for (int q = 0; q < NOUT; ++q) acc[q] = 0.f;
  const float* gbe = ws + gbeofs;
  const float* w2t = ws + w2tofs;
#pragma unroll 2
  for (int o = 0; o < 300; ++o) {
    float v = ap[o] + bp[o];
    float xn = fmaf((v - mean) * inv, gbe[2 * o], gbe[2 * o + 1]);
    float e = xn > 0.f ? xn : (__expf(xn) - 1.f);
#pragma unroll
    for (int q = 0; q < NOUT; ++q) acc[q] = fmaf(e, w2t[o * NOUT + q], acc[q]);
  }
  float mv = miS[ii] * mjS[jj];
  if (TRI && j < i) mv = 0.f;
#pragma unroll
  for (int q = 0; q < NOUT; ++q) {
    float b2v = ws[b2ofs + q];
    stout(dout, base + q, mv / (1.f + __expf(-(acc[q] + b2v))), f32);
  }
}

__global__ __launch_bounds__(512) void k_pairs2(float* ws, void* dout, const void* mask) {
  __shared__ float aS[16 * 305];
  __shared__ float bS[32 * 305];
  __shared__ float miS[16], mjS[32];
  const int f32 = is_f32(mask);
  const int z = blockIdx.z;
  if (z < 8)
    pair_body<8, true>(ws, dout, f32, z, 0L, 0L, O_W2NT, O_B2N, O_GBEN, O_CU,
                       aS, bS, miS, mjS);
  else
    pair_body<12, false>(ws, dout, f32, z - 8, 640000L, 240000L, O_W2RT, O_B2R, O_GBER,
                         O_CU + 2400, aS, bS, miS, mjS);
}

// ---------------- host ----------------
extern "C" void kernel_launch(void* const* d_in, const int* in_sizes, int n_in,
                              void* d_out, int out_size, void* d_ws, size_t ws_size,
                              hipStream_t stream) {
  (void)in_sizes; (void)n_in; (void)out_size; (void)ws_size;
  float* ws = (float*)d_ws;
  const void* mask = d_in[1];
  k_prep<<<dim3(1604), dim3(256), 0, stream>>>(ws, mask,
      d_in[0], d_in[2], d_in[4], d_in[6],
      d_in[8], d_in[16], d_in[10], d_in[18],
      d_in[3], d_in[5], d_in[7],
      d_in[9], d_in[11], d_in[12], d_in[13], d_in[14], d_in[15],
      d_in[17], d_in[19], d_in[20], d_in[21], d_in[22], d_in[23]);
  k_xg<<<dim3(50, 6), dim3(256), 0, stream>>>(ws, d_in[0], d_in[2], mask);
  k_scan<<<dim3(40), dim3(512), 0, stream>>>(ws);
  k_g3ac<<<dim3(50, 2, 6), dim3(256), 0, stream>>>(ws, d_out, mask);
  k_g3b<<<dim3(16), dim3(320), 0, stream>>>(ws);
  k_pairs2<<<dim3(7, 4, 16), dim3(512), 0, stream>>>(ws, d_out, mask);
}